// Round 1
// baseline (2392.554 us; speedup 1.0000x reference)
//
#include <hip/hip_runtime.h>
#include <cstddef>

#define NU_ 50000
#define NF_ 25000
#define E_  500000

// ---------------------------------------------------------------------------
// v = W @ a  (v[k] = sum_h W[k][h] * a[h]) for 8 (W,a) pairs, one block each.
// ---------------------------------------------------------------------------
struct WAArgs {
    const float* W[8];
    const float* a[8];
};

__global__ __launch_bounds__(256) void wa_vec(WAArgs args, float* __restrict__ vout) {
    __shared__ float Ws[128][129];
    __shared__ float as[128];
    const int b = blockIdx.x;
    const float* W = args.W[b];
    const float* a = args.a[b];
    for (int i = threadIdx.x; i < 128 * 32; i += 256) {
        float4 w = ((const float4*)W)[i];
        int r = i >> 5, c = (i & 31) << 2;
        Ws[r][c] = w.x; Ws[r][c + 1] = w.y; Ws[r][c + 2] = w.z; Ws[r][c + 3] = w.w;
    }
    if (threadIdx.x < 128) as[threadIdx.x] = a[threadIdx.x];
    __syncthreads();
    if (threadIdx.x < 128) {
        float s = 0.f;
        #pragma unroll 8
        for (int h = 0; h < 128; ++h) s += Ws[threadIdx.x][h] * as[h];
        vout[b * 128 + threadIdx.x] = s;
    }
}

// ---------------------------------------------------------------------------
// C[N,128] = X[N,128] @ W[128,128]  (fp32, single K-stage, 8x8 reg tile)
// ---------------------------------------------------------------------------
__global__ __launch_bounds__(256) void gemm128(const float* __restrict__ X,
                                               const float* __restrict__ W,
                                               float* __restrict__ C, int N) {
    __shared__ float Xs[128][129];   // +1 pad: Xs[r][k] bank = (r+k)&31 -> conflict-free
    __shared__ float Ws[128][128];   // read as float4 pairs
    const int t = threadIdx.x;
    const int row0 = blockIdx.x * 128;

    for (int i = t; i < 128 * 32; i += 256)
        ((float4*)(&Ws[0][0]))[i] = ((const float4*)W)[i];

    for (int i = t; i < 128 * 32; i += 256) {
        int r = i >> 5, c4 = (i & 31) << 2;
        int gr = row0 + r;
        float4 v = make_float4(0.f, 0.f, 0.f, 0.f);
        if (gr < N) v = ((const float4*)(X + (size_t)gr * 128))[i & 31];
        Xs[r][c4] = v.x; Xs[r][c4 + 1] = v.y; Xs[r][c4 + 2] = v.z; Xs[r][c4 + 3] = v.w;
    }
    __syncthreads();

    const int tr = (t >> 4) * 8;
    const int tc = (t & 15) * 8;
    float acc[8][8];
    #pragma unroll
    for (int i = 0; i < 8; ++i)
        #pragma unroll
        for (int j = 0; j < 8; ++j) acc[i][j] = 0.f;

    for (int k = 0; k < 128; ++k) {
        float xv[8];
        #pragma unroll
        for (int i = 0; i < 8; ++i) xv[i] = Xs[tr + i][k];
        float4 w0 = *(const float4*)&Ws[k][tc];
        float4 w1 = *(const float4*)&Ws[k][tc + 4];
        float wv[8] = {w0.x, w0.y, w0.z, w0.w, w1.x, w1.y, w1.z, w1.w};
        #pragma unroll
        for (int i = 0; i < 8; ++i)
            #pragma unroll
            for (int j = 0; j < 8; ++j) acc[i][j] += xv[i] * wv[j];
    }

    #pragma unroll
    for (int i = 0; i < 8; ++i) {
        int gr = row0 + tr + i;
        if (gr < N) {
            float4* cp = (float4*)(C + (size_t)gr * 128 + tc);
            cp[0] = make_float4(acc[i][0], acc[i][1], acc[i][2], acc[i][3]);
            cp[1] = make_float4(acc[i][4], acc[i][5], acc[i][6], acc[i][7]);
        }
    }
}

// ---------------------------------------------------------------------------
// out[n] = dot(X[n,:], v)   one wave per row
// ---------------------------------------------------------------------------
__global__ __launch_bounds__(256) void matvec128(const float* __restrict__ X,
                                                 const float* __restrict__ v,
                                                 float* __restrict__ out, int N) {
    int row = blockIdx.x * 4 + (threadIdx.x >> 6);
    int lane = threadIdx.x & 63;
    if (row >= N) return;
    float2 x = ((const float2*)(X + (size_t)row * 128))[lane];
    float2 vv = ((const float2*)v)[lane];
    float s = x.x * vv.x + x.y * vv.y;
    #pragma unroll
    for (int off = 32; off; off >>= 1) s += __shfl_xor(s, off);
    if (lane == 0) out[row] = s;
}

// ---------------------------------------------------------------------------
// ee[e] = exp(leaky_relu(asn[src]+adn[dst], 0.2)); den[dst] += ee
// (segment-max skipped: alpha is shift-invariant, e-values are O(1))
// ---------------------------------------------------------------------------
__global__ void edge_softmax_num(const int* __restrict__ src, const int* __restrict__ dst,
                                 const float* __restrict__ asn, const float* __restrict__ adn,
                                 float* __restrict__ ee, float* __restrict__ den, int E) {
    int e = blockIdx.x * 256 + threadIdx.x;
    if (e >= E) return;
    float v = asn[src[e]] + adn[dst[e]];
    v = v > 0.f ? v : 0.2f * v;
    float x = expf(v);
    ee[e] = x;
    atomicAdd(&den[dst[e]], x);
}

// out[n][c] = bias[c]
__global__ void init_bias(float* __restrict__ out, const float* __restrict__ b, int N) {
    int i = blockIdx.x * 256 + threadIdx.x;
    if (i < N * 32) ((float4*)out)[i] = ((const float4*)b)[i & 31];
}

// out[dst] += (ee/den[dst]) * hs[src]   one wave per edge, 2 cols/lane
__global__ __launch_bounds__(256) void edge_aggregate(const int* __restrict__ src,
                                                      const int* __restrict__ dst,
                                                      const float* __restrict__ ee,
                                                      const float* __restrict__ den,
                                                      const float* __restrict__ hs,
                                                      float* __restrict__ out, int E) {
    int e = blockIdx.x * 4 + (threadIdx.x >> 6);
    int lane = threadIdx.x & 63;
    if (e >= E) return;
    int s = src[e], d = dst[e];
    float alpha = ee[e] / (den[d] + 1e-16f);
    float2 h = ((const float2*)(hs + (size_t)s * 128))[lane];
    atomicAdd(&out[(size_t)d * 128 + 2 * lane], alpha * h.x);
    atomicAdd(&out[(size_t)d * 128 + 2 * lane + 1], alpha * h.y);
}

// ---------------------------------------------------------------------------
// BatchNorm stats: stat[c]=sum, stat[128+c]=sumsq (column-wise over N rows)
// ---------------------------------------------------------------------------
__global__ void bn_stats(const float* __restrict__ x, float* __restrict__ stat, int N) {
    int c = threadIdx.x & 127;
    int h = threadIdx.x >> 7;
    float s = 0.f, q = 0.f;
    for (int r = blockIdx.x * 2 + h; r < N; r += gridDim.x * 2) {
        float v = x[(size_t)r * 128 + c];
        s += v; q += v * v;
    }
    atomicAdd(&stat[c], s);
    atomicAdd(&stat[128 + c], q);
}

// x = elu((x-mu)*rsqrt(var+eps)*g + b), in place
__global__ void bn_apply(float* __restrict__ x, const float* __restrict__ stat,
                         const float* __restrict__ g, const float* __restrict__ b,
                         int N, float invN) {
    int i = blockIdx.x * 256 + threadIdx.x;
    if (i >= N * 32) return;
    int c4 = (i & 31) << 2;
    float4 v = ((float4*)x)[i];
    float* vp = &v.x;
    #pragma unroll
    for (int j = 0; j < 4; ++j) {
        int c = c4 + j;
        float mu = stat[c] * invN;
        float var = stat[128 + c] * invN - mu * mu;
        float xn = (vp[j] - mu) * rsqrtf(var + 1e-5f) * g[c] + b[c];
        vp[j] = xn > 0.f ? xn : expm1f(xn);
    }
    ((float4*)x)[i] = v;
}

// ---------------------------------------------------------------------------
// prefs[u] = tanh( leaky_relu(xu2[u]@hw1 + hb1, 0.01) @ hw2 + hb2 )
// one wave per user; lane c owns hidden unit c (H/2 = 64)
// ---------------------------------------------------------------------------
__global__ __launch_bounds__(256) void mlp_pref(const float* __restrict__ xu,
                                                const float* __restrict__ hw1,
                                                const float* __restrict__ hb1,
                                                const float* __restrict__ hw2,
                                                const float* __restrict__ hb2,
                                                float* __restrict__ prefs, int N) {
    __shared__ float xs[4][128];
    int w = threadIdx.x >> 6;
    int lane = threadIdx.x & 63;
    int u = blockIdx.x * 4 + w;
    if (u < N) {
        float2 xv = ((const float2*)(xu + (size_t)u * 128))[lane];
        xs[w][2 * lane] = xv.x;
        xs[w][2 * lane + 1] = xv.y;
    }
    __syncthreads();
    if (u >= N) return;
    float acc = 0.f;
    #pragma unroll 4
    for (int k = 0; k < 128; ++k) acc += xs[w][k] * hw1[k * 64 + lane];
    acc += hb1[lane];
    acc = acc > 0.f ? acc : 0.01f * acc;
    float p = acc * hw2[lane];
    #pragma unroll
    for (int off = 32; off; off >>= 1) p += __shfl_xor(p, off);
    if (lane == 0) prefs[u] = tanhf(p + hb2[0]);
}

// s[he_food[e]] += prefs[he_user[e]] * score[e]
__global__ void health_scatter(const int* __restrict__ hu, const int* __restrict__ hf,
                               const float* __restrict__ score, const float* __restrict__ prefs,
                               float* __restrict__ s, int E) {
    int e = blockIdx.x * 256 + threadIdx.x;
    if (e >= E) return;
    atomicAdd(&s[hf[e]], prefs[hu[e]] * score[e]);
}

// xf2[f][c] += 0.1 * s[f]
__global__ void add_health(float* __restrict__ xf2, const float* __restrict__ s, int n4) {
    int i = blockIdx.x * 256 + threadIdx.x;
    if (i >= n4) return;
    float sv = 0.1f * s[i >> 5];
    float4 v = ((float4*)xf2)[i];
    v.x += sv; v.y += sv; v.z += sv; v.w += sv;
    ((float4*)xf2)[i] = v;
}

// ---------------------------------------------------------------------------
extern "C" void kernel_launch(void* const* d_in, const int* in_sizes, int n_in,
                              void* d_out, int out_size, void* d_ws, size_t ws_size,
                              hipStream_t stream) {
    const float* x_user = (const float*)d_in[0];
    const float* x_food = (const float*)d_in[1];
    const int* uf_src = (const int*)d_in[2];
    const int* uf_dst = (const int*)d_in[3];
    const int* fu_src = (const int*)d_in[4];
    const int* fu_dst = (const int*)d_in[5];
    const int* he_user = (const int*)d_in[6];
    const int* he_food = (const int*)d_in[7];
    const float* scores = (const float*)d_in[8];
    // GAT params: [9..13] w1_uf_src, w1_uf_dst, a1_uf_src, a1_uf_dst, b1_uf
    //             [14..18] w1_fu_*  [19..23] w2_uf_*  [24..28] w2_fu_*
    const float* w1_uf_src = (const float*)d_in[9];
    const float* w1_uf_dst = (const float*)d_in[10];
    const float* a1_uf_src = (const float*)d_in[11];
    const float* a1_uf_dst = (const float*)d_in[12];
    const float* b1_uf     = (const float*)d_in[13];
    const float* w1_fu_src = (const float*)d_in[14];
    const float* w1_fu_dst = (const float*)d_in[15];
    const float* a1_fu_src = (const float*)d_in[16];
    const float* a1_fu_dst = (const float*)d_in[17];
    const float* b1_fu     = (const float*)d_in[18];
    const float* w2_uf_src = (const float*)d_in[19];
    const float* w2_uf_dst = (const float*)d_in[20];
    const float* a2_uf_src = (const float*)d_in[21];
    const float* a2_uf_dst = (const float*)d_in[22];
    const float* b2_uf     = (const float*)d_in[23];
    const float* w2_fu_src = (const float*)d_in[24];
    const float* w2_fu_dst = (const float*)d_in[25];
    const float* a2_fu_src = (const float*)d_in[26];
    const float* a2_fu_dst = (const float*)d_in[27];
    const float* b2_fu     = (const float*)d_in[28];
    const float* bn1_user_g = (const float*)d_in[29];
    const float* bn1_user_b = (const float*)d_in[30];
    const float* bn1_food_g = (const float*)d_in[31];
    const float* bn1_food_b = (const float*)d_in[32];
    const float* bn2_user_g = (const float*)d_in[33];
    const float* bn2_user_b = (const float*)d_in[34];
    const float* bn2_food_g = (const float*)d_in[35];
    const float* bn2_food_b = (const float*)d_in[36];
    const float* hw1 = (const float*)d_in[37];
    const float* hb1 = (const float*)d_in[38];
    const float* hw2 = (const float*)d_in[39];
    const float* hb2 = (const float*)d_in[40];

    float* outp  = (float*)d_out;
    float* xu2   = outp;                          // [NU,128]
    float* xf2   = outp + (size_t)NU_ * 128;      // [NF,128]
    float* prefs = xf2 + (size_t)NF_ * 128;       // [NU]

    float* ws   = (float*)d_ws;
    float* hs   = ws;                             // NU*128
    float* xu1  = hs  + (size_t)NU_ * 128;        // NU*128
    float* xf1  = xu1 + (size_t)NU_ * 128;        // NF*128
    float* ee   = xf1 + (size_t)NF_ * 128;        // E
    float* asn  = ee  + E_;                       // NU
    float* adn  = asn + NU_;                      // NU
    float* den  = adn + NU_;                      // NU
    float* sbuf = den + NU_;                      // NF
    float* stat = sbuf + NF_;                     // 256
    float* vall = stat + 256;                     // 8*128

    // --- precompute v = W@a for all 8 (dst-side GEMMs eliminated) ---
    WAArgs wa;
    wa.W[0] = w1_uf_src; wa.a[0] = a1_uf_src;
    wa.W[1] = w1_uf_dst; wa.a[1] = a1_uf_dst;
    wa.W[2] = w1_fu_src; wa.a[2] = a1_fu_src;
    wa.W[3] = w1_fu_dst; wa.a[3] = a1_fu_dst;
    wa.W[4] = w2_uf_src; wa.a[4] = a2_uf_src;
    wa.W[5] = w2_uf_dst; wa.a[5] = a2_uf_dst;
    wa.W[6] = w2_fu_src; wa.a[6] = a2_fu_src;
    wa.W[7] = w2_fu_dst; wa.a[7] = a2_fu_dst;
    wa_vec<<<8, 256, 0, stream>>>(wa, vall);

    auto run_gat = [&](const float* xsrc, const float* xdst, const int* src, const int* dst,
                       const float* w_s, const float* vs, const float* vd, const float* bias,
                       float* out, int Ns, int Nd) {
        gemm128<<<(Ns + 127) / 128, 256, 0, stream>>>(xsrc, w_s, hs, Ns);
        matvec128<<<(Ns + 3) / 4, 256, 0, stream>>>(xsrc, vs, asn, Ns);
        matvec128<<<(Nd + 3) / 4, 256, 0, stream>>>(xdst, vd, adn, Nd);
        hipMemsetAsync(den, 0, (size_t)Nd * sizeof(float), stream);
        edge_softmax_num<<<(E_ + 255) / 256, 256, 0, stream>>>(src, dst, asn, adn, ee, den, E_);
        init_bias<<<(Nd * 32 + 255) / 256, 256, 0, stream>>>(out, bias, Nd);
        edge_aggregate<<<(E_ + 3) / 4, 256, 0, stream>>>(src, dst, ee, den, hs, out, E_);
    };

    auto run_bn = [&](float* x, const float* g, const float* b, int N) {
        hipMemsetAsync(stat, 0, 256 * sizeof(float), stream);
        bn_stats<<<512, 256, 0, stream>>>(x, stat, N);
        bn_apply<<<(N * 32 + 255) / 256, 256, 0, stream>>>(x, stat, g, b, N, 1.0f / N);
    };

    // ---- layer 1 ----
    run_gat(x_user, x_food, uf_src, uf_dst, w1_uf_src, vall + 0,   vall + 128, b1_uf, xf1, NU_, NF_);
    run_gat(x_food, x_user, fu_src, fu_dst, w1_fu_src, vall + 256, vall + 384, b1_fu, xu1, NF_, NU_);
    run_bn(xu1, bn1_user_g, bn1_user_b, NU_);
    run_bn(xf1, bn1_food_g, bn1_food_b, NF_);

    // ---- layer 2 (aggregate straight into d_out regions) ----
    run_gat(xu1, xf1, uf_src, uf_dst, w2_uf_src, vall + 512, vall + 640, b2_uf, xf2, NU_, NF_);
    run_gat(xf1, xu1, fu_src, fu_dst, w2_fu_src, vall + 768, vall + 896, b2_fu, xu2, NF_, NU_);
    run_bn(xu2, bn2_user_g, bn2_user_b, NU_);
    run_bn(xf2, bn2_food_g, bn2_food_b, NF_);

    // ---- health preference MLP + scatter update ----
    mlp_pref<<<(NU_ + 3) / 4, 256, 0, stream>>>(xu2, hw1, hb1, hw2, hb2, prefs, NU_);
    hipMemsetAsync(sbuf, 0, (size_t)NF_ * sizeof(float), stream);
    health_scatter<<<(E_ + 255) / 256, 256, 0, stream>>>(he_user, he_food, scores, prefs, sbuf, E_);
    add_health<<<(NF_ * 32 + 255) / 256, 256, 0, stream>>>(xf2, sbuf, NF_ * 32);
}

// Round 2
// 1040.417 us; speedup vs baseline: 2.2996x; 2.2996x over previous
//
#include <hip/hip_runtime.h>
#include <cstddef>

#define NU_ 50000
#define NF_ 25000
#define E_  500000

// ---------------------------------------------------------------------------
// v = W @ a  (v[k] = sum_h W[k][h] * a[h]) for 8 (W,a) pairs, one block each.
// ---------------------------------------------------------------------------
struct WAArgs {
    const float* W[8];
    const float* a[8];
};

__global__ __launch_bounds__(256) void wa_vec(WAArgs args, float* __restrict__ vout) {
    __shared__ float Ws[128][129];
    __shared__ float as[128];
    const int b = blockIdx.x;
    const float* W = args.W[b];
    const float* a = args.a[b];
    for (int i = threadIdx.x; i < 128 * 32; i += 256) {
        float4 w = ((const float4*)W)[i];
        int r = i >> 5, c = (i & 31) << 2;
        Ws[r][c] = w.x; Ws[r][c + 1] = w.y; Ws[r][c + 2] = w.z; Ws[r][c + 3] = w.w;
    }
    if (threadIdx.x < 128) as[threadIdx.x] = a[threadIdx.x];
    __syncthreads();
    if (threadIdx.x < 128) {
        float s = 0.f;
        #pragma unroll 8
        for (int h = 0; h < 128; ++h) s += Ws[threadIdx.x][h] * as[h];
        vout[b * 128 + threadIdx.x] = s;
    }
}

// ---------------------------------------------------------------------------
// C[N,128] = X[N,128] @ W[128,128]  (fp32, single K-stage, 8x8 reg tile)
// ---------------------------------------------------------------------------
__global__ __launch_bounds__(256) void gemm128(const float* __restrict__ X,
                                               const float* __restrict__ W,
                                               float* __restrict__ C, int N) {
    __shared__ float Xs[128][129];
    __shared__ float Ws[128][128];
    const int t = threadIdx.x;
    const int row0 = blockIdx.x * 128;

    for (int i = t; i < 128 * 32; i += 256)
        ((float4*)(&Ws[0][0]))[i] = ((const float4*)W)[i];

    for (int i = t; i < 128 * 32; i += 256) {
        int r = i >> 5, c4 = (i & 31) << 2;
        int gr = row0 + r;
        float4 v = make_float4(0.f, 0.f, 0.f, 0.f);
        if (gr < N) v = ((const float4*)(X + (size_t)gr * 128))[i & 31];
        Xs[r][c4] = v.x; Xs[r][c4 + 1] = v.y; Xs[r][c4 + 2] = v.z; Xs[r][c4 + 3] = v.w;
    }
    __syncthreads();

    const int tr = (t >> 4) * 8;
    const int tc = (t & 15) * 8;
    float acc[8][8];
    #pragma unroll
    for (int i = 0; i < 8; ++i)
        #pragma unroll
        for (int j = 0; j < 8; ++j) acc[i][j] = 0.f;

    for (int k = 0; k < 128; ++k) {
        float xv[8];
        #pragma unroll
        for (int i = 0; i < 8; ++i) xv[i] = Xs[tr + i][k];
        float4 w0 = *(const float4*)&Ws[k][tc];
        float4 w1 = *(const float4*)&Ws[k][tc + 4];
        float wv[8] = {w0.x, w0.y, w0.z, w0.w, w1.x, w1.y, w1.z, w1.w};
        #pragma unroll
        for (int i = 0; i < 8; ++i)
            #pragma unroll
            for (int j = 0; j < 8; ++j) acc[i][j] += xv[i] * wv[j];
    }

    #pragma unroll
    for (int i = 0; i < 8; ++i) {
        int gr = row0 + tr + i;
        if (gr < N) {
            float4* cp = (float4*)(C + (size_t)gr * 128 + tc);
            cp[0] = make_float4(acc[i][0], acc[i][1], acc[i][2], acc[i][3]);
            cp[1] = make_float4(acc[i][4], acc[i][5], acc[i][6], acc[i][7]);
        }
    }
}

// ---------------------------------------------------------------------------
// out[n] = dot(X[n,:], v)   one wave per row
// ---------------------------------------------------------------------------
__global__ __launch_bounds__(256) void matvec128(const float* __restrict__ X,
                                                 const float* __restrict__ v,
                                                 float* __restrict__ out, int N) {
    int row = blockIdx.x * 4 + (threadIdx.x >> 6);
    int lane = threadIdx.x & 63;
    if (row >= N) return;
    float2 x = ((const float2*)(X + (size_t)row * 128))[lane];
    float2 vv = ((const float2*)v)[lane];
    float s = x.x * vv.x + x.y * vv.y;
    #pragma unroll
    for (int off = 32; off; off >>= 1) s += __shfl_xor(s, off);
    if (lane == 0) out[row] = s;
}

// ---------------------------------------------------------------------------
// CSR build: histogram -> exclusive scan -> cursor fill (src stored sorted)
// ---------------------------------------------------------------------------
__global__ void count_deg(const int* __restrict__ dst, int* __restrict__ deg, int E) {
    int e = blockIdx.x * 256 + threadIdx.x;
    if (e < E) atomicAdd(&deg[dst[e]], 1);
}

__global__ __launch_bounds__(1024) void scan_excl(const int* __restrict__ deg,
                                                  int* __restrict__ off,
                                                  int* __restrict__ cursor, int N) {
    __shared__ int part[1024];
    const int t = threadIdx.x;
    const int chunk = (N + 1023) / 1024;
    const int b = t * chunk;
    const int e = min(b + chunk, N);
    int s = 0;
    for (int i = b; i < e; ++i) s += deg[i];
    part[t] = s;
    __syncthreads();
    for (int d = 1; d < 1024; d <<= 1) {
        int v = (t >= d) ? part[t - d] : 0;
        __syncthreads();
        part[t] += v;
        __syncthreads();
    }
    int run = (t == 0) ? 0 : part[t - 1];
    for (int i = b; i < e; ++i) {
        off[i] = run; cursor[i] = run;
        run += deg[i];
    }
    if (t == 1023) off[N] = run;
}

__global__ void fill_csr(const int* __restrict__ src, const int* __restrict__ dst,
                         int* __restrict__ cursor, int* __restrict__ esrc, int E) {
    int e = blockIdx.x * 256 + threadIdx.x;
    if (e >= E) return;
    int p = atomicAdd(&cursor[dst[e]], 1);
    esrc[p] = src[e];
}

// ---------------------------------------------------------------------------
// Fused GAT softmax + aggregate, one wave per destination node (gather).
// out[d] = (sum_e ev_e * hs[src_e]) / (sum_e ev_e + 1e-16) + bias
// ev_e = exp(leaky_relu(asn[src_e] + adn[d], 0.2))  (segment-max cancels)
// ---------------------------------------------------------------------------
__global__ __launch_bounds__(256) void gat_aggregate_csr(const int* __restrict__ off,
                                                         const int* __restrict__ esrc,
                                                         const float* __restrict__ asn,
                                                         const float* __restrict__ adn,
                                                         const float* __restrict__ hs,
                                                         const float* __restrict__ bias,
                                                         float* __restrict__ out, int Nd) {
    int d = blockIdx.x * 4 + (threadIdx.x >> 6);
    int lane = threadIdx.x & 63;
    if (d >= Nd) return;
    const int beg = off[d], end = off[d + 1];
    const float ad = adn[d];
    float accx = 0.f, accy = 0.f, den = 0.f;
    for (int base = beg; base < end; base += 64) {
        int e = base + lane;
        int s = 0; float ev = 0.f;
        if (e < end) {
            s = esrc[e];
            float v = asn[s] + ad;
            v = v > 0.f ? v : 0.2f * v;
            ev = __expf(v);
        }
        float r = ev;
        #pragma unroll
        for (int o = 32; o; o >>= 1) r += __shfl_xor(r, o);
        den += r;
        int cnt = min(64, end - base);
        for (int j = 0; j < cnt; ++j) {
            float evj = __shfl(ev, j);
            int sj = __shfl(s, j);
            float2 h = ((const float2*)(hs + (size_t)sj * 128))[lane];
            accx += evj * h.x;
            accy += evj * h.y;
        }
    }
    float inv = 1.f / (den + 1e-16f);
    float2 b2 = ((const float2*)bias)[lane];
    ((float2*)(out + (size_t)d * 128))[lane] = make_float2(accx * inv + b2.x, accy * inv + b2.y);
}

// ---------------------------------------------------------------------------
// BatchNorm stats: stat[c]=sum, stat[128+c]=sumsq (column-wise over N rows)
// ---------------------------------------------------------------------------
__global__ void bn_stats(const float* __restrict__ x, float* __restrict__ stat, int N) {
    int c = threadIdx.x & 127;
    int h = threadIdx.x >> 7;
    float s = 0.f, q = 0.f;
    for (int r = blockIdx.x * 2 + h; r < N; r += gridDim.x * 2) {
        float v = x[(size_t)r * 128 + c];
        s += v; q += v * v;
    }
    atomicAdd(&stat[c], s);
    atomicAdd(&stat[128 + c], q);
}

__global__ void bn_apply(float* __restrict__ x, const float* __restrict__ stat,
                         const float* __restrict__ g, const float* __restrict__ b,
                         int N, float invN) {
    int i = blockIdx.x * 256 + threadIdx.x;
    if (i >= N * 32) return;
    int c4 = (i & 31) << 2;
    float4 v = ((float4*)x)[i];
    float* vp = &v.x;
    #pragma unroll
    for (int j = 0; j < 4; ++j) {
        int c = c4 + j;
        float mu = stat[c] * invN;
        float var = stat[128 + c] * invN - mu * mu;
        float xn = (vp[j] - mu) * rsqrtf(var + 1e-5f) * g[c] + b[c];
        vp[j] = xn > 0.f ? xn : expm1f(xn);
    }
    ((float4*)x)[i] = v;
}

// ---------------------------------------------------------------------------
// prefs[u] = tanh( leaky_relu(xu2[u]@hw1 + hb1, 0.01) @ hw2 + hb2 )
// ---------------------------------------------------------------------------
__global__ __launch_bounds__(256) void mlp_pref(const float* __restrict__ xu,
                                                const float* __restrict__ hw1,
                                                const float* __restrict__ hb1,
                                                const float* __restrict__ hw2,
                                                const float* __restrict__ hb2,
                                                float* __restrict__ prefs, int N) {
    __shared__ float xs[4][128];
    int w = threadIdx.x >> 6;
    int lane = threadIdx.x & 63;
    int u = blockIdx.x * 4 + w;
    if (u < N) {
        float2 xv = ((const float2*)(xu + (size_t)u * 128))[lane];
        xs[w][2 * lane] = xv.x;
        xs[w][2 * lane + 1] = xv.y;
    }
    __syncthreads();
    if (u >= N) return;
    float acc = 0.f;
    #pragma unroll 4
    for (int k = 0; k < 128; ++k) acc += xs[w][k] * hw1[k * 64 + lane];
    acc += hb1[lane];
    acc = acc > 0.f ? acc : 0.01f * acc;
    float p = acc * hw2[lane];
    #pragma unroll
    for (int off = 32; off; off >>= 1) p += __shfl_xor(p, off);
    if (lane == 0) prefs[u] = tanhf(p + hb2[0]);
}

// s[he_food[e]] += prefs[he_user[e]] * score[e]
__global__ void health_scatter(const int* __restrict__ hu, const int* __restrict__ hf,
                               const float* __restrict__ score, const float* __restrict__ prefs,
                               float* __restrict__ s, int E) {
    int e = blockIdx.x * 256 + threadIdx.x;
    if (e >= E) return;
    atomicAdd(&s[hf[e]], prefs[hu[e]] * score[e]);
}

// xf2[f][c] += 0.1 * s[f]
__global__ void add_health(float* __restrict__ xf2, const float* __restrict__ s, int n4) {
    int i = blockIdx.x * 256 + threadIdx.x;
    if (i >= n4) return;
    float sv = 0.1f * s[i >> 5];
    float4 v = ((float4*)xf2)[i];
    v.x += sv; v.y += sv; v.z += sv; v.w += sv;
    ((float4*)xf2)[i] = v;
}

// ---------------------------------------------------------------------------
extern "C" void kernel_launch(void* const* d_in, const int* in_sizes, int n_in,
                              void* d_out, int out_size, void* d_ws, size_t ws_size,
                              hipStream_t stream) {
    const float* x_user = (const float*)d_in[0];
    const float* x_food = (const float*)d_in[1];
    const int* uf_src = (const int*)d_in[2];
    const int* uf_dst = (const int*)d_in[3];
    const int* fu_src = (const int*)d_in[4];
    const int* fu_dst = (const int*)d_in[5];
    const int* he_user = (const int*)d_in[6];
    const int* he_food = (const int*)d_in[7];
    const float* scores = (const float*)d_in[8];
    const float* w1_uf_src = (const float*)d_in[9];
    const float* a1_uf_src = (const float*)d_in[11];
    const float* a1_uf_dst = (const float*)d_in[12];
    const float* b1_uf     = (const float*)d_in[13];
    const float* w1_fu_src = (const float*)d_in[14];
    const float* a1_fu_src = (const float*)d_in[16];
    const float* a1_fu_dst = (const float*)d_in[17];
    const float* b1_fu     = (const float*)d_in[18];
    const float* w2_uf_src = (const float*)d_in[19];
    const float* a2_uf_src = (const float*)d_in[21];
    const float* a2_uf_dst = (const float*)d_in[22];
    const float* b2_uf     = (const float*)d_in[23];
    const float* w2_fu_src = (const float*)d_in[24];
    const float* a2_fu_src = (const float*)d_in[26];
    const float* a2_fu_dst = (const float*)d_in[27];
    const float* b2_fu     = (const float*)d_in[28];
    const float* bn1_user_g = (const float*)d_in[29];
    const float* bn1_user_b = (const float*)d_in[30];
    const float* bn1_food_g = (const float*)d_in[31];
    const float* bn1_food_b = (const float*)d_in[32];
    const float* bn2_user_g = (const float*)d_in[33];
    const float* bn2_user_b = (const float*)d_in[34];
    const float* bn2_food_g = (const float*)d_in[35];
    const float* bn2_food_b = (const float*)d_in[36];
    const float* hw1 = (const float*)d_in[37];
    const float* hb1 = (const float*)d_in[38];
    const float* hw2 = (const float*)d_in[39];
    const float* hb2 = (const float*)d_in[40];

    float* outp  = (float*)d_out;
    float* xu2   = outp;                          // [NU,128]
    float* xf2   = outp + (size_t)NU_ * 128;      // [NF,128]
    float* prefs = xf2 + (size_t)NF_ * 128;       // [NU]

    float* ws   = (float*)d_ws;
    float* hs   = ws;                             // NU*128
    float* xu1  = hs  + (size_t)NU_ * 128;        // NU*128
    float* xf1  = xu1 + (size_t)NU_ * 128;        // NF*128
    float* asn  = xf1 + (size_t)NF_ * 128;        // NU
    float* adn  = asn + NU_;                      // NU
    float* sbuf = adn + NU_;                      // NF
    float* stat = sbuf + NF_;                     // 256
    float* vall = stat + 256;                     // 8*128
    int* uf_off  = (int*)(vall + 1024);           // NF+1
    int* fu_off  = uf_off + (NF_ + 1);            // NU+1
    int* deg     = fu_off + (NU_ + 1);            // max(NU,NF)
    int* cursor  = deg + NU_;                     // max(NU,NF)
    int* uf_esrc = cursor + NU_;                  // E
    int* fu_esrc = uf_esrc + E_;                  // E

    // --- precompute v = W@a for all 8 (dst-side GEMMs eliminated) ---
    WAArgs wa;
    wa.W[0] = (const float*)d_in[9];  wa.a[0] = a1_uf_src;
    wa.W[1] = (const float*)d_in[10]; wa.a[1] = a1_uf_dst;
    wa.W[2] = (const float*)d_in[14]; wa.a[2] = a1_fu_src;
    wa.W[3] = (const float*)d_in[15]; wa.a[3] = a1_fu_dst;
    wa.W[4] = (const float*)d_in[19]; wa.a[4] = a2_uf_src;
    wa.W[5] = (const float*)d_in[20]; wa.a[5] = a2_uf_dst;
    wa.W[6] = (const float*)d_in[24]; wa.a[6] = a2_fu_src;
    wa.W[7] = (const float*)d_in[25]; wa.a[7] = a2_fu_dst;
    wa_vec<<<8, 256, 0, stream>>>(wa, vall);

    // --- build CSR once per edge type (reused by both layers) ---
    const int EB = (E_ + 255) / 256;
    hipMemsetAsync(deg, 0, (size_t)NF_ * sizeof(int), stream);
    count_deg<<<EB, 256, 0, stream>>>(uf_dst, deg, E_);
    scan_excl<<<1, 1024, 0, stream>>>(deg, uf_off, cursor, NF_);
    fill_csr<<<EB, 256, 0, stream>>>(uf_src, uf_dst, cursor, uf_esrc, E_);

    hipMemsetAsync(deg, 0, (size_t)NU_ * sizeof(int), stream);
    count_deg<<<EB, 256, 0, stream>>>(fu_dst, deg, E_);
    scan_excl<<<1, 1024, 0, stream>>>(deg, fu_off, cursor, NU_);
    fill_csr<<<EB, 256, 0, stream>>>(fu_src, fu_dst, cursor, fu_esrc, E_);

    auto run_gat = [&](const float* xsrc, const float* xdst,
                       const int* off, const int* esrc,
                       const float* w_s, const float* vs, const float* vd, const float* bias,
                       float* out, int Ns, int Nd) {
        gemm128<<<(Ns + 127) / 128, 256, 0, stream>>>(xsrc, w_s, hs, Ns);
        matvec128<<<(Ns + 3) / 4, 256, 0, stream>>>(xsrc, vs, asn, Ns);
        matvec128<<<(Nd + 3) / 4, 256, 0, stream>>>(xdst, vd, adn, Nd);
        gat_aggregate_csr<<<(Nd + 3) / 4, 256, 0, stream>>>(off, esrc, asn, adn, hs, bias, out, Nd);
    };

    auto run_bn = [&](float* x, const float* g, const float* b, int N) {
        hipMemsetAsync(stat, 0, 256 * sizeof(float), stream);
        bn_stats<<<512, 256, 0, stream>>>(x, stat, N);
        bn_apply<<<(N * 32 + 255) / 256, 256, 0, stream>>>(x, stat, g, b, N, 1.0f / N);
    };

    // ---- layer 1 ----
    run_gat(x_user, x_food, uf_off, uf_esrc, w1_uf_src, vall + 0,   vall + 128, b1_uf, xf1, NU_, NF_);
    run_gat(x_food, x_user, fu_off, fu_esrc, w1_fu_src, vall + 256, vall + 384, b1_fu, xu1, NF_, NU_);
    run_bn(xu1, bn1_user_g, bn1_user_b, NU_);
    run_bn(xf1, bn1_food_g, bn1_food_b, NF_);

    // ---- layer 2 (aggregate straight into d_out regions) ----
    run_gat(xu1, xf1, uf_off, uf_esrc, w2_uf_src, vall + 512, vall + 640, b2_uf, xf2, NU_, NF_);
    run_gat(xf1, xu1, fu_off, fu_esrc, w2_fu_src, vall + 768, vall + 896, b2_fu, xu2, NF_, NU_);
    run_bn(xu2, bn2_user_g, bn2_user_b, NU_);
    run_bn(xf2, bn2_food_g, bn2_food_b, NF_);

    // ---- health preference MLP + scatter update ----
    mlp_pref<<<(NU_ + 3) / 4, 256, 0, stream>>>(xu2, hw1, hb1, hw2, hb2, prefs, NU_);
    hipMemsetAsync(sbuf, 0, (size_t)NF_ * sizeof(float), stream);
    health_scatter<<<(E_ + 255) / 256, 256, 0, stream>>>(he_user, he_food, scores, prefs, sbuf, E_);
    add_health<<<(NF_ * 32 + 255) / 256, 256, 0, stream>>>(xf2, sbuf, NF_ * 32);
}

// Round 3
// 812.002 us; speedup vs baseline: 2.9465x; 1.2813x over previous
//
#include <hip/hip_runtime.h>
#include <cstddef>

#define NU_ 50000
#define NF_ 25000
#define E_  500000

// ---------------------------------------------------------------------------
// v = W @ a  (v[k] = sum_h W[k][h] * a[h]) for 8 (W,a) pairs, one block each.
// ---------------------------------------------------------------------------
struct WAArgs {
    const float* W[8];
    const float* a[8];
};

__global__ __launch_bounds__(256) void wa_vec(WAArgs args, float* __restrict__ vout) {
    __shared__ float Ws[128][129];
    __shared__ float as[128];
    const int b = blockIdx.x;
    const float* W = args.W[b];
    const float* a = args.a[b];
    for (int i = threadIdx.x; i < 128 * 32; i += 256) {
        float4 w = ((const float4*)W)[i];
        int r = i >> 5, c = (i & 31) << 2;
        Ws[r][c] = w.x; Ws[r][c + 1] = w.y; Ws[r][c + 2] = w.z; Ws[r][c + 3] = w.w;
    }
    if (threadIdx.x < 128) as[threadIdx.x] = a[threadIdx.x];
    __syncthreads();
    if (threadIdx.x < 128) {
        float s = 0.f;
        #pragma unroll 8
        for (int h = 0; h < 128; ++h) s += Ws[threadIdx.x][h] * as[h];
        vout[b * 128 + threadIdx.x] = s;
    }
}

// ---------------------------------------------------------------------------
// C[N,128] = X[N,128] @ W[128,128]  (fp32, single K-stage, 8x8 reg tile)
// ---------------------------------------------------------------------------
__global__ __launch_bounds__(256) void gemm128(const float* __restrict__ X,
                                               const float* __restrict__ W,
                                               float* __restrict__ C, int N) {
    __shared__ float Xs[128][129];
    __shared__ float Ws[128][128];
    const int t = threadIdx.x;
    const int row0 = blockIdx.x * 128;

    for (int i = t; i < 128 * 32; i += 256)
        ((float4*)(&Ws[0][0]))[i] = ((const float4*)W)[i];

    for (int i = t; i < 128 * 32; i += 256) {
        int r = i >> 5, c4 = (i & 31) << 2;
        int gr = row0 + r;
        float4 v = make_float4(0.f, 0.f, 0.f, 0.f);
        if (gr < N) v = ((const float4*)(X + (size_t)gr * 128))[i & 31];
        Xs[r][c4] = v.x; Xs[r][c4 + 1] = v.y; Xs[r][c4 + 2] = v.z; Xs[r][c4 + 3] = v.w;
    }
    __syncthreads();

    const int tr = (t >> 4) * 8;
    const int tc = (t & 15) * 8;
    float acc[8][8];
    #pragma unroll
    for (int i = 0; i < 8; ++i)
        #pragma unroll
        for (int j = 0; j < 8; ++j) acc[i][j] = 0.f;

    for (int k = 0; k < 128; ++k) {
        float xv[8];
        #pragma unroll
        for (int i = 0; i < 8; ++i) xv[i] = Xs[tr + i][k];
        float4 w0 = *(const float4*)&Ws[k][tc];
        float4 w1 = *(const float4*)&Ws[k][tc + 4];
        float wv[8] = {w0.x, w0.y, w0.z, w0.w, w1.x, w1.y, w1.z, w1.w};
        #pragma unroll
        for (int i = 0; i < 8; ++i)
            #pragma unroll
            for (int j = 0; j < 8; ++j) acc[i][j] += xv[i] * wv[j];
    }

    #pragma unroll
    for (int i = 0; i < 8; ++i) {
        int gr = row0 + tr + i;
        if (gr < N) {
            float4* cp = (float4*)(C + (size_t)gr * 128 + tc);
            cp[0] = make_float4(acc[i][0], acc[i][1], acc[i][2], acc[i][3]);
            cp[1] = make_float4(acc[i][4], acc[i][5], acc[i][6], acc[i][7]);
        }
    }
}

// ---------------------------------------------------------------------------
// Fused pair of matvecs: rows [0,Ns) -> outs = Xs@vs ; rows [Ns,Ns+Nd) -> outd
// ---------------------------------------------------------------------------
__global__ __launch_bounds__(256) void matvec128x2(const float* __restrict__ Xsp, const float* __restrict__ vs,
                                                   float* __restrict__ outs, int Ns,
                                                   const float* __restrict__ Xdp, const float* __restrict__ vd,
                                                   float* __restrict__ outd, int Nd) {
    int row = blockIdx.x * 4 + (threadIdx.x >> 6);
    int lane = threadIdx.x & 63;
    const float* X; const float* v; float* out; int r;
    if (row < Ns) { X = Xsp; v = vs; out = outs; r = row; }
    else {
        r = row - Ns;
        if (r >= Nd) return;
        X = Xdp; v = vd; out = outd;
    }
    float2 x = ((const float2*)(X + (size_t)r * 128))[lane];
    float2 vv = ((const float2*)v)[lane];
    float s = x.x * vv.x + x.y * vv.y;
    #pragma unroll
    for (int off = 32; off; off >>= 1) s += __shfl_xor(s, off);
    if (lane == 0) out[r] = s;
}

// ---------------------------------------------------------------------------
// CSR build: histogram -> multi-block exclusive scan -> cursor fill
// ---------------------------------------------------------------------------
__global__ void count_deg(const int* __restrict__ dst, int* __restrict__ deg, int E) {
    int e = blockIdx.x * 256 + threadIdx.x;
    if (e < E) atomicAdd(&deg[dst[e]], 1);
}

// part[b] = sum(deg[b*1024 .. b*1024+1023])
__global__ __launch_bounds__(256) void partial_sums(const int* __restrict__ deg,
                                                    int* __restrict__ part, int N) {
    __shared__ int wsum[4];
    int base = blockIdx.x * 1024;
    int s = 0;
    for (int i = threadIdx.x; i < 1024; i += 256) {
        int idx = base + i;
        if (idx < N) s += deg[idx];
    }
    #pragma unroll
    for (int o = 32; o; o >>= 1) s += __shfl_xor(s, o);
    if ((threadIdx.x & 63) == 0) wsum[threadIdx.x >> 6] = s;
    __syncthreads();
    if (threadIdx.x == 0) part[blockIdx.x] = wsum[0] + wsum[1] + wsum[2] + wsum[3];
}

// one wave scans <=64 partials in place (exclusive); writes off[N] = total
__global__ __launch_bounds__(64) void scan_partials(int* __restrict__ part,
                                                    int* __restrict__ offN, int nb) {
    int lane = threadIdx.x;
    int v = (lane < nb) ? part[lane] : 0;
    int incl = v;
    #pragma unroll
    for (int o = 1; o < 64; o <<= 1) {
        int t = __shfl_up(incl, o);
        if (lane >= o) incl += t;
    }
    if (lane < nb) part[lane] = incl - v;
    if (lane == 63) *offN = incl;
}

// per-chunk scan: off[i] = part[b] + prefix within chunk; cursor = copy
__global__ __launch_bounds__(256) void block_scan(const int* __restrict__ deg,
                                                  const int* __restrict__ part,
                                                  int* __restrict__ off,
                                                  int* __restrict__ cursor, int N) {
    __shared__ int wsum[4];
    int t = threadIdx.x;
    int lane = t & 63, w = t >> 6;
    int base = blockIdx.x * 1024 + t * 4;
    int l0 = 0, l1 = 0, l2 = 0, l3 = 0;
    if (base + 3 < N) {
        int4 v = *(const int4*)(deg + base);
        l0 = v.x; l1 = v.y; l2 = v.z; l3 = v.w;
    } else {
        if (base + 0 < N) l0 = deg[base + 0];
        if (base + 1 < N) l1 = deg[base + 1];
        if (base + 2 < N) l2 = deg[base + 2];
    }
    int tsum = l0 + l1 + l2 + l3;
    int incl = tsum;
    #pragma unroll
    for (int o = 1; o < 64; o <<= 1) {
        int tt = __shfl_up(incl, o);
        if (lane >= o) incl += tt;
    }
    int lexcl = incl - tsum;
    if (lane == 63) wsum[w] = incl;
    __syncthreads();
    int p = part[blockIdx.x] + lexcl;
    for (int i = 0; i < w; ++i) p += wsum[i];
    if (base + 0 < N) { off[base + 0] = p; cursor[base + 0] = p; } p += l0;
    if (base + 1 < N) { off[base + 1] = p; cursor[base + 1] = p; } p += l1;
    if (base + 2 < N) { off[base + 2] = p; cursor[base + 2] = p; } p += l2;
    if (base + 3 < N) { off[base + 3] = p; cursor[base + 3] = p; }
}

__global__ void fill_csr(const int* __restrict__ src, const int* __restrict__ dst,
                         int* __restrict__ cursor, int* __restrict__ esrc, int E) {
    int e = blockIdx.x * 256 + threadIdx.x;
    if (e >= E) return;
    int p = atomicAdd(&cursor[dst[e]], 1);
    esrc[p] = src[e];
}

// ---------------------------------------------------------------------------
// Fused GAT softmax + aggregate, one wave per destination node (gather).
// out[d] = (sum_e ev_e * hs[src_e]) / (sum_e ev_e + 1e-16) + bias
// ev_e = exp(leaky_relu(asn[src_e] + adn[d], 0.2))  (segment-max cancels)
// ---------------------------------------------------------------------------
__global__ __launch_bounds__(256) void gat_aggregate_csr(const int* __restrict__ off,
                                                         const int* __restrict__ esrc,
                                                         const float* __restrict__ asn,
                                                         const float* __restrict__ adn,
                                                         const float* __restrict__ hs,
                                                         const float* __restrict__ bias,
                                                         float* __restrict__ out, int Nd) {
    int d = blockIdx.x * 4 + (threadIdx.x >> 6);
    int lane = threadIdx.x & 63;
    if (d >= Nd) return;
    const int beg = off[d], end = off[d + 1];
    const float ad = adn[d];
    float accx = 0.f, accy = 0.f, den = 0.f;
    for (int base = beg; base < end; base += 64) {
        int e = base + lane;
        int s = 0; float ev = 0.f;     // invalid lanes: ev=0, s=0 (harmless row-0 load)
        if (e < end) {
            s = esrc[e];
            float v = asn[s] + ad;
            v = v > 0.f ? v : 0.2f * v;
            ev = __expf(v);
        }
        float r = ev;
        #pragma unroll
        for (int o = 32; o; o >>= 1) r += __shfl_xor(r, o);
        den += r;
        int cnt4 = (min(64, end - base) + 3) & ~3;
        for (int j = 0; j < cnt4; j += 4) {
            float e0 = __shfl(ev, j),     e1 = __shfl(ev, j + 1);
            float e2 = __shfl(ev, j + 2), e3 = __shfl(ev, j + 3);
            int   s0 = __shfl(s, j),      s1 = __shfl(s, j + 1);
            int   s2 = __shfl(s, j + 2),  s3 = __shfl(s, j + 3);
            float2 h0 = ((const float2*)(hs + (size_t)s0 * 128))[lane];
            float2 h1 = ((const float2*)(hs + (size_t)s1 * 128))[lane];
            float2 h2 = ((const float2*)(hs + (size_t)s2 * 128))[lane];
            float2 h3 = ((const float2*)(hs + (size_t)s3 * 128))[lane];
            accx += e0 * h0.x; accy += e0 * h0.y;
            accx += e1 * h1.x; accy += e1 * h1.y;
            accx += e2 * h2.x; accy += e2 * h2.y;
            accx += e3 * h3.x; accy += e3 * h3.y;
        }
    }
    float inv = 1.f / (den + 1e-16f);
    float2 b2 = ((const float2*)bias)[lane];
    ((float2*)(out + (size_t)d * 128))[lane] = make_float2(accx * inv + b2.x, accy * inv + b2.y);
}

// ---------------------------------------------------------------------------
// BatchNorm stats: stat[c]=sum, stat[128+c]=sumsq (column-wise over N rows)
// ---------------------------------------------------------------------------
__global__ void bn_stats(const float* __restrict__ x, float* __restrict__ stat, int N) {
    int c = threadIdx.x & 127;
    int h = threadIdx.x >> 7;
    float s = 0.f, q = 0.f;
    for (int r = blockIdx.x * 2 + h; r < N; r += gridDim.x * 2) {
        float v = x[(size_t)r * 128 + c];
        s += v; q += v * v;
    }
    atomicAdd(&stat[c], s);
    atomicAdd(&stat[128 + c], q);
}

__global__ void bn_apply(float* __restrict__ x, const float* __restrict__ stat,
                         const float* __restrict__ g, const float* __restrict__ b,
                         int N, float invN) {
    int i = blockIdx.x * 256 + threadIdx.x;
    if (i >= N * 32) return;
    int c4 = (i & 31) << 2;
    float4 v = ((float4*)x)[i];
    float* vp = &v.x;
    #pragma unroll
    for (int j = 0; j < 4; ++j) {
        int c = c4 + j;
        float mu = stat[c] * invN;
        float var = stat[128 + c] * invN - mu * mu;
        float xn = (vp[j] - mu) * rsqrtf(var + 1e-5f) * g[c] + b[c];
        vp[j] = xn > 0.f ? xn : expm1f(xn);
    }
    ((float4*)x)[i] = v;
}

// ---------------------------------------------------------------------------
// prefs[u] = tanh( leaky_relu(xu2[u]@hw1 + hb1, 0.01) @ hw2 + hb2 )
// ---------------------------------------------------------------------------
__global__ __launch_bounds__(256) void mlp_pref(const float* __restrict__ xu,
                                                const float* __restrict__ hw1,
                                                const float* __restrict__ hb1,
                                                const float* __restrict__ hw2,
                                                const float* __restrict__ hb2,
                                                float* __restrict__ prefs, int N) {
    __shared__ float xs[4][128];
    int w = threadIdx.x >> 6;
    int lane = threadIdx.x & 63;
    int u = blockIdx.x * 4 + w;
    if (u < N) {
        float2 xv = ((const float2*)(xu + (size_t)u * 128))[lane];
        xs[w][2 * lane] = xv.x;
        xs[w][2 * lane + 1] = xv.y;
    }
    __syncthreads();
    if (u >= N) return;
    float acc = 0.f;
    #pragma unroll 4
    for (int k = 0; k < 128; ++k) acc += xs[w][k] * hw1[k * 64 + lane];
    acc += hb1[lane];
    acc = acc > 0.f ? acc : 0.01f * acc;
    float p = acc * hw2[lane];
    #pragma unroll
    for (int off = 32; off; off >>= 1) p += __shfl_xor(p, off);
    if (lane == 0) prefs[u] = tanhf(p + hb2[0]);
}

// s[he_food[e]] += prefs[he_user[e]] * score[e]
__global__ void health_scatter(const int* __restrict__ hu, const int* __restrict__ hf,
                               const float* __restrict__ score, const float* __restrict__ prefs,
                               float* __restrict__ s, int E) {
    int e = blockIdx.x * 256 + threadIdx.x;
    if (e >= E) return;
    atomicAdd(&s[hf[e]], prefs[hu[e]] * score[e]);
}

// xf2[f][c] += 0.1 * s[f]
__global__ void add_health(float* __restrict__ xf2, const float* __restrict__ s, int n4) {
    int i = blockIdx.x * 256 + threadIdx.x;
    if (i >= n4) return;
    float sv = 0.1f * s[i >> 5];
    float4 v = ((float4*)xf2)[i];
    v.x += sv; v.y += sv; v.z += sv; v.w += sv;
    ((float4*)xf2)[i] = v;
}

// ---------------------------------------------------------------------------
extern "C" void kernel_launch(void* const* d_in, const int* in_sizes, int n_in,
                              void* d_out, int out_size, void* d_ws, size_t ws_size,
                              hipStream_t stream) {
    const float* x_user = (const float*)d_in[0];
    const float* x_food = (const float*)d_in[1];
    const int* uf_src = (const int*)d_in[2];
    const int* uf_dst = (const int*)d_in[3];
    const int* fu_src = (const int*)d_in[4];
    const int* fu_dst = (const int*)d_in[5];
    const int* he_user = (const int*)d_in[6];
    const int* he_food = (const int*)d_in[7];
    const float* scores = (const float*)d_in[8];
    const float* a1_uf_src = (const float*)d_in[11];
    const float* a1_uf_dst = (const float*)d_in[12];
    const float* b1_uf     = (const float*)d_in[13];
    const float* a1_fu_src = (const float*)d_in[16];
    const float* a1_fu_dst = (const float*)d_in[17];
    const float* b1_fu     = (const float*)d_in[18];
    const float* b2_uf     = (const float*)d_in[23];
    const float* b2_fu     = (const float*)d_in[28];
    const float* w1_uf_src = (const float*)d_in[9];
    const float* w1_fu_src = (const float*)d_in[14];
    const float* w2_uf_src = (const float*)d_in[19];
    const float* w2_fu_src = (const float*)d_in[24];
    const float* bn1_user_g = (const float*)d_in[29];
    const float* bn1_user_b = (const float*)d_in[30];
    const float* bn1_food_g = (const float*)d_in[31];
    const float* bn1_food_b = (const float*)d_in[32];
    const float* bn2_user_g = (const float*)d_in[33];
    const float* bn2_user_b = (const float*)d_in[34];
    const float* bn2_food_g = (const float*)d_in[35];
    const float* bn2_food_b = (const float*)d_in[36];
    const float* hw1 = (const float*)d_in[37];
    const float* hb1 = (const float*)d_in[38];
    const float* hw2 = (const float*)d_in[39];
    const float* hb2 = (const float*)d_in[40];

    float* outp  = (float*)d_out;
    float* xu2   = outp;                          // [NU,128]
    float* xf2   = outp + (size_t)NU_ * 128;      // [NF,128]
    float* prefs = xf2 + (size_t)NF_ * 128;       // [NU]

    // ---- workspace layout (all segment sizes multiples of 4 elements) ----
    float* ws    = (float*)d_ws;
    float* hs    = ws;                             // NU*128
    float* xu1   = hs   + (size_t)NU_ * 128;       // NU*128
    float* xf1   = xu1  + (size_t)NU_ * 128;       // NF*128
    float* asn   = xf1  + (size_t)NF_ * 128;       // NU
    float* adn   = asn  + NU_;                     // NU
    // --- zeroed-once region start ---
    float* stat4 = adn  + NU_;                     // 4*256 (one per BN instance)
    float* sbuf  = stat4 + 1024;                   // NF
    int*   deg_f = (int*)(sbuf + NF_);             // NF (16B aligned)
    int*   deg_u = deg_f + NF_;                    // NU
    // --- zeroed-once region end (1024+NF+NF+NU floats) ---
    float* vall  = (float*)(deg_u + NU_);          // 8*128
    int*   part  = (int*)(vall + 1024);            // 64
    int*   uf_off  = part + 64;                    // NF+4
    int*   fu_off  = uf_off + (NF_ + 4);           // NU+4
    int*   cursor  = fu_off + (NU_ + 4);           // NU (max)
    int*   uf_esrc = cursor + NU_;                 // E
    int*   fu_esrc = uf_esrc + E_;                 // E

    const size_t zero_elems = 1024 + NF_ + NF_ + NU_;
    hipMemsetAsync(stat4, 0, zero_elems * sizeof(float), stream);

    // --- precompute v = W@a for all 8 (dst-side GEMMs eliminated) ---
    WAArgs wa;
    wa.W[0] = (const float*)d_in[9];  wa.a[0] = a1_uf_src;
    wa.W[1] = (const float*)d_in[10]; wa.a[1] = a1_uf_dst;
    wa.W[2] = (const float*)d_in[14]; wa.a[2] = a1_fu_src;
    wa.W[3] = (const float*)d_in[15]; wa.a[3] = a1_fu_dst;
    wa.W[4] = (const float*)d_in[19]; wa.a[4] = (const float*)d_in[21];
    wa.W[5] = (const float*)d_in[20]; wa.a[5] = (const float*)d_in[22];
    wa.W[6] = (const float*)d_in[24]; wa.a[6] = (const float*)d_in[26];
    wa.W[7] = (const float*)d_in[25]; wa.a[7] = (const float*)d_in[27];
    wa_vec<<<8, 256, 0, stream>>>(wa, vall);

    // --- build CSR once per edge type (reused by both layers) ---
    const int EB = (E_ + 255) / 256;
    const int NBF = (NF_ + 1023) / 1024;   // 25
    const int NBU = (NU_ + 1023) / 1024;   // 49

    count_deg<<<EB, 256, 0, stream>>>(uf_dst, deg_f, E_);
    partial_sums<<<NBF, 256, 0, stream>>>(deg_f, part, NF_);
    scan_partials<<<1, 64, 0, stream>>>(part, &uf_off[NF_], NBF);
    block_scan<<<NBF, 256, 0, stream>>>(deg_f, part, uf_off, cursor, NF_);
    fill_csr<<<EB, 256, 0, stream>>>(uf_src, uf_dst, cursor, uf_esrc, E_);

    count_deg<<<EB, 256, 0, stream>>>(fu_dst, deg_u, E_);
    partial_sums<<<NBU, 256, 0, stream>>>(deg_u, part, NU_);
    scan_partials<<<1, 64, 0, stream>>>(part, &fu_off[NU_], NBU);
    block_scan<<<NBU, 256, 0, stream>>>(deg_u, part, fu_off, cursor, NU_);
    fill_csr<<<EB, 256, 0, stream>>>(fu_src, fu_dst, cursor, fu_esrc, E_);

    auto run_gat = [&](const float* xsrc, const float* xdst,
                       const int* off, const int* esrc,
                       const float* w_s, const float* vs, const float* vd, const float* bias,
                       float* out, int Ns, int Nd) {
        gemm128<<<(Ns + 127) / 128, 256, 0, stream>>>(xsrc, w_s, hs, Ns);
        matvec128x2<<<(Ns + Nd + 3) / 4, 256, 0, stream>>>(xsrc, vs, asn, Ns, xdst, vd, adn, Nd);
        gat_aggregate_csr<<<(Nd + 3) / 4, 256, 0, stream>>>(off, esrc, asn, adn, hs, bias, out, Nd);
    };

    auto run_bn = [&](float* x, float* stat, const float* g, const float* b, int N) {
        bn_stats<<<512, 256, 0, stream>>>(x, stat, N);
        bn_apply<<<(N * 32 + 255) / 256, 256, 0, stream>>>(x, stat, g, b, N, 1.0f / N);
    };

    // ---- layer 1 ----
    run_gat(x_user, x_food, uf_off, uf_esrc, w1_uf_src, vall + 0,   vall + 128, b1_uf, xf1, NU_, NF_);
    run_gat(x_food, x_user, fu_off, fu_esrc, w1_fu_src, vall + 256, vall + 384, b1_fu, xu1, NF_, NU_);
    run_bn(xu1, stat4 + 0,   bn1_user_g, bn1_user_b, NU_);
    run_bn(xf1, stat4 + 256, bn1_food_g, bn1_food_b, NF_);

    // ---- layer 2 (aggregate straight into d_out regions) ----
    run_gat(xu1, xf1, uf_off, uf_esrc, w2_uf_src, vall + 512, vall + 640, b2_uf, xf2, NU_, NF_);
    run_gat(xf1, xu1, fu_off, fu_esrc, w2_fu_src, vall + 768, vall + 896, b2_fu, xu2, NF_, NU_);
    run_bn(xu2, stat4 + 512, bn2_user_g, bn2_user_b, NU_);
    run_bn(xf2, stat4 + 768, bn2_food_g, bn2_food_b, NF_);

    // ---- health preference MLP + scatter update ----
    mlp_pref<<<(NU_ + 3) / 4, 256, 0, stream>>>(xu2, hw1, hb1, hw2, hb2, prefs, NU_);
    health_scatter<<<EB, 256, 0, stream>>>(he_user, he_food, scores, prefs, sbuf, E_);
    add_health<<<(NF_ * 32 + 255) / 256, 256, 0, stream>>>(xf2, sbuf, NF_ * 32);
}

// Round 4
// 665.626 us; speedup vs baseline: 3.5944x; 1.2199x over previous
//
#include <hip/hip_runtime.h>
#include <cstddef>

#define NU_ 50000
#define NF_ 25000
#define E_  500000

typedef __attribute__((ext_vector_type(8))) short short8v;
typedef __attribute__((ext_vector_type(4))) float float4v;

static __device__ __forceinline__ ushort f2bf(float f) {
    uint u = __float_as_uint(f);
    uint r = (u + 0x7fffu + ((u >> 16) & 1u)) >> 16;   // RNE
    return (ushort)r;
}

// ---------------------------------------------------------------------------
// v = W @ a  (v[k] = sum_h W[k][h] * a[h]) for 8 (W,a) pairs, one block each.
// ---------------------------------------------------------------------------
struct WAArgs {
    const float* W[8];
    const float* a[8];
};

__global__ __launch_bounds__(256) void wa_vec(WAArgs args, float* __restrict__ vout) {
    __shared__ float Ws[128][129];
    __shared__ float as[128];
    const int b = blockIdx.x;
    const float* W = args.W[b];
    const float* a = args.a[b];
    for (int i = threadIdx.x; i < 128 * 32; i += 256) {
        float4 w = ((const float4*)W)[i];
        int r = i >> 5, c = (i & 31) << 2;
        Ws[r][c] = w.x; Ws[r][c + 1] = w.y; Ws[r][c + 2] = w.z; Ws[r][c + 3] = w.w;
    }
    if (threadIdx.x < 128) as[threadIdx.x] = a[threadIdx.x];
    __syncthreads();
    if (threadIdx.x < 128) {
        float s = 0.f;
        #pragma unroll 8
        for (int h = 0; h < 128; ++h) s += Ws[threadIdx.x][h] * as[h];
        vout[b * 128 + threadIdx.x] = s;
    }
}

// ---------------------------------------------------------------------------
// fp32 -> bf16 bulk convert (activations), float4 -> ushort4
// ---------------------------------------------------------------------------
__global__ void f2b_rows(const float* __restrict__ src, ushort* __restrict__ dst, int n4) {
    int i = blockIdx.x * 256 + threadIdx.x;
    if (i >= n4) return;
    float4 v = ((const float4*)src)[i];
    ushort4 o;
    o.x = f2bf(v.x); o.y = f2bf(v.y); o.z = f2bf(v.z); o.w = f2bf(v.w);
    ((ushort4*)dst)[i] = o;
}

// ---------------------------------------------------------------------------
// Weight convert: Wt[c][k] = bf16(W[k][c]); 5 matrices in one launch (grid.y)
// ---------------------------------------------------------------------------
struct WTArgs {
    const float* W[5];
    ushort* T[5];
    int shift[5];   // log2(ncols)
};

__global__ void wt_conv(WTArgs args) {
    const int m = blockIdx.y;
    const float* W = args.W[m];
    ushort* T = args.T[m];
    const int sh = args.shift[m];
    const int ncols = 1 << sh;
    const int total = 128 << sh;
    int idx = blockIdx.x * 256 + threadIdx.x;
    if (idx >= total) return;
    int k = idx >> sh, c = idx & (ncols - 1);
    T[c * 128 + k] = f2bf(W[idx]);
}

// ---------------------------------------------------------------------------
// C[N,NCOLS] fp32 = Xb[N,128] bf16 @ W[128,NCOLS] bf16 (Wt = transposed bf16)
// MFMA 16x16x32, 128-row tile, K=128 single-shot, 4 waves.
// LDS rows padded to 136 bf16 so 16-row frag reads are ~conflict-free.
// ---------------------------------------------------------------------------
template<int NCOLS>
__global__ __launch_bounds__(256) void gemm_mfma(const ushort* __restrict__ Xb,
                                                 const ushort* __restrict__ Wt,
                                                 float* __restrict__ C, int N) {
    constexpr int LDR = 136;
    __shared__ short Xs[128 * LDR];
    __shared__ short Ws[NCOLS * LDR];
    const int t = threadIdx.x;
    const int row0 = blockIdx.x * 128;

    for (int i = t; i < 128 * 16; i += 256) {
        int r = i >> 4, c8 = (i & 15) << 3;
        short8v v = {};
        if (row0 + r < N) v = *(const short8v*)(Xb + (size_t)(row0 + r) * 128 + c8);
        *(short8v*)(&Xs[r * LDR + c8]) = v;
    }
    for (int i = t; i < NCOLS * 16; i += 256) {
        int r = i >> 4, c8 = (i & 15) << 3;
        *(short8v*)(&Ws[r * LDR + c8]) = *(const short8v*)(Wt + r * 128 + c8);
    }
    __syncthreads();

    constexpr int WM = (NCOLS == 128) ? 2 : 4;    // waves tiling M
    constexpr int WN = (NCOLS == 128) ? 2 : 1;    // waves tiling N
    constexpr int MFR = 128 / WM / 16;            // M fragments per wave
    constexpr int NFR = NCOLS / WN / 16;          // N fragments per wave
    const int w = t >> 6, l = t & 63;
    const int wm = w % WM, wn = w / WM;
    const int m0 = wm * (128 / WM);
    const int n0 = wn * (NCOLS / WN);
    const int frow = l & 15;
    const int koff = (l >> 4) << 3;

    float4v acc[MFR][NFR];
    #pragma unroll
    for (int m = 0; m < MFR; ++m)
        #pragma unroll
        for (int n = 0; n < NFR; ++n) acc[m][n] = (float4v)0.f;

    #pragma unroll
    for (int ks = 0; ks < 4; ++ks) {
        const int k0 = ks * 32 + koff;
        short8v a[MFR], b[NFR];
        #pragma unroll
        for (int m = 0; m < MFR; ++m)
            a[m] = *(const short8v*)(&Xs[(m0 + m * 16 + frow) * LDR + k0]);
        #pragma unroll
        for (int n = 0; n < NFR; ++n)
            b[n] = *(const short8v*)(&Ws[(n0 + n * 16 + frow) * LDR + k0]);
        #pragma unroll
        for (int m = 0; m < MFR; ++m)
            #pragma unroll
            for (int n = 0; n < NFR; ++n)
                acc[m][n] = __builtin_amdgcn_mfma_f32_16x16x32_bf16(a[m], b[n], acc[m][n], 0, 0, 0);
    }

    // C/D layout: col = l&15, row = (l>>4)*4 + reg
    const int crow = (l >> 4) << 2;
    const int ccol = l & 15;
    #pragma unroll
    for (int m = 0; m < MFR; ++m) {
        #pragma unroll
        for (int r4 = 0; r4 < 4; ++r4) {
            int grow = row0 + m0 + m * 16 + crow + r4;
            if (grow < N) {
                #pragma unroll
                for (int n = 0; n < NFR; ++n)
                    C[(size_t)grow * NCOLS + n0 + n * 16 + ccol] = acc[m][n][r4];
            }
        }
    }
}

// ---------------------------------------------------------------------------
// Fused MLP: prefs[u] = tanh( leaky_relu(Xb[u]@hw1 + hb1, 0.01) @ hw2 + hb2 )
// Same MFMA tile as gemm_mfma<64>, epilogue reduces over the 64 hidden cols.
// ---------------------------------------------------------------------------
__global__ __launch_bounds__(256) void mlp_mfma(const ushort* __restrict__ Xb,
                                                const ushort* __restrict__ Wt,   // hw1t [64][128]
                                                const float* __restrict__ hb1,
                                                const float* __restrict__ hw2,
                                                const float* __restrict__ hb2,
                                                float* __restrict__ prefs, int N) {
    constexpr int LDR = 136;
    __shared__ short Xs[128 * LDR];
    __shared__ short Ws[64 * LDR];
    const int t = threadIdx.x;
    const int row0 = blockIdx.x * 128;

    for (int i = t; i < 128 * 16; i += 256) {
        int r = i >> 4, c8 = (i & 15) << 3;
        short8v v = {};
        if (row0 + r < N) v = *(const short8v*)(Xb + (size_t)(row0 + r) * 128 + c8);
        *(short8v*)(&Xs[r * LDR + c8]) = v;
    }
    for (int i = t; i < 64 * 16; i += 256) {
        int r = i >> 4, c8 = (i & 15) << 3;
        *(short8v*)(&Ws[r * LDR + c8]) = *(const short8v*)(Wt + r * 128 + c8);
    }
    __syncthreads();

    const int w = t >> 6, l = t & 63;
    const int m0 = w * 32;
    const int frow = l & 15;
    const int koff = (l >> 4) << 3;

    float4v acc[2][4];
    #pragma unroll
    for (int m = 0; m < 2; ++m)
        #pragma unroll
        for (int n = 0; n < 4; ++n) acc[m][n] = (float4v)0.f;

    #pragma unroll
    for (int ks = 0; ks < 4; ++ks) {
        const int k0 = ks * 32 + koff;
        short8v a[2], b[4];
        #pragma unroll
        for (int m = 0; m < 2; ++m)
            a[m] = *(const short8v*)(&Xs[(m0 + m * 16 + frow) * LDR + k0]);
        #pragma unroll
        for (int n = 0; n < 4; ++n)
            b[n] = *(const short8v*)(&Ws[(n * 16 + frow) * LDR + k0]);
        #pragma unroll
        for (int m = 0; m < 2; ++m)
            #pragma unroll
            for (int n = 0; n < 4; ++n)
                acc[m][n] = __builtin_amdgcn_mfma_f32_16x16x32_bf16(a[m], b[n], acc[m][n], 0, 0, 0);
    }

    float hb1v[4], hw2v[4];
    #pragma unroll
    for (int n = 0; n < 4; ++n) {
        int col = n * 16 + (l & 15);
        hb1v[n] = hb1[col];
        hw2v[n] = hw2[col];
    }
    const float hb2v = hb2[0];
    #pragma unroll
    for (int m = 0; m < 2; ++m) {
        #pragma unroll
        for (int r4 = 0; r4 < 4; ++r4) {
            float p = 0.f;
            #pragma unroll
            for (int n = 0; n < 4; ++n) {
                float v = acc[m][n][r4] + hb1v[n];
                v = v > 0.f ? v : 0.01f * v;
                p += v * hw2v[n];
            }
            p += __shfl_xor(p, 1);
            p += __shfl_xor(p, 2);
            p += __shfl_xor(p, 4);
            p += __shfl_xor(p, 8);
            int grow = row0 + m0 + m * 16 + ((l >> 4) << 2) + r4;
            if ((l & 15) == 0 && grow < N) prefs[grow] = tanhf(p + hb2v);
        }
    }
}

// ---------------------------------------------------------------------------
// Fused pair of matvecs: rows [0,Ns) -> outs = Xs@vs ; rows [Ns,Ns+Nd) -> outd
// ---------------------------------------------------------------------------
__global__ __launch_bounds__(256) void matvec128x2(const float* __restrict__ Xsp, const float* __restrict__ vs,
                                                   float* __restrict__ outs, int Ns,
                                                   const float* __restrict__ Xdp, const float* __restrict__ vd,
                                                   float* __restrict__ outd, int Nd) {
    int row = blockIdx.x * 4 + (threadIdx.x >> 6);
    int lane = threadIdx.x & 63;
    const float* X; const float* v; float* out; int r;
    if (row < Ns) { X = Xsp; v = vs; out = outs; r = row; }
    else {
        r = row - Ns;
        if (r >= Nd) return;
        X = Xdp; v = vd; out = outd;
    }
    float2 x = ((const float2*)(X + (size_t)r * 128))[lane];
    float2 vv = ((const float2*)v)[lane];
    float s = x.x * vv.x + x.y * vv.y;
    #pragma unroll
    for (int off = 32; off; off >>= 1) s += __shfl_xor(s, off);
    if (lane == 0) out[r] = s;
}

// ---------------------------------------------------------------------------
// CSR build: histogram -> multi-block exclusive scan -> cursor fill
// ---------------------------------------------------------------------------
__global__ void count_deg(const int* __restrict__ dst, int* __restrict__ deg, int E) {
    int e = blockIdx.x * 256 + threadIdx.x;
    if (e < E) atomicAdd(&deg[dst[e]], 1);
}

__global__ __launch_bounds__(256) void partial_sums(const int* __restrict__ deg,
                                                    int* __restrict__ part, int N) {
    __shared__ int wsum[4];
    int base = blockIdx.x * 1024;
    int s = 0;
    for (int i = threadIdx.x; i < 1024; i += 256) {
        int idx = base + i;
        if (idx < N) s += deg[idx];
    }
    #pragma unroll
    for (int o = 32; o; o >>= 1) s += __shfl_xor(s, o);
    if ((threadIdx.x & 63) == 0) wsum[threadIdx.x >> 6] = s;
    __syncthreads();
    if (threadIdx.x == 0) part[blockIdx.x] = wsum[0] + wsum[1] + wsum[2] + wsum[3];
}

__global__ __launch_bounds__(64) void scan_partials(int* __restrict__ part,
                                                    int* __restrict__ offN, int nb) {
    int lane = threadIdx.x;
    int v = (lane < nb) ? part[lane] : 0;
    int incl = v;
    #pragma unroll
    for (int o = 1; o < 64; o <<= 1) {
        int t = __shfl_up(incl, o);
        if (lane >= o) incl += t;
    }
    if (lane < nb) part[lane] = incl - v;
    if (lane == 63) *offN = incl;
}

__global__ __launch_bounds__(256) void block_scan(const int* __restrict__ deg,
                                                  const int* __restrict__ part,
                                                  int* __restrict__ off,
                                                  int* __restrict__ cursor, int N) {
    __shared__ int wsum[4];
    int t = threadIdx.x;
    int lane = t & 63, w = t >> 6;
    int base = blockIdx.x * 1024 + t * 4;
    int l0 = 0, l1 = 0, l2 = 0, l3 = 0;
    if (base + 3 < N) {
        int4 v = *(const int4*)(deg + base);
        l0 = v.x; l1 = v.y; l2 = v.z; l3 = v.w;
    } else {
        if (base + 0 < N) l0 = deg[base + 0];
        if (base + 1 < N) l1 = deg[base + 1];
        if (base + 2 < N) l2 = deg[base + 2];
    }
    int tsum = l0 + l1 + l2 + l3;
    int incl = tsum;
    #pragma unroll
    for (int o = 1; o < 64; o <<= 1) {
        int tt = __shfl_up(incl, o);
        if (lane >= o) incl += tt;
    }
    int lexcl = incl - tsum;
    if (lane == 63) wsum[w] = incl;
    __syncthreads();
    int p = part[blockIdx.x] + lexcl;
    for (int i = 0; i < w; ++i) p += wsum[i];
    if (base + 0 < N) { off[base + 0] = p; cursor[base + 0] = p; } p += l0;
    if (base + 1 < N) { off[base + 1] = p; cursor[base + 1] = p; } p += l1;
    if (base + 2 < N) { off[base + 2] = p; cursor[base + 2] = p; } p += l2;
    if (base + 3 < N) { off[base + 3] = p; cursor[base + 3] = p; }
}

__global__ void fill_csr(const int* __restrict__ src, const int* __restrict__ dst,
                         int* __restrict__ cursor, int* __restrict__ esrc, int E) {
    int e = blockIdx.x * 256 + threadIdx.x;
    if (e >= E) return;
    int p = atomicAdd(&cursor[dst[e]], 1);
    esrc[p] = src[e];
}

// ---------------------------------------------------------------------------
// Fused GAT softmax + aggregate, one wave per destination node (gather).
// Half-wave float4 gathers: lanes 0-31 even edges, 32-63 odd edges.
// ---------------------------------------------------------------------------
__global__ __launch_bounds__(256) void gat_aggregate_csr(const int* __restrict__ off,
                                                         const int* __restrict__ esrc,
                                                         const float* __restrict__ asn,
                                                         const float* __restrict__ adn,
                                                         const float* __restrict__ hs,
                                                         const float* __restrict__ bias,
                                                         float* __restrict__ out, int Nd) {
    int d = blockIdx.x * 4 + (threadIdx.x >> 6);
    int lane = threadIdx.x & 63;
    if (d >= Nd) return;
    const int beg = off[d], end = off[d + 1];
    const float ad = adn[d];
    const int half = lane >> 5, l32 = lane & 31;
    float4 acc = make_float4(0.f, 0.f, 0.f, 0.f);
    float den = 0.f;
    for (int base = beg; base < end; base += 64) {
        int e = base + lane;
        int s = 0; float ev = 0.f;        // inactive lanes: ev=0, s=0 (row-0 load harmless)
        if (e < end) {
            s = esrc[e];
            float v = asn[s] + ad;
            v = v > 0.f ? v : 0.2f * v;
            ev = __expf(v);
        }
        float r = ev;
        #pragma unroll
        for (int o = 32; o; o >>= 1) r += __shfl_xor(r, o);
        den += r;
        int cnt2 = (min(64, end - base) + 1) & ~1;
        for (int j = 0; j < cnt2; j += 2) {
            int jj = j + half;
            float evj = __shfl(ev, jj);
            int sj = __shfl(s, jj);
            float4 h = ((const float4*)(hs + (size_t)sj * 128))[l32];
            acc.x += evj * h.x; acc.y += evj * h.y;
            acc.z += evj * h.z; acc.w += evj * h.w;
        }
    }
    acc.x += __shfl_xor(acc.x, 32);
    acc.y += __shfl_xor(acc.y, 32);
    acc.z += __shfl_xor(acc.z, 32);
    acc.w += __shfl_xor(acc.w, 32);
    if (half == 0) {
        float inv = 1.f / (den + 1e-16f);
        float4 b4 = ((const float4*)bias)[l32];
        ((float4*)(out + (size_t)d * 128))[l32] =
            make_float4(acc.x * inv + b4.x, acc.y * inv + b4.y,
                        acc.z * inv + b4.z, acc.w * inv + b4.w);
    }
}

// ---------------------------------------------------------------------------
// BatchNorm stats + apply (apply optionally dual-writes a bf16 copy)
// ---------------------------------------------------------------------------
__global__ void bn_stats(const float* __restrict__ x, float* __restrict__ stat, int N) {
    int c = threadIdx.x & 127;
    int h = threadIdx.x >> 7;
    float s = 0.f, q = 0.f;
    for (int r = blockIdx.x * 2 + h; r < N; r += gridDim.x * 2) {
        float v = x[(size_t)r * 128 + c];
        s += v; q += v * v;
    }
    atomicAdd(&stat[c], s);
    atomicAdd(&stat[128 + c], q);
}

__global__ void bn_apply(float* __restrict__ x, const float* __restrict__ stat,
                         const float* __restrict__ g, const float* __restrict__ b,
                         ushort* __restrict__ xb, int N, float invN) {
    int i = blockIdx.x * 256 + threadIdx.x;
    if (i >= N * 32) return;
    int c4 = (i & 31) << 2;
    float4 v = ((float4*)x)[i];
    float* vp = &v.x;
    #pragma unroll
    for (int j = 0; j < 4; ++j) {
        int c = c4 + j;
        float mu = stat[c] * invN;
        float var = stat[128 + c] * invN - mu * mu;
        float xn = (vp[j] - mu) * rsqrtf(var + 1e-5f) * g[c] + b[c];
        vp[j] = xn > 0.f ? xn : expm1f(xn);
    }
    ((float4*)x)[i] = v;
    if (xb) {
        ushort4 o;
        o.x = f2bf(v.x); o.y = f2bf(v.y); o.z = f2bf(v.z); o.w = f2bf(v.w);
        ((ushort4*)xb)[i] = o;
    }
}

// s[he_food[e]] += prefs[he_user[e]] * score[e]
__global__ void health_scatter(const int* __restrict__ hu, const int* __restrict__ hf,
                               const float* __restrict__ score, const float* __restrict__ prefs,
                               float* __restrict__ s, int E) {
    int e = blockIdx.x * 256 + threadIdx.x;
    if (e >= E) return;
    atomicAdd(&s[hf[e]], prefs[hu[e]] * score[e]);
}

// xf2[f][c] += 0.1 * s[f]
__global__ void add_health(float* __restrict__ xf2, const float* __restrict__ s, int n4) {
    int i = blockIdx.x * 256 + threadIdx.x;
    if (i >= n4) return;
    float sv = 0.1f * s[i >> 5];
    float4 v = ((float4*)xf2)[i];
    v.x += sv; v.y += sv; v.z += sv; v.w += sv;
    ((float4*)xf2)[i] = v;
}

// ---------------------------------------------------------------------------
extern "C" void kernel_launch(void* const* d_in, const int* in_sizes, int n_in,
                              void* d_out, int out_size, void* d_ws, size_t ws_size,
                              hipStream_t stream) {
    const float* x_user = (const float*)d_in[0];
    const float* x_food = (const float*)d_in[1];
    const int* uf_src = (const int*)d_in[2];
    const int* uf_dst = (const int*)d_in[3];
    const int* fu_src = (const int*)d_in[4];
    const int* fu_dst = (const int*)d_in[5];
    const int* he_user = (const int*)d_in[6];
    const int* he_food = (const int*)d_in[7];
    const float* scores = (const float*)d_in[8];
    const float* a1_uf_src = (const float*)d_in[11];
    const float* a1_uf_dst = (const float*)d_in[12];
    const float* b1_uf     = (const float*)d_in[13];
    const float* a1_fu_src = (const float*)d_in[16];
    const float* a1_fu_dst = (const float*)d_in[17];
    const float* b1_fu     = (const float*)d_in[18];
    const float* b2_uf     = (const float*)d_in[23];
    const float* b2_fu     = (const float*)d_in[28];
    const float* bn1_user_g = (const float*)d_in[29];
    const float* bn1_user_b = (const float*)d_in[30];
    const float* bn1_food_g = (const float*)d_in[31];
    const float* bn1_food_b = (const float*)d_in[32];
    const float* bn2_user_g = (const float*)d_in[33];
    const float* bn2_user_b = (const float*)d_in[34];
    const float* bn2_food_g = (const float*)d_in[35];
    const float* bn2_food_b = (const float*)d_in[36];
    const float* hw1 = (const float*)d_in[37];
    const float* hb1 = (const float*)d_in[38];
    const float* hw2 = (const float*)d_in[39];
    const float* hb2 = (const float*)d_in[40];

    float* outp  = (float*)d_out;
    float* xu2   = outp;                          // [NU,128]
    float* xf2   = outp + (size_t)NU_ * 128;      // [NF,128]
    float* prefs = xf2 + (size_t)NF_ * 128;       // [NU]

    // ---- workspace layout ----
    float* ws    = (float*)d_ws;
    float* hs    = ws;                             // NU*128
    float* xu1   = hs   + (size_t)NU_ * 128;       // NU*128
    float* xf1   = xu1  + (size_t)NU_ * 128;       // NF*128
    float* asn   = xf1  + (size_t)NF_ * 128;       // NU
    float* adn   = asn  + NU_;                     // NU
    // --- zeroed-once region start ---
    float* stat4 = adn  + NU_;                     // 4*256 (one per BN instance)
    float* sbuf  = stat4 + 1024;                   // NF
    int*   deg_f = (int*)(sbuf + NF_);             // NF
    int*   deg_u = deg_f + NF_;                    // NU
    // --- zeroed-once region end ---
    float* vall  = (float*)(deg_u + NU_);          // 8*128
    int*   part  = (int*)(vall + 1024);            // 64
    int*   uf_off  = part + 64;                    // NF+4
    int*   fu_off  = uf_off + (NF_ + 4);           // NU+4
    int*   cursor  = fu_off + (NU_ + 4);           // NU (max)
    int*   uf_esrc = cursor + NU_;                 // E
    int*   fu_esrc = uf_esrc + E_;                 // E
    // bf16 buffers (ushort), 16B-aligned since previous sizes are /4
    ushort* bu   = (ushort*)(fu_esrc + E_);        // NU*128 (x_user -> xu1b -> xu2b)
    ushort* bfo  = bu + (size_t)NU_ * 128;         // NF*128 (x_food -> xf1b)
    ushort* wt0  = bfo + (size_t)NF_ * 128;        // 4 x 128*128 transposed weights
    ushort* wt1  = wt0 + 16384;
    ushort* wt2  = wt1 + 16384;
    ushort* wt3  = wt2 + 16384;
    ushort* hw1t = wt3 + 16384;                    // 64*128

    const size_t zero_elems = 1024 + NF_ + NF_ + NU_;
    hipMemsetAsync(stat4, 0, zero_elems * sizeof(float), stream);

    // --- bf16 conversions ---
    f2b_rows<<<(NU_ * 32 + 255) / 256, 256, 0, stream>>>(x_user, bu, NU_ * 32);
    f2b_rows<<<(NF_ * 32 + 255) / 256, 256, 0, stream>>>(x_food, bfo, NF_ * 32);
    WTArgs wt;
    wt.W[0] = (const float*)d_in[9];  wt.T[0] = wt0;  wt.shift[0] = 7;
    wt.W[1] = (const float*)d_in[14]; wt.T[1] = wt1;  wt.shift[1] = 7;
    wt.W[2] = (const float*)d_in[19]; wt.T[2] = wt2;  wt.shift[2] = 7;
    wt.W[3] = (const float*)d_in[24]; wt.T[3] = wt3;  wt.shift[3] = 7;
    wt.W[4] = hw1;                    wt.T[4] = hw1t; wt.shift[4] = 6;
    wt_conv<<<dim3(64, 5), 256, 0, stream>>>(wt);

    // --- precompute v = W@a for all 8 (dst-side GEMMs eliminated) ---
    WAArgs wa;
    wa.W[0] = (const float*)d_in[9];  wa.a[0] = a1_uf_src;
    wa.W[1] = (const float*)d_in[10]; wa.a[1] = a1_uf_dst;
    wa.W[2] = (const float*)d_in[14]; wa.a[2] = a1_fu_src;
    wa.W[3] = (const float*)d_in[15]; wa.a[3] = a1_fu_dst;
    wa.W[4] = (const float*)d_in[19]; wa.a[4] = (const float*)d_in[21];
    wa.W[5] = (const float*)d_in[20]; wa.a[5] = (const float*)d_in[22];
    wa.W[6] = (const float*)d_in[24]; wa.a[6] = (const float*)d_in[26];
    wa.W[7] = (const float*)d_in[25]; wa.a[7] = (const float*)d_in[27];
    wa_vec<<<8, 256, 0, stream>>>(wa, vall);

    // --- build CSR once per edge type (reused by both layers) ---
    const int EB = (E_ + 255) / 256;
    const int NBF = (NF_ + 1023) / 1024;   // 25
    const int NBU = (NU_ + 1023) / 1024;   // 49

    count_deg<<<EB, 256, 0, stream>>>(uf_dst, deg_f, E_);
    partial_sums<<<NBF, 256, 0, stream>>>(deg_f, part, NF_);
    scan_partials<<<1, 64, 0, stream>>>(part, &uf_off[NF_], NBF);
    block_scan<<<NBF, 256, 0, stream>>>(deg_f, part, uf_off, cursor, NF_);
    fill_csr<<<EB, 256, 0, stream>>>(uf_src, uf_dst, cursor, uf_esrc, E_);

    count_deg<<<EB, 256, 0, stream>>>(fu_dst, deg_u, E_);
    partial_sums<<<NBU, 256, 0, stream>>>(deg_u, part, NU_);
    scan_partials<<<1, 64, 0, stream>>>(part, &fu_off[NU_], NBU);
    block_scan<<<NBU, 256, 0, stream>>>(deg_u, part, fu_off, cursor, NU_);
    fill_csr<<<EB, 256, 0, stream>>>(fu_src, fu_dst, cursor, fu_esrc, E_);

    auto run_gat = [&](const ushort* xb, const float* xsrc, const float* xdst,
                       const int* off, const int* esrc,
                       const ushort* wtb, const float* vs, const float* vd, const float* bias,
                       float* out, int Ns, int Nd) {
        gemm_mfma<128><<<(Ns + 127) / 128, 256, 0, stream>>>(xb, wtb, hs, Ns);
        matvec128x2<<<(Ns + Nd + 3) / 4, 256, 0, stream>>>(xsrc, vs, asn, Ns, xdst, vd, adn, Nd);
        gat_aggregate_csr<<<(Nd + 3) / 4, 256, 0, stream>>>(off, esrc, asn, adn, hs, bias, out, Nd);
    };

    auto run_bn = [&](float* x, float* stat, const float* g, const float* b,
                      ushort* xb, int N) {
        bn_stats<<<512, 256, 0, stream>>>(x, stat, N);
        bn_apply<<<(N * 32 + 255) / 256, 256, 0, stream>>>(x, stat, g, b, xb, N, 1.0f / N);
    };

    // ---- layer 1 ----
    run_gat(bu, x_user, x_food, uf_off, uf_esrc, wt0, vall + 0,   vall + 128, b1_uf, xf1, NU_, NF_);
    run_gat(bfo, x_food, x_user, fu_off, fu_esrc, wt1, vall + 256, vall + 384, b1_fu, xu1, NF_, NU_);
    run_bn(xu1, stat4 + 0,   bn1_user_g, bn1_user_b, bu,  NU_);   // bu <- xu1 bf16
    run_bn(xf1, stat4 + 256, bn1_food_g, bn1_food_b, bfo, NF_);   // bfo <- xf1 bf16

    // ---- layer 2 (aggregate straight into d_out regions) ----
    run_gat(bu, xu1, xf1, uf_off, uf_esrc, wt2, vall + 512, vall + 640, b2_uf, xf2, NU_, NF_);
    run_gat(bfo, xf1, xu1, fu_off, fu_esrc, wt3, vall + 768, vall + 896, b2_fu, xu2, NF_, NU_);
    run_bn(xu2, stat4 + 512, bn2_user_g, bn2_user_b, bu, NU_);    // bu <- xu2 bf16
    run_bn(xf2, stat4 + 768, bn2_food_g, bn2_food_b, nullptr, NF_);

    // ---- health preference MLP + scatter update ----
    mlp_mfma<<<(NU_ + 127) / 128, 256, 0, stream>>>(bu, hw1t, hb1, hw2, hb2, prefs, NU_);
    health_scatter<<<EB, 256, 0, stream>>>(he_user, he_food, scores, prefs, sbuf, E_);
    add_health<<<(NF_ * 32 + 255) / 256, 256, 0, stream>>>(xf2, sbuf, NF_ * 32);
}

// Round 5
// 541.066 us; speedup vs baseline: 4.4219x; 1.2302x over previous
//
#include <hip/hip_runtime.h>
#include <cstddef>

#define NU_ 50000
#define NF_ 25000
#define E_  500000

typedef __attribute__((ext_vector_type(8))) short short8v;
typedef __attribute__((ext_vector_type(4))) float float4v;

static __device__ __forceinline__ ushort f2bf(float f) {
    uint u = __float_as_uint(f);
    uint r = (u + 0x7fffu + ((u >> 16) & 1u)) >> 16;   // RNE
    return (ushort)r;
}
static __device__ __forceinline__ float bf2f(ushort u) {
    return __uint_as_float(((uint)u) << 16);
}

// ---------------------------------------------------------------------------
// v = W @ a  (v[k] = sum_h W[k][h] * a[h]) for 8 (W,a) pairs, one block each.
// ---------------------------------------------------------------------------
struct WAArgs {
    const float* W[8];
    const float* a[8];
};

__global__ __launch_bounds__(256) void wa_vec(WAArgs args, float* __restrict__ vout) {
    __shared__ float Ws[128][129];
    __shared__ float as[128];
    const int b = blockIdx.x;
    const float* W = args.W[b];
    const float* a = args.a[b];
    for (int i = threadIdx.x; i < 128 * 32; i += 256) {
        float4 w = ((const float4*)W)[i];
        int r = i >> 5, c = (i & 31) << 2;
        Ws[r][c] = w.x; Ws[r][c + 1] = w.y; Ws[r][c + 2] = w.z; Ws[r][c + 3] = w.w;
    }
    if (threadIdx.x < 128) as[threadIdx.x] = a[threadIdx.x];
    __syncthreads();
    if (threadIdx.x < 128) {
        float s = 0.f;
        #pragma unroll 8
        for (int h = 0; h < 128; ++h) s += Ws[threadIdx.x][h] * as[h];
        vout[b * 128 + threadIdx.x] = s;
    }
}

// ---------------------------------------------------------------------------
// fp32 -> bf16 bulk convert for both feature matrices in one launch
// ---------------------------------------------------------------------------
__global__ void f2b_two(const float* __restrict__ a, ushort* __restrict__ da, int n4a,
                        const float* __restrict__ b, ushort* __restrict__ db, int n4b) {
    int i = blockIdx.x * 256 + threadIdx.x;
    const float* s; ushort* d; int idx;
    if (i < n4a) { s = a; d = da; idx = i; }
    else {
        idx = i - n4a;
        if (idx >= n4b) return;
        s = b; d = db;
    }
    float4 v = ((const float4*)s)[idx];
    ushort4 o;
    o.x = f2bf(v.x); o.y = f2bf(v.y); o.z = f2bf(v.z); o.w = f2bf(v.w);
    ((ushort4*)d)[idx] = o;
}

// ---------------------------------------------------------------------------
// Weight convert: Wt[c][k] = bf16(W[k][c]); 5 matrices in one launch (grid.y)
// ---------------------------------------------------------------------------
struct WTArgs {
    const float* W[5];
    ushort* T[5];
    int shift[5];   // log2(ncols)
};

__global__ void wt_conv(WTArgs args) {
    const int m = blockIdx.y;
    const float* W = args.W[m];
    ushort* T = args.T[m];
    const int sh = args.shift[m];
    const int ncols = 1 << sh;
    const int total = 128 << sh;
    int idx = blockIdx.x * 256 + threadIdx.x;
    if (idx >= total) return;
    int k = idx >> sh, c = idx & (ncols - 1);
    T[c * 128 + k] = f2bf(W[idx]);
}

// ---------------------------------------------------------------------------
// C[N,128] bf16 = Xb[N,128] bf16 @ W[128,128] (Wt transposed bf16)
// MFMA 16x16x32, 128-row tile, K=128 single-shot, 4 waves (2x2).
// ---------------------------------------------------------------------------
__global__ __launch_bounds__(256) void gemm_mfma(const ushort* __restrict__ Xb,
                                                 const ushort* __restrict__ Wt,
                                                 ushort* __restrict__ C, int N) {
    constexpr int LDR = 136;
    __shared__ short Xs[128 * LDR];
    __shared__ short Ws[128 * LDR];
    const int t = threadIdx.x;
    const int row0 = blockIdx.x * 128;

    for (int i = t; i < 128 * 16; i += 256) {
        int r = i >> 4, c8 = (i & 15) << 3;
        short8v v = {};
        if (row0 + r < N) v = *(const short8v*)(Xb + (size_t)(row0 + r) * 128 + c8);
        *(short8v*)(&Xs[r * LDR + c8]) = v;
    }
    for (int i = t; i < 128 * 16; i += 256) {
        int r = i >> 4, c8 = (i & 15) << 3;
        *(short8v*)(&Ws[r * LDR + c8]) = *(const short8v*)(Wt + r * 128 + c8);
    }
    __syncthreads();

    const int w = t >> 6, l = t & 63;
    const int wm = w & 1, wn = w >> 1;
    const int m0 = wm * 64;
    const int n0 = wn * 64;
    const int frow = l & 15;
    const int koff = (l >> 4) << 3;

    float4v acc[4][4];
    #pragma unroll
    for (int m = 0; m < 4; ++m)
        #pragma unroll
        for (int n = 0; n < 4; ++n) acc[m][n] = (float4v)0.f;

    #pragma unroll
    for (int ks = 0; ks < 4; ++ks) {
        const int k0 = ks * 32 + koff;
        short8v a[4], b[4];
        #pragma unroll
        for (int m = 0; m < 4; ++m)
            a[m] = *(const short8v*)(&Xs[(m0 + m * 16 + frow) * LDR + k0]);
        #pragma unroll
        for (int n = 0; n < 4; ++n)
            b[n] = *(const short8v*)(&Ws[(n0 + n * 16 + frow) * LDR + k0]);
        #pragma unroll
        for (int m = 0; m < 4; ++m)
            #pragma unroll
            for (int n = 0; n < 4; ++n)
                acc[m][n] = __builtin_amdgcn_mfma_f32_16x16x32_bf16(a[m], b[n], acc[m][n], 0, 0, 0);
    }

    // C/D layout: col = l&15, row = (l>>4)*4 + reg
    const int crow = (l >> 4) << 2;
    const int ccol = l & 15;
    #pragma unroll
    for (int m = 0; m < 4; ++m) {
        #pragma unroll
        for (int r4 = 0; r4 < 4; ++r4) {
            int grow = row0 + m0 + m * 16 + crow + r4;
            if (grow < N) {
                #pragma unroll
                for (int n = 0; n < 4; ++n)
                    C[(size_t)grow * 128 + n0 + n * 16 + ccol] = f2bf(acc[m][n][r4]);
            }
        }
    }
}

// ---------------------------------------------------------------------------
// Fused MLP: prefs[u] = tanh( leaky_relu(Xb[u]@hw1 + hb1, 0.01) @ hw2 + hb2 )
// ---------------------------------------------------------------------------
__global__ __launch_bounds__(256) void mlp_mfma(const ushort* __restrict__ Xb,
                                                const ushort* __restrict__ Wt,   // hw1t [64][128]
                                                const float* __restrict__ hb1,
                                                const float* __restrict__ hw2,
                                                const float* __restrict__ hb2,
                                                float* __restrict__ prefs, int N) {
    constexpr int LDR = 136;
    __shared__ short Xs[128 * LDR];
    __shared__ short Ws[64 * LDR];
    const int t = threadIdx.x;
    const int row0 = blockIdx.x * 128;

    for (int i = t; i < 128 * 16; i += 256) {
        int r = i >> 4, c8 = (i & 15) << 3;
        short8v v = {};
        if (row0 + r < N) v = *(const short8v*)(Xb + (size_t)(row0 + r) * 128 + c8);
        *(short8v*)(&Xs[r * LDR + c8]) = v;
    }
    for (int i = t; i < 64 * 16; i += 256) {
        int r = i >> 4, c8 = (i & 15) << 3;
        *(short8v*)(&Ws[r * LDR + c8]) = *(const short8v*)(Wt + r * 128 + c8);
    }
    __syncthreads();

    const int w = t >> 6, l = t & 63;
    const int m0 = w * 32;
    const int frow = l & 15;
    const int koff = (l >> 4) << 3;

    float4v acc[2][4];
    #pragma unroll
    for (int m = 0; m < 2; ++m)
        #pragma unroll
        for (int n = 0; n < 4; ++n) acc[m][n] = (float4v)0.f;

    #pragma unroll
    for (int ks = 0; ks < 4; ++ks) {
        const int k0 = ks * 32 + koff;
        short8v a[2], b[4];
        #pragma unroll
        for (int m = 0; m < 2; ++m)
            a[m] = *(const short8v*)(&Xs[(m0 + m * 16 + frow) * LDR + k0]);
        #pragma unroll
        for (int n = 0; n < 4; ++n)
            b[n] = *(const short8v*)(&Ws[(n * 16 + frow) * LDR + k0]);
        #pragma unroll
        for (int m = 0; m < 2; ++m)
            #pragma unroll
            for (int n = 0; n < 4; ++n)
                acc[m][n] = __builtin_amdgcn_mfma_f32_16x16x32_bf16(a[m], b[n], acc[m][n], 0, 0, 0);
    }

    float hb1v[4], hw2v[4];
    #pragma unroll
    for (int n = 0; n < 4; ++n) {
        int col = n * 16 + (l & 15);
        hb1v[n] = hb1[col];
        hw2v[n] = hw2[col];
    }
    const float hb2v = hb2[0];
    #pragma unroll
    for (int m = 0; m < 2; ++m) {
        #pragma unroll
        for (int r4 = 0; r4 < 4; ++r4) {
            float p = 0.f;
            #pragma unroll
            for (int n = 0; n < 4; ++n) {
                float v = acc[m][n][r4] + hb1v[n];
                v = v > 0.f ? v : 0.01f * v;
                p += v * hw2v[n];
            }
            p += __shfl_xor(p, 1);
            p += __shfl_xor(p, 2);
            p += __shfl_xor(p, 4);
            p += __shfl_xor(p, 8);
            int grow = row0 + m0 + m * 16 + ((l >> 4) << 2) + r4;
            if ((l & 15) == 0 && grow < N) prefs[grow] = tanhf(p + hb2v);
        }
    }
}

// ---------------------------------------------------------------------------
// Fused pair of matvecs on bf16 features.
// ---------------------------------------------------------------------------
__global__ __launch_bounds__(256) void matvec128x2(const ushort* __restrict__ Xsp, const float* __restrict__ vs,
                                                   float* __restrict__ outs, int Ns,
                                                   const ushort* __restrict__ Xdp, const float* __restrict__ vd,
                                                   float* __restrict__ outd, int Nd) {
    int row = blockIdx.x * 4 + (threadIdx.x >> 6);
    int lane = threadIdx.x & 63;
    const ushort* X; const float* v; float* out; int r;
    if (row < Ns) { X = Xsp; v = vs; out = outs; r = row; }
    else {
        r = row - Ns;
        if (r >= Nd) return;
        X = Xdp; v = vd; out = outd;
    }
    ushort2 x = ((const ushort2*)(X + (size_t)r * 128))[lane];
    float2 vv = ((const float2*)v)[lane];
    float s = bf2f(x.x) * vv.x + bf2f(x.y) * vv.y;
    #pragma unroll
    for (int off = 32; off; off >>= 1) s += __shfl_xor(s, off);
    if (lane == 0) out[r] = s;
}

// ---------------------------------------------------------------------------
// CSR build: histogram -> multi-block exclusive scan -> cursor fill
// ---------------------------------------------------------------------------
__global__ void count_deg(const int* __restrict__ dst, int* __restrict__ deg, int E) {
    int e = blockIdx.x * 256 + threadIdx.x;
    if (e < E) atomicAdd(&deg[dst[e]], 1);
}

__global__ __launch_bounds__(256) void partial_sums(const int* __restrict__ deg,
                                                    int* __restrict__ part, int N) {
    __shared__ int wsum[4];
    int base = blockIdx.x * 1024;
    int s = 0;
    for (int i = threadIdx.x; i < 1024; i += 256) {
        int idx = base + i;
        if (idx < N) s += deg[idx];
    }
    #pragma unroll
    for (int o = 32; o; o >>= 1) s += __shfl_xor(s, o);
    if ((threadIdx.x & 63) == 0) wsum[threadIdx.x >> 6] = s;
    __syncthreads();
    if (threadIdx.x == 0) part[blockIdx.x] = wsum[0] + wsum[1] + wsum[2] + wsum[3];
}

__global__ __launch_bounds__(64) void scan_partials(int* __restrict__ part,
                                                    int* __restrict__ offN, int nb) {
    int lane = threadIdx.x;
    int v = (lane < nb) ? part[lane] : 0;
    int incl = v;
    #pragma unroll
    for (int o = 1; o < 64; o <<= 1) {
        int t = __shfl_up(incl, o);
        if (lane >= o) incl += t;
    }
    if (lane < nb) part[lane] = incl - v;
    if (lane == 63) *offN = incl;
}

__global__ __launch_bounds__(256) void block_scan(const int* __restrict__ deg,
                                                  const int* __restrict__ part,
                                                  int* __restrict__ off,
                                                  int* __restrict__ cursor, int N) {
    __shared__ int wsum[4];
    int t = threadIdx.x;
    int lane = t & 63, w = t >> 6;
    int base = blockIdx.x * 1024 + t * 4;
    int l0 = 0, l1 = 0, l2 = 0, l3 = 0;
    if (base + 3 < N) {
        int4 v = *(const int4*)(deg + base);
        l0 = v.x; l1 = v.y; l2 = v.z; l3 = v.w;
    } else {
        if (base + 0 < N) l0 = deg[base + 0];
        if (base + 1 < N) l1 = deg[base + 1];
        if (base + 2 < N) l2 = deg[base + 2];
    }
    int tsum = l0 + l1 + l2 + l3;
    int incl = tsum;
    #pragma unroll
    for (int o = 1; o < 64; o <<= 1) {
        int tt = __shfl_up(incl, o);
        if (lane >= o) incl += tt;
    }
    int lexcl = incl - tsum;
    if (lane == 63) wsum[w] = incl;
    __syncthreads();
    int p = part[blockIdx.x] + lexcl;
    for (int i = 0; i < w; ++i) p += wsum[i];
    if (base + 0 < N) { off[base + 0] = p; cursor[base + 0] = p; } p += l0;
    if (base + 1 < N) { off[base + 1] = p; cursor[base + 1] = p; } p += l1;
    if (base + 2 < N) { off[base + 2] = p; cursor[base + 2] = p; } p += l2;
    if (base + 3 < N) { off[base + 3] = p; cursor[base + 3] = p; }
}

__global__ void fill_csr(const int* __restrict__ src, const int* __restrict__ dst,
                         int* __restrict__ cursor, int* __restrict__ esrc, int E) {
    int e = blockIdx.x * 256 + threadIdx.x;
    if (e >= E) return;
    int p = atomicAdd(&cursor[dst[e]], 1);
    esrc[p] = src[e];
}

// ---------------------------------------------------------------------------
// Fused GAT softmax + aggregate, one wave per destination node, bf16 gathers.
// Quarter-wave rows: 16 lanes x ushort8 = 256B row; 4 edges in flight.
// ---------------------------------------------------------------------------
__global__ __launch_bounds__(256) void gat_aggregate_csr(const int* __restrict__ off,
                                                         const int* __restrict__ esrc,
                                                         const float* __restrict__ asn,
                                                         const float* __restrict__ adn,
                                                         const ushort* __restrict__ hs,
                                                         const float* __restrict__ bias,
                                                         float* __restrict__ out, int Nd) {
    int d = blockIdx.x * 4 + (threadIdx.x >> 6);
    int lane = threadIdx.x & 63;
    if (d >= Nd) return;
    const int beg = off[d], end = off[d + 1];
    const float ad = adn[d];
    const int qw = lane >> 4, l16 = lane & 15;
    float acc[8] = {0.f, 0.f, 0.f, 0.f, 0.f, 0.f, 0.f, 0.f};
    float den = 0.f;
    for (int base = beg; base < end; base += 64) {
        int e = base + lane;
        int s = 0; float ev = 0.f;        // inactive lanes: ev=0, s=0 (row-0 load harmless)
        if (e < end) {
            s = esrc[e];
            float v = asn[s] + ad;
            v = v > 0.f ? v : 0.2f * v;
            ev = __expf(v);
        }
        float r = ev;
        #pragma unroll
        for (int o = 32; o; o >>= 1) r += __shfl_xor(r, o);
        den += r;
        int cnt4 = (min(64, end - base) + 3) & ~3;
        for (int j = 0; j < cnt4; j += 4) {
            int jj = j + qw;
            float evj = __shfl(ev, jj);
            int sj = __shfl(s, jj);
            short8v h = *(const short8v*)(hs + (size_t)sj * 128 + l16 * 8);
            #pragma unroll
            for (int k = 0; k < 8; ++k)
                acc[k] += evj * bf2f((ushort)h[k]);
        }
    }
    // reduce across the 4 quarter-waves
    #pragma unroll
    for (int k = 0; k < 8; ++k) {
        acc[k] += __shfl_xor(acc[k], 16);
        acc[k] += __shfl_xor(acc[k], 32);
    }
    if (qw == 0) {
        float inv = 1.f / (den + 1e-16f);
        float4 b0 = ((const float4*)bias)[l16 * 2];
        float4 b1 = ((const float4*)bias)[l16 * 2 + 1];
        float4* op = (float4*)(out + (size_t)d * 128 + l16 * 8);
        op[0] = make_float4(acc[0] * inv + b0.x, acc[1] * inv + b0.y,
                            acc[2] * inv + b0.z, acc[3] * inv + b0.w);
        op[1] = make_float4(acc[4] * inv + b1.x, acc[5] * inv + b1.y,
                            acc[6] * inv + b1.z, acc[7] * inv + b1.w);
    }
}

// ---------------------------------------------------------------------------
// BatchNorm stats + apply for TWO tensors in one launch each.
// ---------------------------------------------------------------------------
__global__ void bn_stats2(const float* __restrict__ x1, float* __restrict__ stat1, int N1, int B1,
                          const float* __restrict__ x2, float* __restrict__ stat2, int N2) {
    const float* x; float* stat; int N, b;
    if ((int)blockIdx.x < B1) { x = x1; stat = stat1; N = N1; b = blockIdx.x; }
    else { x = x2; stat = stat2; N = N2; b = blockIdx.x - B1; }
    int c = threadIdx.x & 127;
    int h = threadIdx.x >> 7;
    float s = 0.f, q = 0.f;
    for (int r = b * 2 + h; r < N; r += 512) {
        float v = x[(size_t)r * 128 + c];
        s += v; q += v * v;
    }
    atomicAdd(&stat[c], s);
    atomicAdd(&stat[128 + c], q);
}

__global__ void bn_apply2(float* __restrict__ x1, const float* __restrict__ stat1,
                          const float* __restrict__ g1, const float* __restrict__ b1,
                          ushort* __restrict__ xb1, int N1,
                          float* __restrict__ x2, const float* __restrict__ stat2,
                          const float* __restrict__ g2, const float* __restrict__ b2,
                          ushort* __restrict__ xb2, int N2) {
    int i = blockIdx.x * 256 + threadIdx.x;
    float* x; const float* stat; const float* g; const float* b; ushort* xb; float invN;
    if (i < N1 * 32) { x = x1; stat = stat1; g = g1; b = b1; xb = xb1; invN = 1.0f / N1; }
    else {
        i -= N1 * 32;
        if (i >= N2 * 32) return;
        x = x2; stat = stat2; g = g2; b = b2; xb = xb2; invN = 1.0f / N2;
    }
    int c4 = (i & 31) << 2;
    float4 v = ((float4*)x)[i];
    float* vp = &v.x;
    #pragma unroll
    for (int j = 0; j < 4; ++j) {
        int c = c4 + j;
        float mu = stat[c] * invN;
        float var = stat[128 + c] * invN - mu * mu;
        float xn = (vp[j] - mu) * rsqrtf(var + 1e-5f) * g[c] + b[c];
        vp[j] = xn > 0.f ? xn : expm1f(xn);
    }
    ((float4*)x)[i] = v;
    if (xb) {
        ushort4 o;
        o.x = f2bf(v.x); o.y = f2bf(v.y); o.z = f2bf(v.z); o.w = f2bf(v.w);
        ((ushort4*)xb)[i] = o;
    }
}

// s[he_food[e]] += prefs[he_user[e]] * score[e]
__global__ void health_scatter(const int* __restrict__ hu, const int* __restrict__ hf,
                               const float* __restrict__ score, const float* __restrict__ prefs,
                               float* __restrict__ s, int E) {
    int e = blockIdx.x * 256 + threadIdx.x;
    if (e >= E) return;
    atomicAdd(&s[hf[e]], prefs[hu[e]] * score[e]);
}

// xf2[f][c] += 0.1 * s[f]
__global__ void add_health(float* __restrict__ xf2, const float* __restrict__ s, int n4) {
    int i = blockIdx.x * 256 + threadIdx.x;
    if (i >= n4) return;
    float sv = 0.1f * s[i >> 5];
    float4 v = ((float4*)xf2)[i];
    v.x += sv; v.y += sv; v.z += sv; v.w += sv;
    ((float4*)xf2)[i] = v;
}

// ---------------------------------------------------------------------------
extern "C" void kernel_launch(void* const* d_in, const int* in_sizes, int n_in,
                              void* d_out, int out_size, void* d_ws, size_t ws_size,
                              hipStream_t stream) {
    const float* x_user = (const float*)d_in[0];
    const float* x_food = (const float*)d_in[1];
    const int* uf_src = (const int*)d_in[2];
    const int* uf_dst = (const int*)d_in[3];
    const int* fu_src = (const int*)d_in[4];
    const int* fu_dst = (const int*)d_in[5];
    const int* he_user = (const int*)d_in[6];
    const int* he_food = (const int*)d_in[7];
    const float* scores = (const float*)d_in[8];
    const float* a1_uf_src = (const float*)d_in[11];
    const float* a1_uf_dst = (const float*)d_in[12];
    const float* b1_uf     = (const float*)d_in[13];
    const float* a1_fu_src = (const float*)d_in[16];
    const float* a1_fu_dst = (const float*)d_in[17];
    const float* b1_fu     = (const float*)d_in[18];
    const float* b2_uf     = (const float*)d_in[23];
    const float* b2_fu     = (const float*)d_in[28];
    const float* bn1_user_g = (const float*)d_in[29];
    const float* bn1_user_b = (const float*)d_in[30];
    const float* bn1_food_g = (const float*)d_in[31];
    const float* bn1_food_b = (const float*)d_in[32];
    const float* bn2_user_g = (const float*)d_in[33];
    const float* bn2_user_b = (const float*)d_in[34];
    const float* bn2_food_g = (const float*)d_in[35];
    const float* bn2_food_b = (const float*)d_in[36];
    const float* hw1 = (const float*)d_in[37];
    const float* hb1 = (const float*)d_in[38];
    const float* hw2 = (const float*)d_in[39];
    const float* hb2 = (const float*)d_in[40];

    float* outp  = (float*)d_out;
    float* xu2   = outp;                          // [NU,128]
    float* xf2   = outp + (size_t)NU_ * 128;      // [NF,128]
    float* prefs = xf2 + (size_t)NF_ * 128;       // [NU]

    // ---- workspace layout ----
    float* ws    = (float*)d_ws;
    float* hsf   = ws;                             // NU*128 slot (bf16 used: NU*128 ushort)
    ushort* hs   = (ushort*)hsf;
    float* xu1   = hsf  + (size_t)NU_ * 128;       // NU*128
    float* xf1   = xu1  + (size_t)NU_ * 128;       // NF*128
    float* asn   = xf1  + (size_t)NF_ * 128;       // NU
    float* adn   = asn  + NU_;                     // NU
    // --- zeroed-once region start ---
    float* stat4 = adn  + NU_;                     // 4*256 (one per BN instance)
    float* sbuf  = stat4 + 1024;                   // NF
    int*   deg_f = (int*)(sbuf + NF_);             // NF
    int*   deg_u = deg_f + NF_;                    // NU
    // --- zeroed-once region end ---
    float* vall  = (float*)(deg_u + NU_);          // 8*128
    int*   part  = (int*)(vall + 1024);            // 64
    int*   uf_off  = part + 64;                    // NF+4
    int*   fu_off  = uf_off + (NF_ + 4);           // NU+4
    int*   cursor  = fu_off + (NU_ + 4);           // NU (max)
    int*   uf_esrc = cursor + NU_;                 // E
    int*   fu_esrc = uf_esrc + E_;                 // E
    // bf16 buffers (ushort), 16B-aligned since previous sizes are /4
    ushort* bu   = (ushort*)(fu_esrc + E_);        // NU*128 (x_user -> xu1b -> xu2b)
    ushort* bfo  = bu + (size_t)NU_ * 128;         // NF*128 (x_food -> xf1b)
    ushort* wt0  = bfo + (size_t)NF_ * 128;        // 4 x 128*128 transposed weights
    ushort* wt1  = wt0 + 16384;
    ushort* wt2  = wt1 + 16384;
    ushort* wt3  = wt2 + 16384;
    ushort* hw1t = wt3 + 16384;                    // 64*128

    const size_t zero_elems = 1024 + NF_ + NF_ + NU_;
    hipMemsetAsync(stat4, 0, zero_elems * sizeof(float), stream);

    // --- bf16 conversions ---
    f2b_two<<<((NU_ + NF_) * 32 + 255) / 256, 256, 0, stream>>>(
        x_user, bu, NU_ * 32, x_food, bfo, NF_ * 32);
    WTArgs wt;
    wt.W[0] = (const float*)d_in[9];  wt.T[0] = wt0;  wt.shift[0] = 7;
    wt.W[1] = (const float*)d_in[14]; wt.T[1] = wt1;  wt.shift[1] = 7;
    wt.W[2] = (const float*)d_in[19]; wt.T[2] = wt2;  wt.shift[2] = 7;
    wt.W[3] = (const float*)d_in[24]; wt.T[3] = wt3;  wt.shift[3] = 7;
    wt.W[4] = hw1;                    wt.T[4] = hw1t; wt.shift[4] = 6;
    wt_conv<<<dim3(64, 5), 256, 0, stream>>>(wt);

    // --- precompute v = W@a for all 8 (dst-side GEMMs eliminated) ---
    WAArgs wa;
    wa.W[0] = (const float*)d_in[9];  wa.a[0] = a1_uf_src;
    wa.W[1] = (const float*)d_in[10]; wa.a[1] = a1_uf_dst;
    wa.W[2] = (const float*)d_in[14]; wa.a[2] = a1_fu_src;
    wa.W[3] = (const float*)d_in[15]; wa.a[3] = a1_fu_dst;
    wa.W[4] = (const float*)d_in[19]; wa.a[4] = (const float*)d_in[21];
    wa.W[5] = (const float*)d_in[20]; wa.a[5] = (const float*)d_in[22];
    wa.W[6] = (const float*)d_in[24]; wa.a[6] = (const float*)d_in[26];
    wa.W[7] = (const float*)d_in[25]; wa.a[7] = (const float*)d_in[27];
    wa_vec<<<8, 256, 0, stream>>>(wa, vall);

    // --- build CSR once per edge type (reused by both layers) ---
    const int EB = (E_ + 255) / 256;
    const int NBF = (NF_ + 1023) / 1024;   // 25
    const int NBU = (NU_ + 1023) / 1024;   // 49

    count_deg<<<EB, 256, 0, stream>>>(uf_dst, deg_f, E_);
    partial_sums<<<NBF, 256, 0, stream>>>(deg_f, part, NF_);
    scan_partials<<<1, 64, 0, stream>>>(part, &uf_off[NF_], NBF);
    block_scan<<<NBF, 256, 0, stream>>>(deg_f, part, uf_off, cursor, NF_);
    fill_csr<<<EB, 256, 0, stream>>>(uf_src, uf_dst, cursor, uf_esrc, E_);

    count_deg<<<EB, 256, 0, stream>>>(fu_dst, deg_u, E_);
    partial_sums<<<NBU, 256, 0, stream>>>(deg_u, part, NU_);
    scan_partials<<<1, 64, 0, stream>>>(part, &fu_off[NU_], NBU);
    block_scan<<<NBU, 256, 0, stream>>>(deg_u, part, fu_off, cursor, NU_);
    fill_csr<<<EB, 256, 0, stream>>>(fu_src, fu_dst, cursor, fu_esrc, E_);

    auto run_gat = [&](const ushort* xb, const ushort* xsb, const ushort* xdb,
                       const int* off, const int* esrc,
                       const ushort* wtb, const float* vs, const float* vd, const float* bias,
                       float* out, int Ns, int Nd) {
        gemm_mfma<<<(Ns + 127) / 128, 256, 0, stream>>>(xb, wtb, hs, Ns);
        matvec128x2<<<(Ns + Nd + 3) / 4, 256, 0, stream>>>(xsb, vs, asn, Ns, xdb, vd, adn, Nd);
        gat_aggregate_csr<<<(Nd + 3) / 4, 256, 0, stream>>>(off, esrc, asn, adn, hs, bias, out, Nd);
    };

    // ---- layer 1 ----
    run_gat(bu,  bu,  bfo, uf_off, uf_esrc, wt0, vall + 0,   vall + 128, b1_uf, xf1, NU_, NF_);
    run_gat(bfo, bfo, bu,  fu_off, fu_esrc, wt1, vall + 256, vall + 384, b1_fu, xu1, NF_, NU_);
    bn_stats2<<<512, 256, 0, stream>>>(xu1, stat4 + 0, NU_, 256, xf1, stat4 + 256, NF_);
    bn_apply2<<<((NU_ + NF_) * 32 + 255) / 256, 256, 0, stream>>>(
        xu1, stat4 + 0,   bn1_user_g, bn1_user_b, bu,  NU_,
        xf1, stat4 + 256, bn1_food_g, bn1_food_b, bfo, NF_);

    // ---- layer 2 (aggregate straight into d_out regions) ----
    run_gat(bu,  bu,  bfo, uf_off, uf_esrc, wt2, vall + 512, vall + 640, b2_uf, xf2, NU_, NF_);
    run_gat(bfo, bfo, bu,  fu_off, fu_esrc, wt3, vall + 768, vall + 896, b2_fu, xu2, NF_, NU_);
    bn_stats2<<<512, 256, 0, stream>>>(xu2, stat4 + 512, NU_, 256, xf2, stat4 + 768, NF_);
    bn_apply2<<<((NU_ + NF_) * 32 + 255) / 256, 256, 0, stream>>>(
        xu2, stat4 + 512, bn2_user_g, bn2_user_b, bu, NU_,
        xf2, stat4 + 768, bn2_food_g, bn2_food_b, (ushort*)nullptr, NF_);

    // ---- health preference MLP + scatter update ----
    mlp_mfma<<<(NU_ + 127) / 128, 256, 0, stream>>>(bu, hw1t, hb1, hw2, hb2, prefs, NU_);
    health_scatter<<<EB, 256, 0, stream>>>(he_user, he_food, scores, prefs, sbuf, E_);
    add_health<<<(NF_ * 32 + 255) / 256, 256, 0, stream>>>(xf2, sbuf, NF_ * 32);
}

// Round 6
// 492.769 us; speedup vs baseline: 4.8553x; 1.0980x over previous
//
#include <hip/hip_runtime.h>
#include <cstddef>

#define NU_ 50000
#define NF_ 25000
#define E_  500000

typedef __attribute__((ext_vector_type(8))) short short8v;
typedef __attribute__((ext_vector_type(4))) float float4v;

static __device__ __forceinline__ ushort f2bf(float f) {
    uint u = __float_as_uint(f);
    uint r = (u + 0x7fffu + ((u >> 16) & 1u)) >> 16;   // RNE
    return (ushort)r;
}
static __device__ __forceinline__ float bf2f(ushort u) {
    return __uint_as_float(((uint)u) << 16);
}

// ---------------------------------------------------------------------------
// v = W @ a  (v[k] = sum_h W[k][h] * a[h]) for 8 (W,a) pairs, one block each.
// ---------------------------------------------------------------------------
struct WAArgs {
    const float* W[8];
    const float* a[8];
};

__global__ __launch_bounds__(256) void wa_vec(WAArgs args, float* __restrict__ vout) {
    __shared__ float Ws[128][129];
    __shared__ float as[128];
    const int b = blockIdx.x;
    const float* W = args.W[b];
    const float* a = args.a[b];
    for (int i = threadIdx.x; i < 128 * 32; i += 256) {
        float4 w = ((const float4*)W)[i];
        int r = i >> 5, c = (i & 31) << 2;
        Ws[r][c] = w.x; Ws[r][c + 1] = w.y; Ws[r][c + 2] = w.z; Ws[r][c + 3] = w.w;
    }
    if (threadIdx.x < 128) as[threadIdx.x] = a[threadIdx.x];
    __syncthreads();
    if (threadIdx.x < 128) {
        float s = 0.f;
        #pragma unroll 8
        for (int h = 0; h < 128; ++h) s += Ws[threadIdx.x][h] * as[h];
        vout[b * 128 + threadIdx.x] = s;
    }
}

// ---------------------------------------------------------------------------
// fp32 -> bf16 bulk convert for both feature matrices in one launch
// ---------------------------------------------------------------------------
__global__ void f2b_two(const float* __restrict__ a, ushort* __restrict__ da, int n4a,
                        const float* __restrict__ b, ushort* __restrict__ db, int n4b) {
    int i = blockIdx.x * 256 + threadIdx.x;
    const float* s; ushort* d; int idx;
    if (i < n4a) { s = a; d = da; idx = i; }
    else {
        idx = i - n4a;
        if (idx >= n4b) return;
        s = b; d = db;
    }
    float4 v = ((const float4*)s)[idx];
    ushort4 o;
    o.x = f2bf(v.x); o.y = f2bf(v.y); o.z = f2bf(v.z); o.w = f2bf(v.w);
    ((ushort4*)d)[idx] = o;
}

// ---------------------------------------------------------------------------
// Weight convert: Wt[c][k] = bf16(W[k][c]); 5 matrices in one launch (grid.y)
// ---------------------------------------------------------------------------
struct WTArgs {
    const float* W[5];
    ushort* T[5];
    int shift[5];   // log2(ncols)
};

__global__ void wt_conv(WTArgs args) {
    const int m = blockIdx.y;
    const float* W = args.W[m];
    ushort* T = args.T[m];
    const int sh = args.shift[m];
    const int ncols = 1 << sh;
    const int total = 128 << sh;
    int idx = blockIdx.x * 256 + threadIdx.x;
    if (idx >= total) return;
    int k = idx >> sh, c = idx & (ncols - 1);
    T[c * 128 + k] = f2bf(W[idx]);
}

// ---------------------------------------------------------------------------
// C[N,128] bf16 = Xb[N,128] bf16 @ W[128,128] (Wt transposed bf16)
// MFMA 16x16x32, 128-row tile, K=128 single-shot, 4 waves (2x2).
// ---------------------------------------------------------------------------
__global__ __launch_bounds__(256) void gemm_mfma(const ushort* __restrict__ Xb,
                                                 const ushort* __restrict__ Wt,
                                                 ushort* __restrict__ C, int N) {
    constexpr int LDR = 136;
    __shared__ short Xs[128 * LDR];
    __shared__ short Ws[128 * LDR];
    const int t = threadIdx.x;
    const int row0 = blockIdx.x * 128;

    for (int i = t; i < 128 * 16; i += 256) {
        int r = i >> 4, c8 = (i & 15) << 3;
        short8v v = {};
        if (row0 + r < N) v = *(const short8v*)(Xb + (size_t)(row0 + r) * 128 + c8);
        *(short8v*)(&Xs[r * LDR + c8]) = v;
    }
    for (int i = t; i < 128 * 16; i += 256) {
        int r = i >> 4, c8 = (i & 15) << 3;
        *(short8v*)(&Ws[r * LDR + c8]) = *(const short8v*)(Wt + r * 128 + c8);
    }
    __syncthreads();

    const int w = t >> 6, l = t & 63;
    const int wm = w & 1, wn = w >> 1;
    const int m0 = wm * 64;
    const int n0 = wn * 64;
    const int frow = l & 15;
    const int koff = (l >> 4) << 3;

    float4v acc[4][4];
    #pragma unroll
    for (int m = 0; m < 4; ++m)
        #pragma unroll
        for (int n = 0; n < 4; ++n) acc[m][n] = (float4v)0.f;

    #pragma unroll
    for (int ks = 0; ks < 4; ++ks) {
        const int k0 = ks * 32 + koff;
        short8v a[4], b[4];
        #pragma unroll
        for (int m = 0; m < 4; ++m)
            a[m] = *(const short8v*)(&Xs[(m0 + m * 16 + frow) * LDR + k0]);
        #pragma unroll
        for (int n = 0; n < 4; ++n)
            b[n] = *(const short8v*)(&Ws[(n0 + n * 16 + frow) * LDR + k0]);
        #pragma unroll
        for (int m = 0; m < 4; ++m)
            #pragma unroll
            for (int n = 0; n < 4; ++n)
                acc[m][n] = __builtin_amdgcn_mfma_f32_16x16x32_bf16(a[m], b[n], acc[m][n], 0, 0, 0);
    }

    // C/D layout: col = l&15, row = (l>>4)*4 + reg
    const int crow = (l >> 4) << 2;
    const int ccol = l & 15;
    #pragma unroll
    for (int m = 0; m < 4; ++m) {
        #pragma unroll
        for (int r4 = 0; r4 < 4; ++r4) {
            int grow = row0 + m0 + m * 16 + crow + r4;
            if (grow < N) {
                #pragma unroll
                for (int n = 0; n < 4; ++n)
                    C[(size_t)grow * 128 + n0 + n * 16 + ccol] = f2bf(acc[m][n][r4]);
            }
        }
    }
}

// ---------------------------------------------------------------------------
// Fused MLP: prefs[u] = tanh( leaky_relu(Xb[u]@hw1 + hb1, 0.01) @ hw2 + hb2 )
// ---------------------------------------------------------------------------
__global__ __launch_bounds__(256) void mlp_mfma(const ushort* __restrict__ Xb,
                                                const ushort* __restrict__ Wt,   // hw1t [64][128]
                                                const float* __restrict__ hb1,
                                                const float* __restrict__ hw2,
                                                const float* __restrict__ hb2,
                                                float* __restrict__ prefs, int N) {
    constexpr int LDR = 136;
    __shared__ short Xs[128 * LDR];
    __shared__ short Ws[64 * LDR];
    const int t = threadIdx.x;
    const int row0 = blockIdx.x * 128;

    for (int i = t; i < 128 * 16; i += 256) {
        int r = i >> 4, c8 = (i & 15) << 3;
        short8v v = {};
        if (row0 + r < N) v = *(const short8v*)(Xb + (size_t)(row0 + r) * 128 + c8);
        *(short8v*)(&Xs[r * LDR + c8]) = v;
    }
    for (int i = t; i < 64 * 16; i += 256) {
        int r = i >> 4, c8 = (i & 15) << 3;
        *(short8v*)(&Ws[r * LDR + c8]) = *(const short8v*)(Wt + r * 128 + c8);
    }
    __syncthreads();

    const int w = t >> 6, l = t & 63;
    const int m0 = w * 32;
    const int frow = l & 15;
    const int koff = (l >> 4) << 3;

    float4v acc[2][4];
    #pragma unroll
    for (int m = 0; m < 2; ++m)
        #pragma unroll
        for (int n = 0; n < 4; ++n) acc[m][n] = (float4v)0.f;

    #pragma unroll
    for (int ks = 0; ks < 4; ++ks) {
        const int k0 = ks * 32 + koff;
        short8v a[2], b[4];
        #pragma unroll
        for (int m = 0; m < 2; ++m)
            a[m] = *(const short8v*)(&Xs[(m0 + m * 16 + frow) * LDR + k0]);
        #pragma unroll
        for (int n = 0; n < 4; ++n)
            b[n] = *(const short8v*)(&Ws[(n * 16 + frow) * LDR + k0]);
        #pragma unroll
        for (int m = 0; m < 2; ++m)
            #pragma unroll
            for (int n = 0; n < 4; ++n)
                acc[m][n] = __builtin_amdgcn_mfma_f32_16x16x32_bf16(a[m], b[n], acc[m][n], 0, 0, 0);
    }

    float hb1v[4], hw2v[4];
    #pragma unroll
    for (int n = 0; n < 4; ++n) {
        int col = n * 16 + (l & 15);
        hb1v[n] = hb1[col];
        hw2v[n] = hw2[col];
    }
    const float hb2v = hb2[0];
    #pragma unroll
    for (int m = 0; m < 2; ++m) {
        #pragma unroll
        for (int r4 = 0; r4 < 4; ++r4) {
            float p = 0.f;
            #pragma unroll
            for (int n = 0; n < 4; ++n) {
                float v = acc[m][n][r4] + hb1v[n];
                v = v > 0.f ? v : 0.01f * v;
                p += v * hw2v[n];
            }
            p += __shfl_xor(p, 1);
            p += __shfl_xor(p, 2);
            p += __shfl_xor(p, 4);
            p += __shfl_xor(p, 8);
            int grow = row0 + m0 + m * 16 + ((l >> 4) << 2) + r4;
            if ((l & 15) == 0 && grow < N) prefs[grow] = tanhf(p + hb2v);
        }
    }
}

// ---------------------------------------------------------------------------
// Fused pair of matvecs on bf16 features.
// ---------------------------------------------------------------------------
__global__ __launch_bounds__(256) void matvec128x2(const ushort* __restrict__ Xsp, const float* __restrict__ vs,
                                                   float* __restrict__ outs, int Ns,
                                                   const ushort* __restrict__ Xdp, const float* __restrict__ vd,
                                                   float* __restrict__ outd, int Nd) {
    int row = blockIdx.x * 4 + (threadIdx.x >> 6);
    int lane = threadIdx.x & 63;
    const ushort* X; const float* v; float* out; int r;
    if (row < Ns) { X = Xsp; v = vs; out = outs; r = row; }
    else {
        r = row - Ns;
        if (r >= Nd) return;
        X = Xdp; v = vd; out = outd;
    }
    ushort2 x = ((const ushort2*)(X + (size_t)r * 128))[lane];
    float2 vv = ((const float2*)v)[lane];
    float s = bf2f(x.x) * vv.x + bf2f(x.y) * vv.y;
    #pragma unroll
    for (int off = 32; off; off >>= 1) s += __shfl_xor(s, off);
    if (lane == 0) out[r] = s;
}

// ---------------------------------------------------------------------------
// CSR build: histogram -> multi-block exclusive scan -> cursor fill
// ---------------------------------------------------------------------------
__global__ void count_deg(const int* __restrict__ dst, int* __restrict__ deg, int E) {
    int e = blockIdx.x * 256 + threadIdx.x;
    if (e < E) atomicAdd(&deg[dst[e]], 1);
}

__global__ __launch_bounds__(256) void partial_sums(const int* __restrict__ deg,
                                                    int* __restrict__ part, int N) {
    __shared__ int wsum[4];
    int base = blockIdx.x * 1024;
    int s = 0;
    for (int i = threadIdx.x; i < 1024; i += 256) {
        int idx = base + i;
        if (idx < N) s += deg[idx];
    }
    #pragma unroll
    for (int o = 32; o; o >>= 1) s += __shfl_xor(s, o);
    if ((threadIdx.x & 63) == 0) wsum[threadIdx.x >> 6] = s;
    __syncthreads();
    if (threadIdx.x == 0) part[blockIdx.x] = wsum[0] + wsum[1] + wsum[2] + wsum[3];
}

__global__ __launch_bounds__(64) void scan_partials(int* __restrict__ part,
                                                    int* __restrict__ offN, int nb) {
    int lane = threadIdx.x;
    int v = (lane < nb) ? part[lane] : 0;
    int incl = v;
    #pragma unroll
    for (int o = 1; o < 64; o <<= 1) {
        int t = __shfl_up(incl, o);
        if (lane >= o) incl += t;
    }
    if (lane < nb) part[lane] = incl - v;
    if (lane == 63) *offN = incl;
}

__global__ __launch_bounds__(256) void block_scan(const int* __restrict__ deg,
                                                  const int* __restrict__ part,
                                                  int* __restrict__ off,
                                                  int* __restrict__ cursor, int N) {
    __shared__ int wsum[4];
    int t = threadIdx.x;
    int lane = t & 63, w = t >> 6;
    int base = blockIdx.x * 1024 + t * 4;
    int l0 = 0, l1 = 0, l2 = 0, l3 = 0;
    if (base + 3 < N) {
        int4 v = *(const int4*)(deg + base);
        l0 = v.x; l1 = v.y; l2 = v.z; l3 = v.w;
    } else {
        if (base + 0 < N) l0 = deg[base + 0];
        if (base + 1 < N) l1 = deg[base + 1];
        if (base + 2 < N) l2 = deg[base + 2];
    }
    int tsum = l0 + l1 + l2 + l3;
    int incl = tsum;
    #pragma unroll
    for (int o = 1; o < 64; o <<= 1) {
        int tt = __shfl_up(incl, o);
        if (lane >= o) incl += tt;
    }
    int lexcl = incl - tsum;
    if (lane == 63) wsum[w] = incl;
    __syncthreads();
    int p = part[blockIdx.x] + lexcl;
    for (int i = 0; i < w; ++i) p += wsum[i];
    if (base + 0 < N) { off[base + 0] = p; cursor[base + 0] = p; } p += l0;
    if (base + 1 < N) { off[base + 1] = p; cursor[base + 1] = p; } p += l1;
    if (base + 2 < N) { off[base + 2] = p; cursor[base + 2] = p; } p += l2;
    if (base + 3 < N) { off[base + 3] = p; cursor[base + 3] = p; }
}

__global__ void fill_csr(const int* __restrict__ src, const int* __restrict__ dst,
                         int* __restrict__ cursor, int* __restrict__ esrc, int E) {
    int e = blockIdx.x * 256 + threadIdx.x;
    if (e >= E) return;
    int p = atomicAdd(&cursor[dst[e]], 1);
    esrc[p] = src[e];
}

// ---------------------------------------------------------------------------
// Fused GAT softmax + aggregate, one wave per destination node, bf16 gathers.
// Quarter-wave rows (16 lanes x ushort8 = 256B), 8 edges in flight (2/qwave).
// ---------------------------------------------------------------------------
__global__ __launch_bounds__(256) void gat_aggregate_csr(const int* __restrict__ off,
                                                         const int* __restrict__ esrc,
                                                         const float* __restrict__ asn,
                                                         const float* __restrict__ adn,
                                                         const ushort* __restrict__ hs,
                                                         const float* __restrict__ bias,
                                                         float* __restrict__ out, int Nd) {
    int d = blockIdx.x * 4 + (threadIdx.x >> 6);
    int lane = threadIdx.x & 63;
    if (d >= Nd) return;
    const int beg = off[d], end = off[d + 1];
    const float ad = adn[d];
    const int qw = lane >> 4, l16 = lane & 15;
    float acc[8] = {0.f, 0.f, 0.f, 0.f, 0.f, 0.f, 0.f, 0.f};
    float den = 0.f;
    for (int base = beg; base < end; base += 64) {
        int e = base + lane;
        int s = 0; float ev = 0.f;        // inactive lanes: ev=0, s=0 (row-0 load harmless)
        if (e < end) {
            s = esrc[e];
            float v = asn[s] + ad;
            v = v > 0.f ? v : 0.2f * v;
            ev = __expf(v);
        }
        float r = ev;
        #pragma unroll
        for (int o = 32; o; o >>= 1) r += __shfl_xor(r, o);
        den += r;
        int cnt4 = (min(64, end - base) + 3) & ~3;
        for (int j = 0; j < cnt4; j += 8) {
            int jj = j + qw;
            float ev0 = __shfl(ev, jj);
            int   sj0 = __shfl(s, jj);
            short8v h0 = *(const short8v*)(hs + (size_t)sj0 * 128 + l16 * 8);
            if (j + 4 < cnt4) {                  // wave-uniform
                float ev1 = __shfl(ev, jj + 4);
                int   sj1 = __shfl(s, jj + 4);
                short8v h1 = *(const short8v*)(hs + (size_t)sj1 * 128 + l16 * 8);
                #pragma unroll
                for (int k = 0; k < 8; ++k)
                    acc[k] += ev0 * bf2f((ushort)h0[k]) + ev1 * bf2f((ushort)h1[k]);
            } else {
                #pragma unroll
                for (int k = 0; k < 8; ++k)
                    acc[k] += ev0 * bf2f((ushort)h0[k]);
            }
        }
    }
    // reduce across the 4 quarter-waves
    #pragma unroll
    for (int k = 0; k < 8; ++k) {
        acc[k] += __shfl_xor(acc[k], 16);
        acc[k] += __shfl_xor(acc[k], 32);
    }
    if (qw == 0) {
        float inv = 1.f / (den + 1e-16f);
        float4 b0 = ((const float4*)bias)[l16 * 2];
        float4 b1 = ((const float4*)bias)[l16 * 2 + 1];
        float4* op = (float4*)(out + (size_t)d * 128 + l16 * 8);
        op[0] = make_float4(acc[0] * inv + b0.x, acc[1] * inv + b0.y,
                            acc[2] * inv + b0.z, acc[3] * inv + b0.w);
        op[1] = make_float4(acc[4] * inv + b1.x, acc[5] * inv + b1.y,
                            acc[6] * inv + b1.z, acc[7] * inv + b1.w);
    }
}

// ---------------------------------------------------------------------------
// BatchNorm stats for TWO tensors, vectorized float4 per lane.
// Block covers 8 rows x 128 cols per iteration; register accumulation;
// shfl + LDS reduce; 256 atomics per block.
// ---------------------------------------------------------------------------
__global__ __launch_bounds__(256) void bn_stats2(const float* __restrict__ x1, float* __restrict__ stat1,
                                                 int N1, int B1,
                                                 const float* __restrict__ x2, float* __restrict__ stat2,
                                                 int N2, int B2) {
    const float* x; float* stat; int N, b, nb;
    if ((int)blockIdx.x < B1) { x = x1; stat = stat1; N = N1; b = blockIdx.x; nb = B1; }
    else { x = x2; stat = stat2; N = N2; b = blockIdx.x - B1; nb = B2; }
    const int t = threadIdx.x;
    const int rg = t >> 5;          // row within 8-row group
    const int c32 = t & 31;         // float4 column index
    float s[4] = {0.f, 0.f, 0.f, 0.f}, q[4] = {0.f, 0.f, 0.f, 0.f};
    for (int r = b * 8 + rg; r < N; r += nb * 8) {
        float4 v = ((const float4*)(x + (size_t)r * 128))[c32];
        s[0] += v.x; q[0] += v.x * v.x;
        s[1] += v.y; q[1] += v.y * v.y;
        s[2] += v.z; q[2] += v.z * v.z;
        s[3] += v.w; q[3] += v.w * v.w;
    }
    #pragma unroll
    for (int k = 0; k < 4; ++k) {
        s[k] += __shfl_xor(s[k], 32);
        q[k] += __shfl_xor(q[k], 32);
    }
    __shared__ float rs[4][128], rq[4][128];
    const int w = t >> 6, l = t & 63;
    if (l < 32) {
        #pragma unroll
        for (int k = 0; k < 4; ++k) {
            rs[w][c32 * 4 + k] = s[k];
            rq[w][c32 * 4 + k] = q[k];
        }
    }
    __syncthreads();
    if (t < 128) {
        float ts = rs[0][t] + rs[1][t] + rs[2][t] + rs[3][t];
        float tq = rq[0][t] + rq[1][t] + rq[2][t] + rq[3][t];
        atomicAdd(&stat[t], ts);
        atomicAdd(&stat[128 + t], tq);
    }
}

__global__ void bn_apply2(float* __restrict__ x1, const float* __restrict__ stat1,
                          const float* __restrict__ g1, const float* __restrict__ b1,
                          ushort* __restrict__ xb1, int N1,
                          float* __restrict__ x2, const float* __restrict__ stat2,
                          const float* __restrict__ g2, const float* __restrict__ b2,
                          ushort* __restrict__ xb2, int N2) {
    int i = blockIdx.x * 256 + threadIdx.x;
    float* x; const float* stat; const float* g; const float* b; ushort* xb; float invN;
    if (i < N1 * 32) { x = x1; stat = stat1; g = g1; b = b1; xb = xb1; invN = 1.0f / N1; }
    else {
        i -= N1 * 32;
        if (i >= N2 * 32) return;
        x = x2; stat = stat2; g = g2; b = b2; xb = xb2; invN = 1.0f / N2;
    }
    int c4 = (i & 31) << 2;
    float4 v = ((float4*)x)[i];
    float* vp = &v.x;
    #pragma unroll
    for (int j = 0; j < 4; ++j) {
        int c = c4 + j;
        float mu = stat[c] * invN;
        float var = stat[128 + c] * invN - mu * mu;
        float xn = (vp[j] - mu) * rsqrtf(var + 1e-5f) * g[c] + b[c];
        vp[j] = xn > 0.f ? xn : expm1f(xn);
    }
    ((float4*)x)[i] = v;
    if (xb) {
        ushort4 o;
        o.x = f2bf(v.x); o.y = f2bf(v.y); o.z = f2bf(v.z); o.w = f2bf(v.w);
        ((ushort4*)xb)[i] = o;
    }
}

// s[he_food[e]] += prefs[he_user[e]] * score[e]
__global__ void health_scatter(const int* __restrict__ hu, const int* __restrict__ hf,
                               const float* __restrict__ score, const float* __restrict__ prefs,
                               float* __restrict__ s, int E) {
    int e = blockIdx.x * 256 + threadIdx.x;
    if (e >= E) return;
    atomicAdd(&s[hf[e]], prefs[hu[e]] * score[e]);
}

// xf2[f][c] += 0.1 * s[f]
__global__ void add_health(float* __restrict__ xf2, const float* __restrict__ s, int n4) {
    int i = blockIdx.x * 256 + threadIdx.x;
    if (i >= n4) return;
    float sv = 0.1f * s[i >> 5];
    float4 v = ((float4*)xf2)[i];
    v.x += sv; v.y += sv; v.z += sv; v.w += sv;
    ((float4*)xf2)[i] = v;
}

// ---------------------------------------------------------------------------
extern "C" void kernel_launch(void* const* d_in, const int* in_sizes, int n_in,
                              void* d_out, int out_size, void* d_ws, size_t ws_size,
                              hipStream_t stream) {
    const float* x_user = (const float*)d_in[0];
    const float* x_food = (const float*)d_in[1];
    const int* uf_src = (const int*)d_in[2];
    const int* uf_dst = (const int*)d_in[3];
    const int* fu_src = (const int*)d_in[4];
    const int* fu_dst = (const int*)d_in[5];
    const int* he_user = (const int*)d_in[6];
    const int* he_food = (const int*)d_in[7];
    const float* scores = (const float*)d_in[8];
    const float* a1_uf_src = (const float*)d_in[11];
    const float* a1_uf_dst = (const float*)d_in[12];
    const float* b1_uf     = (const float*)d_in[13];
    const float* a1_fu_src = (const float*)d_in[16];
    const float* a1_fu_dst = (const float*)d_in[17];
    const float* b1_fu     = (const float*)d_in[18];
    const float* b2_uf     = (const float*)d_in[23];
    const float* b2_fu     = (const float*)d_in[28];
    const float* bn1_user_g = (const float*)d_in[29];
    const float* bn1_user_b = (const float*)d_in[30];
    const float* bn1_food_g = (const float*)d_in[31];
    const float* bn1_food_b = (const float*)d_in[32];
    const float* bn2_user_g = (const float*)d_in[33];
    const float* bn2_user_b = (const float*)d_in[34];
    const float* bn2_food_g = (const float*)d_in[35];
    const float* bn2_food_b = (const float*)d_in[36];
    const float* hw1 = (const float*)d_in[37];
    const float* hb1 = (const float*)d_in[38];
    const float* hw2 = (const float*)d_in[39];
    const float* hb2 = (const float*)d_in[40];

    float* outp  = (float*)d_out;
    float* xu2   = outp;                          // [NU,128]
    float* xf2   = outp + (size_t)NU_ * 128;      // [NF,128]
    float* prefs = xf2 + (size_t)NF_ * 128;       // [NU]

    // ---- workspace layout ----
    float* ws    = (float*)d_ws;
    float* hsf   = ws;                             // NU*128 slot (bf16 used: NU*128 ushort)
    ushort* hs   = (ushort*)hsf;
    float* xu1   = hsf  + (size_t)NU_ * 128;       // NU*128
    float* xf1   = xu1  + (size_t)NU_ * 128;       // NF*128
    float* asn   = xf1  + (size_t)NF_ * 128;       // NU
    float* adn   = asn  + NU_;                     // NU
    // --- zeroed-once region start ---
    float* stat4 = adn  + NU_;                     // 4*256 (one per BN instance)
    float* sbuf  = stat4 + 1024;                   // NF
    int*   deg_f = (int*)(sbuf + NF_);             // NF
    int*   deg_u = deg_f + NF_;                    // NU
    // --- zeroed-once region end ---
    float* vall  = (float*)(deg_u + NU_);          // 8*128
    int*   part  = (int*)(vall + 1024);            // 64
    int*   uf_off  = part + 64;                    // NF+4
    int*   fu_off  = uf_off + (NF_ + 4);           // NU+4
    int*   cursor  = fu_off + (NU_ + 4);           // NU (max)
    int*   uf_esrc = cursor + NU_;                 // E
    int*   fu_esrc = uf_esrc + E_;                 // E
    // bf16 buffers (ushort), 16B-aligned since previous sizes are /4
    ushort* bu   = (ushort*)(fu_esrc + E_);        // NU*128 (x_user -> xu1b -> xu2b)
    ushort* bfo  = bu + (size_t)NU_ * 128;         // NF*128 (x_food -> xf1b)
    ushort* wt0  = bfo + (size_t)NF_ * 128;        // 4 x 128*128 transposed weights
    ushort* wt1  = wt0 + 16384;
    ushort* wt2  = wt1 + 16384;
    ushort* wt3  = wt2 + 16384;
    ushort* hw1t = wt3 + 16384;                    // 64*128

    const size_t zero_elems = 1024 + NF_ + NF_ + NU_;
    hipMemsetAsync(stat4, 0, zero_elems * sizeof(float), stream);

    // --- bf16 conversions ---
    f2b_two<<<((NU_ + NF_) * 32 + 255) / 256, 256, 0, stream>>>(
        x_user, bu, NU_ * 32, x_food, bfo, NF_ * 32);
    WTArgs wt;
    wt.W[0] = (const float*)d_in[9];  wt.T[0] = wt0;  wt.shift[0] = 7;
    wt.W[1] = (const float*)d_in[14]; wt.T[1] = wt1;  wt.shift[1] = 7;
    wt.W[2] = (const float*)d_in[19]; wt.T[2] = wt2;  wt.shift[2] = 7;
    wt.W[3] = (const float*)d_in[24]; wt.T[3] = wt3;  wt.shift[3] = 7;
    wt.W[4] = hw1;                    wt.T[4] = hw1t; wt.shift[4] = 6;
    wt_conv<<<dim3(64, 5), 256, 0, stream>>>(wt);

    // --- precompute v = W@a for all 8 (dst-side GEMMs eliminated) ---
    WAArgs wa;
    wa.W[0] = (const float*)d_in[9];  wa.a[0] = a1_uf_src;
    wa.W[1] = (const float*)d_in[10]; wa.a[1] = a1_uf_dst;
    wa.W[2] = (const float*)d_in[14]; wa.a[2] = a1_fu_src;
    wa.W[3] = (const float*)d_in[15]; wa.a[3] = a1_fu_dst;
    wa.W[4] = (const float*)d_in[19]; wa.a[4] = (const float*)d_in[21];
    wa.W[5] = (const float*)d_in[20]; wa.a[5] = (const float*)d_in[22];
    wa.W[6] = (const float*)d_in[24]; wa.a[6] = (const float*)d_in[26];
    wa.W[7] = (const float*)d_in[25]; wa.a[7] = (const float*)d_in[27];
    wa_vec<<<8, 256, 0, stream>>>(wa, vall);

    // --- build CSR once per edge type (reused by both layers) ---
    const int EB = (E_ + 255) / 256;
    const int NBF = (NF_ + 1023) / 1024;   // 25
    const int NBU = (NU_ + 1023) / 1024;   // 49

    count_deg<<<EB, 256, 0, stream>>>(uf_dst, deg_f, E_);
    partial_sums<<<NBF, 256, 0, stream>>>(deg_f, part, NF_);
    scan_partials<<<1, 64, 0, stream>>>(part, &uf_off[NF_], NBF);
    block_scan<<<NBF, 256, 0, stream>>>(deg_f, part, uf_off, cursor, NF_);
    fill_csr<<<EB, 256, 0, stream>>>(uf_src, uf_dst, cursor, uf_esrc, E_);

    count_deg<<<EB, 256, 0, stream>>>(fu_dst, deg_u, E_);
    partial_sums<<<NBU, 256, 0, stream>>>(deg_u, part, NU_);
    scan_partials<<<1, 64, 0, stream>>>(part, &fu_off[NU_], NBU);
    block_scan<<<NBU, 256, 0, stream>>>(deg_u, part, fu_off, cursor, NU_);
    fill_csr<<<EB, 256, 0, stream>>>(fu_src, fu_dst, cursor, fu_esrc, E_);

    auto run_gat = [&](const ushort* xb, const ushort* xsb, const ushort* xdb,
                       const int* off, const int* esrc,
                       const ushort* wtb, const float* vs, const float* vd, const float* bias,
                       float* out, int Ns, int Nd) {
        gemm_mfma<<<(Ns + 127) / 128, 256, 0, stream>>>(xb, wtb, hs, Ns);
        matvec128x2<<<(Ns + Nd + 3) / 4, 256, 0, stream>>>(xsb, vs, asn, Ns, xdb, vd, adn, Nd);
        gat_aggregate_csr<<<(Nd + 3) / 4, 256, 0, stream>>>(off, esrc, asn, adn, hs, bias, out, Nd);
    };

    // ---- layer 1 ----
    run_gat(bu,  bu,  bfo, uf_off, uf_esrc, wt0, vall + 0,   vall + 128, b1_uf, xf1, NU_, NF_);
    run_gat(bfo, bfo, bu,  fu_off, fu_esrc, wt1, vall + 256, vall + 384, b1_fu, xu1, NF_, NU_);
    bn_stats2<<<768, 256, 0, stream>>>(xu1, stat4 + 0, NU_, 512, xf1, stat4 + 256, NF_, 256);
    bn_apply2<<<((NU_ + NF_) * 32 + 255) / 256, 256, 0, stream>>>(
        xu1, stat4 + 0,   bn1_user_g, bn1_user_b, bu,  NU_,
        xf1, stat4 + 256, bn1_food_g, bn1_food_b, bfo, NF_);

    // ---- layer 2 (aggregate straight into d_out regions) ----
    run_gat(bu,  bu,  bfo, uf_off, uf_esrc, wt2, vall + 512, vall + 640, b2_uf, xf2, NU_, NF_);
    run_gat(bfo, bfo, bu,  fu_off, fu_esrc, wt3, vall + 768, vall + 896, b2_fu, xu2, NF_, NU_);
    bn_stats2<<<768, 256, 0, stream>>>(xu2, stat4 + 512, NU_, 512, xf2, stat4 + 768, NF_, 256);
    bn_apply2<<<((NU_ + NF_) * 32 + 255) / 256, 256, 0, stream>>>(
        xu2, stat4 + 512, bn2_user_g, bn2_user_b, bu, NU_,
        xf2, stat4 + 768, bn2_food_g, bn2_food_b, (ushort*)nullptr, NF_);

    // ---- health preference MLP + scatter update ----
    mlp_mfma<<<(NU_ + 127) / 128, 256, 0, stream>>>(bu, hw1t, hb1, hw2, hb2, prefs, NU_);
    health_scatter<<<EB, 256, 0, stream>>>(he_user, he_food, scores, prefs, sbuf, E_);
    add_health<<<(NF_ * 32 + 255) / 256, 256, 0, stream>>>(xf2, sbuf, NF_ * 32);
}

// Round 7
// 444.420 us; speedup vs baseline: 5.3835x; 1.1088x over previous
//
#include <hip/hip_runtime.h>
#include <cstddef>

#define NU_ 50000
#define NF_ 25000
#define E_  500000

typedef __attribute__((ext_vector_type(8))) short short8v;
typedef __attribute__((ext_vector_type(4))) float float4v;

static __device__ __forceinline__ ushort f2bf(float f) {
    uint u = __float_as_uint(f);
    uint r = (u + 0x7fffu + ((u >> 16) & 1u)) >> 16;   // RNE
    return (ushort)r;
}
static __device__ __forceinline__ float bf2f(ushort u) {
    return __uint_as_float(((uint)u) << 16);
}

// ---------------------------------------------------------------------------
// v = W @ a  (v[k] = sum_h W[k][h] * a[h]) for 8 (W,a) pairs, one block each.
// ---------------------------------------------------------------------------
struct WAArgs {
    const float* W[8];
    const float* a[8];
};

__global__ __launch_bounds__(256) void wa_vec(WAArgs args, float* __restrict__ vout) {
    __shared__ float Ws[128][129];
    __shared__ float as[128];
    const int b = blockIdx.x;
    const float* W = args.W[b];
    const float* a = args.a[b];
    for (int i = threadIdx.x; i < 128 * 32; i += 256) {
        float4 w = ((const float4*)W)[i];
        int r = i >> 5, c = (i & 31) << 2;
        Ws[r][c] = w.x; Ws[r][c + 1] = w.y; Ws[r][c + 2] = w.z; Ws[r][c + 3] = w.w;
    }
    if (threadIdx.x < 128) as[threadIdx.x] = a[threadIdx.x];
    __syncthreads();
    if (threadIdx.x < 128) {
        float s = 0.f;
        #pragma unroll 8
        for (int h = 0; h < 128; ++h) s += Ws[threadIdx.x][h] * as[h];
        vout[b * 128 + threadIdx.x] = s;
    }
}

// ---------------------------------------------------------------------------
// fp32 -> bf16 bulk convert for both feature matrices in one launch
// ---------------------------------------------------------------------------
__global__ void f2b_two(const float* __restrict__ a, ushort* __restrict__ da, int n4a,
                        const float* __restrict__ b, ushort* __restrict__ db, int n4b) {
    int i = blockIdx.x * 256 + threadIdx.x;
    const float* s; ushort* d; int idx;
    if (i < n4a) { s = a; d = da; idx = i; }
    else {
        idx = i - n4a;
        if (idx >= n4b) return;
        s = b; d = db;
    }
    float4 v = ((const float4*)s)[idx];
    ushort4 o;
    o.x = f2bf(v.x); o.y = f2bf(v.y); o.z = f2bf(v.z); o.w = f2bf(v.w);
    ((ushort4*)d)[idx] = o;
}

// ---------------------------------------------------------------------------
// Weight convert: Wt[c][k] = bf16(W[k][c]); 5 matrices in one launch (grid.y)
// ---------------------------------------------------------------------------
struct WTArgs {
    const float* W[5];
    ushort* T[5];
    int shift[5];   // log2(ncols)
};

__global__ void wt_conv(WTArgs args) {
    const int m = blockIdx.y;
    const float* W = args.W[m];
    ushort* T = args.T[m];
    const int sh = args.shift[m];
    const int ncols = 1 << sh;
    const int total = 128 << sh;
    int idx = blockIdx.x * 256 + threadIdx.x;
    if (idx >= total) return;
    int k = idx >> sh, c = idx & (ncols - 1);
    T[c * 128 + k] = f2bf(W[idx]);
}

// ---------------------------------------------------------------------------
// C[N,128] bf16 = Xb[N,128] bf16 @ W[128,128] (Wt transposed bf16)
// MFMA 16x16x32, 128-row tile, K=128 single-shot, 4 waves (2x2).
// ---------------------------------------------------------------------------
__global__ __launch_bounds__(256) void gemm_mfma(const ushort* __restrict__ Xb,
                                                 const ushort* __restrict__ Wt,
                                                 ushort* __restrict__ C, int N) {
    constexpr int LDR = 136;
    __shared__ short Xs[128 * LDR];
    __shared__ short Ws[128 * LDR];
    const int t = threadIdx.x;
    const int row0 = blockIdx.x * 128;

    for (int i = t; i < 128 * 16; i += 256) {
        int r = i >> 4, c8 = (i & 15) << 3;
        short8v v = {};
        if (row0 + r < N) v = *(const short8v*)(Xb + (size_t)(row0 + r) * 128 + c8);
        *(short8v*)(&Xs[r * LDR + c8]) = v;
    }
    for (int i = t; i < 128 * 16; i += 256) {
        int r = i >> 4, c8 = (i & 15) << 3;
        *(short8v*)(&Ws[r * LDR + c8]) = *(const short8v*)(Wt + r * 128 + c8);
    }
    __syncthreads();

    const int w = t >> 6, l = t & 63;
    const int wm = w & 1, wn = w >> 1;
    const int m0 = wm * 64;
    const int n0 = wn * 64;
    const int frow = l & 15;
    const int koff = (l >> 4) << 3;

    float4v acc[4][4];
    #pragma unroll
    for (int m = 0; m < 4; ++m)
        #pragma unroll
        for (int n = 0; n < 4; ++n) acc[m][n] = (float4v)0.f;

    #pragma unroll
    for (int ks = 0; ks < 4; ++ks) {
        const int k0 = ks * 32 + koff;
        short8v a[4], b[4];
        #pragma unroll
        for (int m = 0; m < 4; ++m)
            a[m] = *(const short8v*)(&Xs[(m0 + m * 16 + frow) * LDR + k0]);
        #pragma unroll
        for (int n = 0; n < 4; ++n)
            b[n] = *(const short8v*)(&Ws[(n0 + n * 16 + frow) * LDR + k0]);
        #pragma unroll
        for (int m = 0; m < 4; ++m)
            #pragma unroll
            for (int n = 0; n < 4; ++n)
                acc[m][n] = __builtin_amdgcn_mfma_f32_16x16x32_bf16(a[m], b[n], acc[m][n], 0, 0, 0);
    }

    // C/D layout: col = l&15, row = (l>>4)*4 + reg
    const int crow = (l >> 4) << 2;
    const int ccol = l & 15;
    #pragma unroll
    for (int m = 0; m < 4; ++m) {
        #pragma unroll
        for (int r4 = 0; r4 < 4; ++r4) {
            int grow = row0 + m0 + m * 16 + crow + r4;
            if (grow < N) {
                #pragma unroll
                for (int n = 0; n < 4; ++n)
                    C[(size_t)grow * 128 + n0 + n * 16 + ccol] = f2bf(acc[m][n][r4]);
            }
        }
    }
}

// ---------------------------------------------------------------------------
// Fused MLP: prefs[u] = tanh( leaky_relu(Xb[u]@hw1 + hb1, 0.01) @ hw2 + hb2 )
// ---------------------------------------------------------------------------
__global__ __launch_bounds__(256) void mlp_mfma(const ushort* __restrict__ Xb,
                                                const ushort* __restrict__ Wt,   // hw1t [64][128]
                                                const float* __restrict__ hb1,
                                                const float* __restrict__ hw2,
                                                const float* __restrict__ hb2,
                                                float* __restrict__ prefs, int N) {
    constexpr int LDR = 136;
    __shared__ short Xs[128 * LDR];
    __shared__ short Ws[64 * LDR];
    const int t = threadIdx.x;
    const int row0 = blockIdx.x * 128;

    for (int i = t; i < 128 * 16; i += 256) {
        int r = i >> 4, c8 = (i & 15) << 3;
        short8v v = {};
        if (row0 + r < N) v = *(const short8v*)(Xb + (size_t)(row0 + r) * 128 + c8);
        *(short8v*)(&Xs[r * LDR + c8]) = v;
    }
    for (int i = t; i < 64 * 16; i += 256) {
        int r = i >> 4, c8 = (i & 15) << 3;
        *(short8v*)(&Ws[r * LDR + c8]) = *(const short8v*)(Wt + r * 128 + c8);
    }
    __syncthreads();

    const int w = t >> 6, l = t & 63;
    const int m0 = w * 32;
    const int frow = l & 15;
    const int koff = (l >> 4) << 3;

    float4v acc[2][4];
    #pragma unroll
    for (int m = 0; m < 2; ++m)
        #pragma unroll
        for (int n = 0; n < 4; ++n) acc[m][n] = (float4v)0.f;

    #pragma unroll
    for (int ks = 0; ks < 4; ++ks) {
        const int k0 = ks * 32 + koff;
        short8v a[2], b[4];
        #pragma unroll
        for (int m = 0; m < 2; ++m)
            a[m] = *(const short8v*)(&Xs[(m0 + m * 16 + frow) * LDR + k0]);
        #pragma unroll
        for (int n = 0; n < 4; ++n)
            b[n] = *(const short8v*)(&Ws[(n * 16 + frow) * LDR + k0]);
        #pragma unroll
        for (int m = 0; m < 2; ++m)
            #pragma unroll
            for (int n = 0; n < 4; ++n)
                acc[m][n] = __builtin_amdgcn_mfma_f32_16x16x32_bf16(a[m], b[n], acc[m][n], 0, 0, 0);
    }

    float hb1v[4], hw2v[4];
    #pragma unroll
    for (int n = 0; n < 4; ++n) {
        int col = n * 16 + (l & 15);
        hb1v[n] = hb1[col];
        hw2v[n] = hw2[col];
    }
    const float hb2v = hb2[0];
    #pragma unroll
    for (int m = 0; m < 2; ++m) {
        #pragma unroll
        for (int r4 = 0; r4 < 4; ++r4) {
            float p = 0.f;
            #pragma unroll
            for (int n = 0; n < 4; ++n) {
                float v = acc[m][n][r4] + hb1v[n];
                v = v > 0.f ? v : 0.01f * v;
                p += v * hw2v[n];
            }
            p += __shfl_xor(p, 1);
            p += __shfl_xor(p, 2);
            p += __shfl_xor(p, 4);
            p += __shfl_xor(p, 8);
            int grow = row0 + m0 + m * 16 + ((l >> 4) << 2) + r4;
            if ((l & 15) == 0 && grow < N) prefs[grow] = tanhf(p + hb2v);
        }
    }
}

// ---------------------------------------------------------------------------
// Fused pair of matvecs on bf16 features.
// ---------------------------------------------------------------------------
__global__ __launch_bounds__(256) void matvec128x2(const ushort* __restrict__ Xsp, const float* __restrict__ vs,
                                                   float* __restrict__ outs, int Ns,
                                                   const ushort* __restrict__ Xdp, const float* __restrict__ vd,
                                                   float* __restrict__ outd, int Nd) {
    int row = blockIdx.x * 4 + (threadIdx.x >> 6);
    int lane = threadIdx.x & 63;
    const ushort* X; const float* v; float* out; int r;
    if (row < Ns) { X = Xsp; v = vs; out = outs; r = row; }
    else {
        r = row - Ns;
        if (r >= Nd) return;
        X = Xdp; v = vd; out = outd;
    }
    ushort2 x = ((const ushort2*)(X + (size_t)r * 128))[lane];
    float2 vv = ((const float2*)v)[lane];
    float s = bf2f(x.x) * vv.x + bf2f(x.y) * vv.y;
    #pragma unroll
    for (int off = 32; off; off >>= 1) s += __shfl_xor(s, off);
    if (lane == 0) out[r] = s;
}

// ---------------------------------------------------------------------------
// CSR build: histogram -> multi-block exclusive scan -> cursor fill
// ---------------------------------------------------------------------------
__global__ void count_deg(const int* __restrict__ dst, int* __restrict__ deg, int E) {
    int e = blockIdx.x * 256 + threadIdx.x;
    if (e < E) atomicAdd(&deg[dst[e]], 1);
}

__global__ __launch_bounds__(256) void partial_sums(const int* __restrict__ deg,
                                                    int* __restrict__ part, int N) {
    __shared__ int wsum[4];
    int base = blockIdx.x * 1024;
    int s = 0;
    for (int i = threadIdx.x; i < 1024; i += 256) {
        int idx = base + i;
        if (idx < N) s += deg[idx];
    }
    #pragma unroll
    for (int o = 32; o; o >>= 1) s += __shfl_xor(s, o);
    if ((threadIdx.x & 63) == 0) wsum[threadIdx.x >> 6] = s;
    __syncthreads();
    if (threadIdx.x == 0) part[blockIdx.x] = wsum[0] + wsum[1] + wsum[2] + wsum[3];
}

__global__ __launch_bounds__(64) void scan_partials(int* __restrict__ part,
                                                    int* __restrict__ offN, int nb) {
    int lane = threadIdx.x;
    int v = (lane < nb) ? part[lane] : 0;
    int incl = v;
    #pragma unroll
    for (int o = 1; o < 64; o <<= 1) {
        int t = __shfl_up(incl, o);
        if (lane >= o) incl += t;
    }
    if (lane < nb) part[lane] = incl - v;
    if (lane == 63) *offN = incl;
}

__global__ __launch_bounds__(256) void block_scan(const int* __restrict__ deg,
                                                  const int* __restrict__ part,
                                                  int* __restrict__ off,
                                                  int* __restrict__ cursor, int N) {
    __shared__ int wsum[4];
    int t = threadIdx.x;
    int lane = t & 63, w = t >> 6;
    int base = blockIdx.x * 1024 + t * 4;
    int l0 = 0, l1 = 0, l2 = 0, l3 = 0;
    if (base + 3 < N) {
        int4 v = *(const int4*)(deg + base);
        l0 = v.x; l1 = v.y; l2 = v.z; l3 = v.w;
    } else {
        if (base + 0 < N) l0 = deg[base + 0];
        if (base + 1 < N) l1 = deg[base + 1];
        if (base + 2 < N) l2 = deg[base + 2];
    }
    int tsum = l0 + l1 + l2 + l3;
    int incl = tsum;
    #pragma unroll
    for (int o = 1; o < 64; o <<= 1) {
        int tt = __shfl_up(incl, o);
        if (lane >= o) incl += tt;
    }
    int lexcl = incl - tsum;
    if (lane == 63) wsum[w] = incl;
    __syncthreads();
    int p = part[blockIdx.x] + lexcl;
    for (int i = 0; i < w; ++i) p += wsum[i];
    if (base + 0 < N) { off[base + 0] = p; cursor[base + 0] = p; } p += l0;
    if (base + 1 < N) { off[base + 1] = p; cursor[base + 1] = p; } p += l1;
    if (base + 2 < N) { off[base + 2] = p; cursor[base + 2] = p; } p += l2;
    if (base + 3 < N) { off[base + 3] = p; cursor[base + 3] = p; }
}

__global__ void fill_csr(const int* __restrict__ src, const int* __restrict__ dst,
                         int* __restrict__ cursor, int* __restrict__ esrc, int E) {
    int e = blockIdx.x * 256 + threadIdx.x;
    if (e >= E) return;
    int p = atomicAdd(&cursor[dst[e]], 1);
    esrc[p] = src[e];
}

// ---------------------------------------------------------------------------
// Fused GAT softmax + aggregate, one wave per destination node, bf16 gathers.
// Quarter-wave rows (16 lanes x ushort8 = 256B), 8 edges in flight (2/qwave).
// ---------------------------------------------------------------------------
__global__ __launch_bounds__(256) void gat_aggregate_csr(const int* __restrict__ off,
                                                         const int* __restrict__ esrc,
                                                         const float* __restrict__ asn,
                                                         const float* __restrict__ adn,
                                                         const ushort* __restrict__ hs,
                                                         const float* __restrict__ bias,
                                                         float* __restrict__ out, int Nd) {
    int d = blockIdx.x * 4 + (threadIdx.x >> 6);
    int lane = threadIdx.x & 63;
    if (d >= Nd) return;
    const int beg = off[d], end = off[d + 1];
    const float ad = adn[d];
    const int qw = lane >> 4, l16 = lane & 15;
    float acc[8] = {0.f, 0.f, 0.f, 0.f, 0.f, 0.f, 0.f, 0.f};
    float den = 0.f;
    for (int base = beg; base < end; base += 64) {
        int e = base + lane;
        int s = 0; float ev = 0.f;        // inactive lanes: ev=0, s=0 (row-0 load harmless)
        if (e < end) {
            s = esrc[e];
            float v = asn[s] + ad;
            v = v > 0.f ? v : 0.2f * v;
            ev = __expf(v);
        }
        float r = ev;
        #pragma unroll
        for (int o = 32; o; o >>= 1) r += __shfl_xor(r, o);
        den += r;
        int cnt4 = (min(64, end - base) + 3) & ~3;
        for (int j = 0; j < cnt4; j += 8) {
            int jj = j + qw;
            float ev0 = __shfl(ev, jj);
            int   sj0 = __shfl(s, jj);
            short8v h0 = *(const short8v*)(hs + (size_t)sj0 * 128 + l16 * 8);
            if (j + 4 < cnt4) {                  // wave-uniform
                float ev1 = __shfl(ev, jj + 4);
                int   sj1 = __shfl(s, jj + 4);
                short8v h1 = *(const short8v*)(hs + (size_t)sj1 * 128 + l16 * 8);
                #pragma unroll
                for (int k = 0; k < 8; ++k)
                    acc[k] += ev0 * bf2f((ushort)h0[k]) + ev1 * bf2f((ushort)h1[k]);
            } else {
                #pragma unroll
                for (int k = 0; k < 8; ++k)
                    acc[k] += ev0 * bf2f((ushort)h0[k]);
            }
        }
    }
    // reduce across the 4 quarter-waves
    #pragma unroll
    for (int k = 0; k < 8; ++k) {
        acc[k] += __shfl_xor(acc[k], 16);
        acc[k] += __shfl_xor(acc[k], 32);
    }
    if (qw == 0) {
        float inv = 1.f / (den + 1e-16f);
        float4 b0 = ((const float4*)bias)[l16 * 2];
        float4 b1 = ((const float4*)bias)[l16 * 2 + 1];
        float4* op = (float4*)(out + (size_t)d * 128 + l16 * 8);
        op[0] = make_float4(acc[0] * inv + b0.x, acc[1] * inv + b0.y,
                            acc[2] * inv + b0.z, acc[3] * inv + b0.w);
        op[1] = make_float4(acc[4] * inv + b1.x, acc[5] * inv + b1.y,
                            acc[6] * inv + b1.z, acc[7] * inv + b1.w);
    }
}

// ---------------------------------------------------------------------------
// BatchNorm stats for TWO tensors, vectorized float4 per lane.
// ---------------------------------------------------------------------------
__global__ __launch_bounds__(256) void bn_stats2(const float* __restrict__ x1, float* __restrict__ stat1,
                                                 int N1, int B1,
                                                 const float* __restrict__ x2, float* __restrict__ stat2,
                                                 int N2, int B2) {
    const float* x; float* stat; int N, b, nb;
    if ((int)blockIdx.x < B1) { x = x1; stat = stat1; N = N1; b = blockIdx.x; nb = B1; }
    else { x = x2; stat = stat2; N = N2; b = blockIdx.x - B1; nb = B2; }
    const int t = threadIdx.x;
    const int rg = t >> 5;          // row within 8-row group
    const int c32 = t & 31;         // float4 column index
    float s[4] = {0.f, 0.f, 0.f, 0.f}, q[4] = {0.f, 0.f, 0.f, 0.f};
    for (int r = b * 8 + rg; r < N; r += nb * 8) {
        float4 v = ((const float4*)(x + (size_t)r * 128))[c32];
        s[0] += v.x; q[0] += v.x * v.x;
        s[1] += v.y; q[1] += v.y * v.y;
        s[2] += v.z; q[2] += v.z * v.z;
        s[3] += v.w; q[3] += v.w * v.w;
    }
    #pragma unroll
    for (int k = 0; k < 4; ++k) {
        s[k] += __shfl_xor(s[k], 32);
        q[k] += __shfl_xor(q[k], 32);
    }
    __shared__ float rs[4][128], rq[4][128];
    const int w = t >> 6, l = t & 63;
    if (l < 32) {
        #pragma unroll
        for (int k = 0; k < 4; ++k) {
            rs[w][c32 * 4 + k] = s[k];
            rq[w][c32 * 4 + k] = q[k];
        }
    }
    __syncthreads();
    if (t < 128) {
        float ts = rs[0][t] + rs[1][t] + rs[2][t] + rs[3][t];
        float tq = rq[0][t] + rq[1][t] + rq[2][t] + rq[3][t];
        atomicAdd(&stat[t], ts);
        atomicAdd(&stat[128 + t], tq);
    }
}

// ---------------------------------------------------------------------------
// Convert raw (sum, sumsq) -> (scale, shift) in place, two BN instances.
// scale = g*rsqrt(var+eps), shift = b - mu*scale
// ---------------------------------------------------------------------------
__global__ __launch_bounds__(256) void bn_finalize2(float* __restrict__ s1, int N1,
                                                    const float* __restrict__ g1, const float* __restrict__ b1,
                                                    float* __restrict__ s2, int N2,
                                                    const float* __restrict__ g2, const float* __restrict__ b2) {
    int t = threadIdx.x;
    float* s; int N; const float *g, *b; int c;
    if (t < 128) { s = s1; N = N1; g = g1; b = b1; c = t; }
    else         { s = s2; N = N2; g = g2; b = b2; c = t - 128; }
    float invN = 1.0f / N;
    float mu  = s[c] * invN;
    float var = s[128 + c] * invN - mu * mu;
    float sc  = g[c] * rsqrtf(var + 1e-5f);
    s[c]       = sc;
    s[128 + c] = b[c] - mu * sc;
}

// ---------------------------------------------------------------------------
// BN apply: y = elu(x*scale + shift); optional fp32 out, optional bf16 out.
// ---------------------------------------------------------------------------
__global__ void bn_apply2(const float* __restrict__ x1, const float* __restrict__ ss1,
                          float* __restrict__ xo1, ushort* __restrict__ xb1, int N1,
                          const float* __restrict__ x2, const float* __restrict__ ss2,
                          float* __restrict__ xo2, ushort* __restrict__ xb2, int N2) {
    int i = blockIdx.x * 256 + threadIdx.x;
    const float* x; const float* ss; float* xo; ushort* xb;
    if (i < N1 * 32) { x = x1; ss = ss1; xo = xo1; xb = xb1; }
    else {
        i -= N1 * 32;
        if (i >= N2 * 32) return;
        x = x2; ss = ss2; xo = xo2; xb = xb2;
    }
    int c32 = i & 31;
    float4 v  = ((const float4*)x)[i];
    float4 sc = ((const float4*)ss)[c32];
    float4 sh = ((const float4*)(ss + 128))[c32];
    float4 o;
    o.x = v.x * sc.x + sh.x;
    o.y = v.y * sc.y + sh.y;
    o.z = v.z * sc.z + sh.z;
    o.w = v.w * sc.w + sh.w;
    o.x = o.x > 0.f ? o.x : __expf(o.x) - 1.f;
    o.y = o.y > 0.f ? o.y : __expf(o.y) - 1.f;
    o.z = o.z > 0.f ? o.z : __expf(o.z) - 1.f;
    o.w = o.w > 0.f ? o.w : __expf(o.w) - 1.f;
    if (xo) ((float4*)xo)[i] = o;
    if (xb) {
        ushort4 u;
        u.x = f2bf(o.x); u.y = f2bf(o.y); u.z = f2bf(o.z); u.w = f2bf(o.w);
        ((ushort4*)xb)[i] = u;
    }
}

// s[he_food[e]] += prefs[he_user[e]] * score[e]
__global__ void health_scatter(const int* __restrict__ hu, const int* __restrict__ hf,
                               const float* __restrict__ score, const float* __restrict__ prefs,
                               float* __restrict__ s, int E) {
    int e = blockIdx.x * 256 + threadIdx.x;
    if (e >= E) return;
    atomicAdd(&s[hf[e]], prefs[hu[e]] * score[e]);
}

// xf2[f][c] += 0.1 * s[f]
__global__ void add_health(float* __restrict__ xf2, const float* __restrict__ s, int n4) {
    int i = blockIdx.x * 256 + threadIdx.x;
    if (i >= n4) return;
    float sv = 0.1f * s[i >> 5];
    float4 v = ((float4*)xf2)[i];
    v.x += sv; v.y += sv; v.z += sv; v.w += sv;
    ((float4*)xf2)[i] = v;
}

// ---------------------------------------------------------------------------
extern "C" void kernel_launch(void* const* d_in, const int* in_sizes, int n_in,
                              void* d_out, int out_size, void* d_ws, size_t ws_size,
                              hipStream_t stream) {
    const float* x_user = (const float*)d_in[0];
    const float* x_food = (const float*)d_in[1];
    const int* uf_src = (const int*)d_in[2];
    const int* uf_dst = (const int*)d_in[3];
    const int* fu_src = (const int*)d_in[4];
    const int* fu_dst = (const int*)d_in[5];
    const int* he_user = (const int*)d_in[6];
    const int* he_food = (const int*)d_in[7];
    const float* scores = (const float*)d_in[8];
    const float* a1_uf_src = (const float*)d_in[11];
    const float* a1_uf_dst = (const float*)d_in[12];
    const float* b1_uf     = (const float*)d_in[13];
    const float* a1_fu_src = (const float*)d_in[16];
    const float* a1_fu_dst = (const float*)d_in[17];
    const float* b1_fu     = (const float*)d_in[18];
    const float* b2_uf     = (const float*)d_in[23];
    const float* b2_fu     = (const float*)d_in[28];
    const float* bn1_user_g = (const float*)d_in[29];
    const float* bn1_user_b = (const float*)d_in[30];
    const float* bn1_food_g = (const float*)d_in[31];
    const float* bn1_food_b = (const float*)d_in[32];
    const float* bn2_user_g = (const float*)d_in[33];
    const float* bn2_user_b = (const float*)d_in[34];
    const float* bn2_food_g = (const float*)d_in[35];
    const float* bn2_food_b = (const float*)d_in[36];
    const float* hw1 = (const float*)d_in[37];
    const float* hb1 = (const float*)d_in[38];
    const float* hw2 = (const float*)d_in[39];
    const float* hb2 = (const float*)d_in[40];

    float* outp  = (float*)d_out;
    float* xu2   = outp;                          // [NU,128]
    float* xf2   = outp + (size_t)NU_ * 128;      // [NF,128]
    float* prefs = xf2 + (size_t)NF_ * 128;       // [NU]

    // ---- workspace layout ----
    float* ws    = (float*)d_ws;
    float* hsf   = ws;                             // NU*128 slot (bf16 used: NU*128 ushort)
    ushort* hs   = (ushort*)hsf;
    float* xu1   = hsf  + (size_t)NU_ * 128;       // NU*128
    float* xf1   = xu1  + (size_t)NU_ * 128;       // NF*128
    float* asn   = xf1  + (size_t)NF_ * 128;       // NU
    float* adn   = asn  + NU_;                     // NU
    // --- zeroed-once region start ---
    float* stat4 = adn  + NU_;                     // 4*256 (one per BN instance)
    float* sbuf  = stat4 + 1024;                   // NF
    int*   deg_f = (int*)(sbuf + NF_);             // NF
    int*   deg_u = deg_f + NF_;                    // NU
    // --- zeroed-once region end ---
    float* vall  = (float*)(deg_u + NU_);          // 8*128
    int*   part  = (int*)(vall + 1024);            // 64
    int*   uf_off  = part + 64;                    // NF+4
    int*   fu_off  = uf_off + (NF_ + 4);           // NU+4
    int*   cursor  = fu_off + (NU_ + 4);           // NU (max)
    int*   uf_esrc = cursor + NU_;                 // E
    int*   fu_esrc = uf_esrc + E_;                 // E
    // bf16 buffers (ushort), 16B-aligned since previous sizes are /4
    ushort* bu   = (ushort*)(fu_esrc + E_);        // NU*128 (x_user -> xu1b -> xu2b)
    ushort* bfo  = bu + (size_t)NU_ * 128;         // NF*128 (x_food -> xf1b)
    ushort* wt0  = bfo + (size_t)NF_ * 128;        // 4 x 128*128 transposed weights
    ushort* wt1  = wt0 + 16384;
    ushort* wt2  = wt1 + 16384;
    ushort* wt3  = wt2 + 16384;
    ushort* hw1t = wt3 + 16384;                    // 64*128

    const size_t zero_elems = 1024 + NF_ + NF_ + NU_;
    hipMemsetAsync(stat4, 0, zero_elems * sizeof(float), stream);

    // --- bf16 conversions ---
    f2b_two<<<((NU_ + NF_) * 32 + 255) / 256, 256, 0, stream>>>(
        x_user, bu, NU_ * 32, x_food, bfo, NF_ * 32);
    WTArgs wt;
    wt.W[0] = (const float*)d_in[9];  wt.T[0] = wt0;  wt.shift[0] = 7;
    wt.W[1] = (const float*)d_in[14]; wt.T[1] = wt1;  wt.shift[1] = 7;
    wt.W[2] = (const float*)d_in[19]; wt.T[2] = wt2;  wt.shift[2] = 7;
    wt.W[3] = (const float*)d_in[24]; wt.T[3] = wt3;  wt.shift[3] = 7;
    wt.W[4] = hw1;                    wt.T[4] = hw1t; wt.shift[4] = 6;
    wt_conv<<<dim3(64, 5), 256, 0, stream>>>(wt);

    // --- precompute v = W@a for all 8 (dst-side GEMMs eliminated) ---
    WAArgs wa;
    wa.W[0] = (const float*)d_in[9];  wa.a[0] = a1_uf_src;
    wa.W[1] = (const float*)d_in[10]; wa.a[1] = a1_uf_dst;
    wa.W[2] = (const float*)d_in[14]; wa.a[2] = a1_fu_src;
    wa.W[3] = (const float*)d_in[15]; wa.a[3] = a1_fu_dst;
    wa.W[4] = (const float*)d_in[19]; wa.a[4] = (const float*)d_in[21];
    wa.W[5] = (const float*)d_in[20]; wa.a[5] = (const float*)d_in[22];
    wa.W[6] = (const float*)d_in[24]; wa.a[6] = (const float*)d_in[26];
    wa.W[7] = (const float*)d_in[25]; wa.a[7] = (const float*)d_in[27];
    wa_vec<<<8, 256, 0, stream>>>(wa, vall);

    // --- build CSR once per edge type (reused by both layers) ---
    const int EB = (E_ + 255) / 256;
    const int NBF = (NF_ + 1023) / 1024;   // 25
    const int NBU = (NU_ + 1023) / 1024;   // 49

    count_deg<<<EB, 256, 0, stream>>>(uf_dst, deg_f, E_);
    partial_sums<<<NBF, 256, 0, stream>>>(deg_f, part, NF_);
    scan_partials<<<1, 64, 0, stream>>>(part, &uf_off[NF_], NBF);
    block_scan<<<NBF, 256, 0, stream>>>(deg_f, part, uf_off, cursor, NF_);
    fill_csr<<<EB, 256, 0, stream>>>(uf_src, uf_dst, cursor, uf_esrc, E_);

    count_deg<<<EB, 256, 0, stream>>>(fu_dst, deg_u, E_);
    partial_sums<<<NBU, 256, 0, stream>>>(deg_u, part, NU_);
    scan_partials<<<1, 64, 0, stream>>>(part, &fu_off[NU_], NBU);
    block_scan<<<NBU, 256, 0, stream>>>(deg_u, part, fu_off, cursor, NU_);
    fill_csr<<<EB, 256, 0, stream>>>(fu_src, fu_dst, cursor, fu_esrc, E_);

    auto run_gat = [&](const ushort* xb, const ushort* xsb, const ushort* xdb,
                       const int* off, const int* esrc,
                       const ushort* wtb, const float* vs, const float* vd, const float* bias,
                       float* out, int Ns, int Nd) {
        gemm_mfma<<<(Ns + 127) / 128, 256, 0, stream>>>(xb, wtb, hs, Ns);
        matvec128x2<<<(Ns + Nd + 3) / 4, 256, 0, stream>>>(xsb, vs, asn, Ns, xdb, vd, adn, Nd);
        gat_aggregate_csr<<<(Nd + 3) / 4, 256, 0, stream>>>(off, esrc, asn, adn, hs, bias, out, Nd);
    };

    // ---- layer 1 ----
    run_gat(bu,  bu,  bfo, uf_off, uf_esrc, wt0, vall + 0,   vall + 128, b1_uf, xf1, NU_, NF_);
    run_gat(bfo, bfo, bu,  fu_off, fu_esrc, wt1, vall + 256, vall + 384, b1_fu, xu1, NF_, NU_);
    bn_stats2<<<768, 256, 0, stream>>>(xu1, stat4 + 0, NU_, 512, xf1, stat4 + 256, NF_, 256);
    bn_finalize2<<<1, 256, 0, stream>>>(stat4 + 0, NU_, bn1_user_g, bn1_user_b,
                                        stat4 + 256, NF_, bn1_food_g, bn1_food_b);
    // layer-1 fp32 post-BN values are dead (layer 2 consumes bf16 copies only)
    bn_apply2<<<((NU_ + NF_) * 32 + 255) / 256, 256, 0, stream>>>(
        xu1, stat4 + 0,   (float*)nullptr, bu,  NU_,
        xf1, stat4 + 256, (float*)nullptr, bfo, NF_);

    // ---- layer 2 (aggregate straight into d_out regions) ----
    run_gat(bu,  bu,  bfo, uf_off, uf_esrc, wt2, vall + 512, vall + 640, b2_uf, xf2, NU_, NF_);
    run_gat(bfo, bfo, bu,  fu_off, fu_esrc, wt3, vall + 768, vall + 896, b2_fu, xu2, NF_, NU_);
    bn_stats2<<<768, 256, 0, stream>>>(xu2, stat4 + 512, NU_, 512, xf2, stat4 + 768, NF_, 256);
    bn_finalize2<<<1, 256, 0, stream>>>(stat4 + 512, NU_, bn2_user_g, bn2_user_b,
                                        stat4 + 768, NF_, bn2_food_g, bn2_food_b);
    bn_apply2<<<((NU_ + NF_) * 32 + 255) / 256, 256, 0, stream>>>(
        xu2, stat4 + 512, xu2, bu, NU_,
        xf2, stat4 + 768, xf2, (ushort*)nullptr, NF_);

    // ---- health preference MLP + scatter update ----
    mlp_mfma<<<(NU_ + 127) / 128, 256, 0, stream>>>(bu, hw1t, hb1, hw2, hb2, prefs, NU_);
    health_scatter<<<EB, 256, 0, stream>>>(he_user, he_food, scores, prefs, sbuf, E_);
    add_health<<<(NF_ * 32 + 255) / 256, 256, 0, stream>>>(xf2, sbuf, NF_ * 32);
}

// Round 8
// 368.397 us; speedup vs baseline: 6.4945x; 1.2064x over previous
//
#include <hip/hip_runtime.h>
#include <cstddef>

#define NU_ 50000
#define NF_ 25000
#define E_  500000

typedef __attribute__((ext_vector_type(8))) short short8v;
typedef __attribute__((ext_vector_type(4))) float float4v;

constexpr int LDR = 136;

static __device__ __forceinline__ ushort f2bf(float f) {
    uint u = __float_as_uint(f);
    uint r = (u + 0x7fffu + ((u >> 16) & 1u)) >> 16;   // RNE
    return (ushort)r;
}
static __device__ __forceinline__ float bf2f(ushort u) {
    return __uint_as_float(((uint)u) << 16);
}

// ---------------------------------------------------------------------------
// Fused preprocessing: f2b(x_user), f2b(x_food), 5 weight transposes,
// 8 W@a attention vectors. One kernel, block-range sections.
// ---------------------------------------------------------------------------
struct PPArgs {
    const float* xu; const float* xf;
    ushort* bu; ushort* bfo;
    const float* W[5];  ushort* T[5];      // transpose targets (shift 7,7,7,7,6)
    const float* waW[8]; const float* waA[8];
    float* vall;
};

__global__ __launch_bounds__(256) void preprocess(PPArgs A) {
    const int nbA = NU_ * 32 / 256;        // 6250
    const int nbB = NF_ * 32 / 256;        // 3125
    const int nbC = 4 * 64 + 32;           // 288
    int b = blockIdx.x, t = threadIdx.x;
    if (b < nbA) {
        int i = b * 256 + t;
        float4 v = ((const float4*)A.xu)[i];
        ushort4 o; o.x = f2bf(v.x); o.y = f2bf(v.y); o.z = f2bf(v.z); o.w = f2bf(v.w);
        ((ushort4*)A.bu)[i] = o;
    } else if (b < nbA + nbB) {
        int i = (b - nbA) * 256 + t;
        float4 v = ((const float4*)A.xf)[i];
        ushort4 o; o.x = f2bf(v.x); o.y = f2bf(v.y); o.z = f2bf(v.z); o.w = f2bf(v.w);
        ((ushort4*)A.bfo)[i] = o;
    } else if (b < nbA + nbB + nbC) {
        int cb = b - nbA - nbB;
        int m, wb, sh;
        if (cb < 256) { m = cb >> 6; wb = cb & 63; sh = 7; }
        else          { m = 4; wb = cb - 256; sh = 6; }
        int idx = wb * 256 + t;
        int k = idx >> sh, c = idx & ((1 << sh) - 1);
        A.T[m][c * 128 + k] = f2bf(A.W[m][idx]);
    } else {
        int db = b - nbA - nbB - nbC;          // 0..255
        int row = db * 4 + (t >> 6);           // 0..1023 = m*128+k
        int m = row >> 7, k = row & 127, lane = t & 63;
        float2 w = ((const float2*)(A.waW[m] + k * 128))[lane];
        float2 av = ((const float2*)A.waA[m])[lane];
        float s = w.x * av.x + w.y * av.y;
        #pragma unroll
        for (int o = 32; o; o >>= 1) s += __shfl_xor(s, o);
        if (lane == 0) A.vall[row] = s;
    }
}

// ---------------------------------------------------------------------------
// CSR build for BOTH edge types, fused stage by stage.
// ---------------------------------------------------------------------------
__global__ void csr_count_both(const int* __restrict__ uf_dst, const int* __restrict__ fu_dst,
                               int* __restrict__ deg_f, int* __restrict__ deg_u, int EB) {
    int b = blockIdx.x;
    const int* dst; int* deg; int e;
    if (b < EB) { dst = uf_dst; deg = deg_f; e = b * 256 + threadIdx.x; }
    else        { dst = fu_dst; deg = deg_u; e = (b - EB) * 256 + threadIdx.x; }
    if (e < E_) atomicAdd(&deg[dst[e]], 1);
}

__global__ __launch_bounds__(256) void csr_psum_both(const int* __restrict__ deg_f, int* __restrict__ part_f,
                                                     const int* __restrict__ deg_u, int* __restrict__ part_u) {
    const int NBF = (NF_ + 1023) / 1024;
    __shared__ int wsum[4];
    int b = blockIdx.x;
    const int* deg; int* part; int N, bb;
    if (b < NBF) { deg = deg_f; part = part_f; N = NF_; bb = b; }
    else         { deg = deg_u; part = part_u; N = NU_; bb = b - NBF; }
    int base = bb * 1024;
    int s = 0;
    for (int i = threadIdx.x; i < 1024; i += 256) {
        int idx = base + i;
        if (idx < N) s += deg[idx];
    }
    #pragma unroll
    for (int o = 32; o; o >>= 1) s += __shfl_xor(s, o);
    if ((threadIdx.x & 63) == 0) wsum[threadIdx.x >> 6] = s;
    __syncthreads();
    if (threadIdx.x == 0) part[bb] = wsum[0] + wsum[1] + wsum[2] + wsum[3];
}

__global__ __launch_bounds__(128) void csr_scan_both(int* __restrict__ part_f, int* __restrict__ offN_f,
                                                     int* __restrict__ part_u, int* __restrict__ offN_u) {
    int w = threadIdx.x >> 6, lane = threadIdx.x & 63;
    int nb; int* part; int* offN;
    if (w == 0) { nb = (NF_ + 1023) / 1024; part = part_f; offN = offN_f; }
    else        { nb = (NU_ + 1023) / 1024; part = part_u; offN = offN_u; }
    int v = (lane < nb) ? part[lane] : 0;
    int incl = v;
    #pragma unroll
    for (int o = 1; o < 64; o <<= 1) {
        int t = __shfl_up(incl, o);
        if (lane >= o) incl += t;
    }
    if (lane < nb) part[lane] = incl - v;
    if (lane == 63) *offN = incl;
}

__global__ __launch_bounds__(256) void csr_bscan_both(const int* __restrict__ deg_f, const int* __restrict__ part_f,
                                                      int* __restrict__ uf_off, int* __restrict__ cur_f,
                                                      const int* __restrict__ deg_u, const int* __restrict__ part_u,
                                                      int* __restrict__ fu_off, int* __restrict__ cur_u) {
    const int NBF = (NF_ + 1023) / 1024;
    __shared__ int wsum[4];
    int blk = blockIdx.x;
    const int *deg, *part; int *off, *cursor; int N, bb;
    if (blk < NBF) { deg = deg_f; part = part_f; off = uf_off; cursor = cur_f; N = NF_; bb = blk; }
    else           { deg = deg_u; part = part_u; off = fu_off; cursor = cur_u; N = NU_; bb = blk - NBF; }
    int t = threadIdx.x;
    int lane = t & 63, w = t >> 6;
    int base = bb * 1024 + t * 4;
    int l0 = 0, l1 = 0, l2 = 0, l3 = 0;
    if (base + 3 < N) {
        int4 v = *(const int4*)(deg + base);
        l0 = v.x; l1 = v.y; l2 = v.z; l3 = v.w;
    } else {
        if (base + 0 < N) l0 = deg[base + 0];
        if (base + 1 < N) l1 = deg[base + 1];
        if (base + 2 < N) l2 = deg[base + 2];
    }
    int tsum = l0 + l1 + l2 + l3;
    int incl = tsum;
    #pragma unroll
    for (int o = 1; o < 64; o <<= 1) {
        int tt = __shfl_up(incl, o);
        if (lane >= o) incl += tt;
    }
    int lexcl = incl - tsum;
    if (lane == 63) wsum[w] = incl;
    __syncthreads();
    int p = part[bb] + lexcl;
    for (int i = 0; i < w; ++i) p += wsum[i];
    if (base + 0 < N) { off[base + 0] = p; cursor[base + 0] = p; } p += l0;
    if (base + 1 < N) { off[base + 1] = p; cursor[base + 1] = p; } p += l1;
    if (base + 2 < N) { off[base + 2] = p; cursor[base + 2] = p; } p += l2;
    if (base + 3 < N) { off[base + 3] = p; cursor[base + 3] = p; }
}

__global__ void csr_fill_both(const int* __restrict__ uf_src, const int* __restrict__ uf_dst,
                              int* __restrict__ cur_f, int* __restrict__ uf_esrc,
                              const int* __restrict__ fu_src, const int* __restrict__ fu_dst,
                              int* __restrict__ cur_u, int* __restrict__ fu_esrc, int EB) {
    int b = blockIdx.x;
    const int *src, *dst; int *cursor, *esrc; int e;
    if (b < EB) { src = uf_src; dst = uf_dst; cursor = cur_f; esrc = uf_esrc; e = b * 256 + threadIdx.x; }
    else        { src = fu_src; dst = fu_dst; cursor = cur_u; esrc = fu_esrc; e = (b - EB) * 256 + threadIdx.x; }
    if (e >= E_) return;
    int p = atomicAdd(&cursor[dst[e]], 1);
    esrc[p] = src[e];
}

// ---------------------------------------------------------------------------
// MFMA 128x128 GEMM tile (bf16 in/out), shared body for both directions.
// ---------------------------------------------------------------------------
static __device__ __forceinline__ void gemm_tile(const ushort* __restrict__ Xb,
                                                 const ushort* __restrict__ Wt,
                                                 ushort* __restrict__ C, int N, int row0,
                                                 short* Xs, short* Ws) {
    const int t = threadIdx.x;
    for (int i = t; i < 128 * 16; i += 256) {
        int r = i >> 4, c8 = (i & 15) << 3;
        short8v v = {};
        if (row0 + r < N) v = *(const short8v*)(Xb + (size_t)(row0 + r) * 128 + c8);
        *(short8v*)(&Xs[r * LDR + c8]) = v;
    }
    for (int i = t; i < 128 * 16; i += 256) {
        int r = i >> 4, c8 = (i & 15) << 3;
        *(short8v*)(&Ws[r * LDR + c8]) = *(const short8v*)(Wt + r * 128 + c8);
    }
    __syncthreads();

    const int w = t >> 6, l = t & 63;
    const int m0 = (w & 1) * 64;
    const int n0 = (w >> 1) * 64;
    const int frow = l & 15;
    const int koff = (l >> 4) << 3;

    float4v acc[4][4];
    #pragma unroll
    for (int m = 0; m < 4; ++m)
        #pragma unroll
        for (int n = 0; n < 4; ++n) acc[m][n] = (float4v)0.f;

    #pragma unroll
    for (int ks = 0; ks < 4; ++ks) {
        const int k0 = ks * 32 + koff;
        short8v a[4], b[4];
        #pragma unroll
        for (int m = 0; m < 4; ++m)
            a[m] = *(const short8v*)(&Xs[(m0 + m * 16 + frow) * LDR + k0]);
        #pragma unroll
        for (int n = 0; n < 4; ++n)
            b[n] = *(const short8v*)(&Ws[(n0 + n * 16 + frow) * LDR + k0]);
        #pragma unroll
        for (int m = 0; m < 4; ++m)
            #pragma unroll
            for (int n = 0; n < 4; ++n)
                acc[m][n] = __builtin_amdgcn_mfma_f32_16x16x32_bf16(a[m], b[n], acc[m][n], 0, 0, 0);
    }

    const int crow = (l >> 4) << 2;
    const int ccol = l & 15;
    #pragma unroll
    for (int m = 0; m < 4; ++m) {
        #pragma unroll
        for (int r4 = 0; r4 < 4; ++r4) {
            int grow = row0 + m0 + m * 16 + crow + r4;
            if (grow < N) {
                #pragma unroll
                for (int n = 0; n < 4; ++n)
                    C[(size_t)grow * 128 + n0 + n * 16 + ccol] = f2bf(acc[m][n][r4]);
            }
        }
    }
}

__global__ __launch_bounds__(256) void gemm_both(const ushort* __restrict__ Xu, const ushort* __restrict__ Wtu,
                                                 ushort* __restrict__ Cu,
                                                 const ushort* __restrict__ Xf, const ushort* __restrict__ Wtf,
                                                 ushort* __restrict__ Cf) {
    __shared__ short Xs[128 * LDR];
    __shared__ short Ws[128 * LDR];
    const int GU = (NU_ + 127) / 128;
    if ((int)blockIdx.x < GU)
        gemm_tile(Xu, Wtu, Cu, NU_, blockIdx.x * 128, Xs, Ws);
    else
        gemm_tile(Xf, Wtf, Cf, NF_, (blockIdx.x - GU) * 128, Xs, Ws);
}

// ---------------------------------------------------------------------------
// All 4 attention matvecs in one dispatch (each row read once, 2 dots).
// user rows: asn_u = bu.va, adn_u = bu.vb ; food rows: adn_f, asn_f.
// ---------------------------------------------------------------------------
__global__ __launch_bounds__(256) void matvec4(const ushort* __restrict__ bu, const ushort* __restrict__ bfo,
                                               const float* __restrict__ v_asn_u, const float* __restrict__ v_adn_u,
                                               const float* __restrict__ v_adn_f, const float* __restrict__ v_asn_f,
                                               float* __restrict__ asn_u, float* __restrict__ adn_u,
                                               float* __restrict__ adn_f, float* __restrict__ asn_f) {
    int row = blockIdx.x * 4 + (threadIdx.x >> 6);
    int lane = threadIdx.x & 63;
    const ushort* X; const float *va, *vb; float *oa, *ob; int r;
    if (row < NU_) { X = bu; va = v_asn_u; vb = v_adn_u; oa = asn_u; ob = adn_u; r = row; }
    else {
        r = row - NU_;
        if (r >= NF_) return;
        X = bfo; va = v_adn_f; vb = v_asn_f; oa = adn_f; ob = asn_f;
    }
    ushort2 x = ((const ushort2*)(X + (size_t)r * 128))[lane];
    float2 va2 = ((const float2*)va)[lane];
    float2 vb2 = ((const float2*)vb)[lane];
    float fx = bf2f(x.x), fy = bf2f(x.y);
    float s1 = fx * va2.x + fy * va2.y;
    float s2 = fx * vb2.x + fy * vb2.y;
    #pragma unroll
    for (int o = 32; o; o >>= 1) { s1 += __shfl_xor(s1, o); s2 += __shfl_xor(s2, o); }
    if (lane == 0) { oa[r] = s1; ob[r] = s2; }
}

// ---------------------------------------------------------------------------
// Fused GAT softmax+aggregate for BOTH directions; bf16 gather AND bf16 out.
// No bias (per-column constants cancel exactly through BatchNorm).
// ---------------------------------------------------------------------------
__global__ __launch_bounds__(256) void gat_agg_both(
        const int* __restrict__ uf_off, const int* __restrict__ uf_esrc,
        const float* __restrict__ asn_u, const float* __restrict__ adn_f,
        const ushort* __restrict__ hs_u, ushort* __restrict__ out_f,
        const int* __restrict__ fu_off, const int* __restrict__ fu_esrc,
        const float* __restrict__ asn_f, const float* __restrict__ adn_u,
        const ushort* __restrict__ hs_f, ushort* __restrict__ out_u) {
    const int NBAF = (NF_ + 3) / 4;
    int blk = blockIdx.x;
    const int *off, *esrc; const float *asn, *adn; const ushort* hs; ushort* out; int Nd, d;
    if (blk < NBAF) {
        off = uf_off; esrc = uf_esrc; asn = asn_u; adn = adn_f; hs = hs_u; out = out_f;
        Nd = NF_; d = blk * 4 + (threadIdx.x >> 6);
    } else {
        off = fu_off; esrc = fu_esrc; asn = asn_f; adn = adn_u; hs = hs_f; out = out_u;
        Nd = NU_; d = (blk - NBAF) * 4 + (threadIdx.x >> 6);
    }
    int lane = threadIdx.x & 63;
    if (d >= Nd) return;
    const int beg = off[d], end = off[d + 1];
    const float ad = adn[d];
    const int qw = lane >> 4, l16 = lane & 15;
    float acc[8] = {0.f, 0.f, 0.f, 0.f, 0.f, 0.f, 0.f, 0.f};
    float den = 0.f;
    for (int base = beg; base < end; base += 64) {
        int e = base + lane;
        int s = 0; float ev = 0.f;    // inactive lanes: ev=0, s=0 (row-0 load harmless)
        if (e < end) {
            s = esrc[e];
            float v = asn[s] + ad;
            v = v > 0.f ? v : 0.2f * v;
            ev = __expf(v);
        }
        float r = ev;
        #pragma unroll
        for (int o = 32; o; o >>= 1) r += __shfl_xor(r, o);
        den += r;
        int cnt4 = (min(64, end - base) + 3) & ~3;
        for (int j = 0; j < cnt4; j += 8) {
            int jj = j + qw;
            float ev0 = __shfl(ev, jj);
            int   sj0 = __shfl(s, jj);
            short8v h0 = *(const short8v*)(hs + (size_t)sj0 * 128 + l16 * 8);
            if (j + 4 < cnt4) {                  // wave-uniform
                float ev1 = __shfl(ev, jj + 4);
                int   sj1 = __shfl(s, jj + 4);
                short8v h1 = *(const short8v*)(hs + (size_t)sj1 * 128 + l16 * 8);
                #pragma unroll
                for (int k = 0; k < 8; ++k)
                    acc[k] += ev0 * bf2f((ushort)h0[k]) + ev1 * bf2f((ushort)h1[k]);
            } else {
                #pragma unroll
                for (int k = 0; k < 8; ++k)
                    acc[k] += ev0 * bf2f((ushort)h0[k]);
            }
        }
    }
    #pragma unroll
    for (int k = 0; k < 8; ++k) {
        acc[k] += __shfl_xor(acc[k], 16);
        acc[k] += __shfl_xor(acc[k], 32);
    }
    if (qw == 0) {
        float inv = 1.f / (den + 1e-16f);
        short8v o;
        #pragma unroll
        for (int k = 0; k < 8; ++k) o[k] = (short)f2bf(acc[k] * inv);
        *(short8v*)(out + (size_t)d * 128 + l16 * 8) = o;
    }
}

// ---------------------------------------------------------------------------
// BN stats on bf16 inputs, two tensors per launch; ushort8 loads.
// ---------------------------------------------------------------------------
__global__ __launch_bounds__(256) void bn_stats2b(const ushort* __restrict__ x1, float* __restrict__ stat1,
                                                  int N1, int B1,
                                                  const ushort* __restrict__ x2, float* __restrict__ stat2,
                                                  int N2, int B2) {
    const ushort* x; float* stat; int N, b, nb;
    if ((int)blockIdx.x < B1) { x = x1; stat = stat1; N = N1; b = blockIdx.x; nb = B1; }
    else { x = x2; stat = stat2; N = N2; b = blockIdx.x - B1; nb = B2; }
    const int t = threadIdx.x;
    const int rg = t >> 4;         // 16 rows covered per block-iteration
    const int c16 = t & 15;        // 8-col group
    float s[8] = {0,0,0,0,0,0,0,0}, q[8] = {0,0,0,0,0,0,0,0};
    for (int r = b * 16 + rg; r < N; r += nb * 16) {
        short8v v = *(const short8v*)(x + (size_t)r * 128 + c16 * 8);
        #pragma unroll
        for (int k = 0; k < 8; ++k) {
            float f = bf2f((ushort)v[k]);
            s[k] += f; q[k] += f * f;
        }
    }
    #pragma unroll
    for (int k = 0; k < 8; ++k) {
        s[k] += __shfl_xor(s[k], 16); q[k] += __shfl_xor(q[k], 16);
        s[k] += __shfl_xor(s[k], 32); q[k] += __shfl_xor(q[k], 32);
    }
    __shared__ float rs[4][128], rq[4][128];
    const int w = t >> 6, l = t & 63;
    if (l < 16) {
        #pragma unroll
        for (int k = 0; k < 8; ++k) {
            rs[w][l * 8 + k] = s[k];
            rq[w][l * 8 + k] = q[k];
        }
    }
    __syncthreads();
    if (t < 128) {
        float ts = rs[0][t] + rs[1][t] + rs[2][t] + rs[3][t];
        float tq = rq[0][t] + rq[1][t] + rq[2][t] + rq[3][t];
        atomicAdd(&stat[t], ts);
        atomicAdd(&stat[128 + t], tq);
    }
}

// scale = g*rsqrt(var+eps), shift = b - mu*scale  (two BN instances)
__global__ __launch_bounds__(256) void bn_finalize2(float* __restrict__ s1, int N1,
                                                    const float* __restrict__ g1, const float* __restrict__ b1,
                                                    float* __restrict__ s2, int N2,
                                                    const float* __restrict__ g2, const float* __restrict__ b2) {
    int t = threadIdx.x;
    float* s; int N; const float *g, *b; int c;
    if (t < 128) { s = s1; N = N1; g = g1; b = b1; c = t; }
    else         { s = s2; N = N2; g = g2; b = b2; c = t - 128; }
    float invN = 1.0f / N;
    float mu  = s[c] * invN;
    float var = s[128 + c] * invN - mu * mu;
    float sc  = g[c] * rsqrtf(var + 1e-5f);
    s[c]       = sc;
    s[128 + c] = b[c] - mu * sc;
}

// y = elu(x*scale + shift); bf16 input; optional fp32 out; optional bf16 out (in-place ok)
__global__ void bn_apply2b(const ushort* __restrict__ x1, const float* __restrict__ ss1,
                           float* __restrict__ xo1, ushort* __restrict__ xb1, int N1,
                           const ushort* __restrict__ x2, const float* __restrict__ ss2,
                           float* __restrict__ xo2, ushort* __restrict__ xb2, int N2) {
    int i = blockIdx.x * 256 + threadIdx.x;       // each thread: 8 elements
    const ushort* x; const float* ss; float* xo; ushort* xb;
    if (i < N1 * 16) { x = x1; ss = ss1; xo = xo1; xb = xb1; }
    else {
        i -= N1 * 16;
        if (i >= N2 * 16) return;
        x = x2; ss = ss2; xo = xo2; xb = xb2;
    }
    int c16 = i & 15;
    short8v v = *(const short8v*)(x + (size_t)i * 8);
    float sc[8], sh[8];
    *(float4*)&sc[0] = *(const float4*)(ss + c16 * 8);
    *(float4*)&sc[4] = *(const float4*)(ss + c16 * 8 + 4);
    *(float4*)&sh[0] = *(const float4*)(ss + 128 + c16 * 8);
    *(float4*)&sh[4] = *(const float4*)(ss + 128 + c16 * 8 + 4);
    float o[8];
    #pragma unroll
    for (int k = 0; k < 8; ++k) {
        float f = bf2f((ushort)v[k]) * sc[k] + sh[k];
        o[k] = f > 0.f ? f : __expf(f) - 1.f;
    }
    if (xo) {
        *(float4*)(xo + (size_t)i * 8)     = make_float4(o[0], o[1], o[2], o[3]);
        *(float4*)(xo + (size_t)i * 8 + 4) = make_float4(o[4], o[5], o[6], o[7]);
    }
    if (xb) {
        short8v u;
        #pragma unroll
        for (int k = 0; k < 8; ++k) u[k] = (short)f2bf(o[k]);
        *(short8v*)(xb + (size_t)i * 8) = u;
    }
}

// ---------------------------------------------------------------------------
// Fused MLP: prefs[u] = tanh( leaky_relu(Xb[u]@hw1 + hb1, 0.01) @ hw2 + hb2 )
// ---------------------------------------------------------------------------
__global__ __launch_bounds__(256) void mlp_mfma(const ushort* __restrict__ Xb,
                                                const ushort* __restrict__ Wt,   // hw1t [64][128]
                                                const float* __restrict__ hb1,
                                                const float* __restrict__ hw2,
                                                const float* __restrict__ hb2,
                                                float* __restrict__ prefs, int N) {
    __shared__ short Xs[128 * LDR];
    __shared__ short Ws[64 * LDR];
    const int t = threadIdx.x;
    const int row0 = blockIdx.x * 128;

    for (int i = t; i < 128 * 16; i += 256) {
        int r = i >> 4, c8 = (i & 15) << 3;
        short8v v = {};
        if (row0 + r < N) v = *(const short8v*)(Xb + (size_t)(row0 + r) * 128 + c8);
        *(short8v*)(&Xs[r * LDR + c8]) = v;
    }
    for (int i = t; i < 64 * 16; i += 256) {
        int r = i >> 4, c8 = (i & 15) << 3;
        *(short8v*)(&Ws[r * LDR + c8]) = *(const short8v*)(Wt + r * 128 + c8);
    }
    __syncthreads();

    const int w = t >> 6, l = t & 63;
    const int m0 = w * 32;
    const int frow = l & 15;
    const int koff = (l >> 4) << 3;

    float4v acc[2][4];
    #pragma unroll
    for (int m = 0; m < 2; ++m)
        #pragma unroll
        for (int n = 0; n < 4; ++n) acc[m][n] = (float4v)0.f;

    #pragma unroll
    for (int ks = 0; ks < 4; ++ks) {
        const int k0 = ks * 32 + koff;
        short8v a[2], b[4];
        #pragma unroll
        for (int m = 0; m < 2; ++m)
            a[m] = *(const short8v*)(&Xs[(m0 + m * 16 + frow) * LDR + k0]);
        #pragma unroll
        for (int n = 0; n < 4; ++n)
            b[n] = *(const short8v*)(&Ws[(n * 16 + frow) * LDR + k0]);
        #pragma unroll
        for (int m = 0; m < 2; ++m)
            #pragma unroll
            for (int n = 0; n < 4; ++n)
                acc[m][n] = __builtin_amdgcn_mfma_f32_16x16x32_bf16(a[m], b[n], acc[m][n], 0, 0, 0);
    }

    float hb1v[4], hw2v[4];
    #pragma unroll
    for (int n = 0; n < 4; ++n) {
        int col = n * 16 + (l & 15);
        hb1v[n] = hb1[col];
        hw2v[n] = hw2[col];
    }
    const float hb2v = hb2[0];
    #pragma unroll
    for (int m = 0; m < 2; ++m) {
        #pragma unroll
        for (int r4 = 0; r4 < 4; ++r4) {
            float p = 0.f;
            #pragma unroll
            for (int n = 0; n < 4; ++n) {
                float v = acc[m][n][r4] + hb1v[n];
                v = v > 0.f ? v : 0.01f * v;
                p += v * hw2v[n];
            }
            p += __shfl_xor(p, 1);
            p += __shfl_xor(p, 2);
            p += __shfl_xor(p, 4);
            p += __shfl_xor(p, 8);
            int grow = row0 + m0 + m * 16 + ((l >> 4) << 2) + r4;
            if ((l & 15) == 0 && grow < N) prefs[grow] = tanhf(p + hb2v);
        }
    }
}

// s[he_food[e]] += prefs[he_user[e]] * score[e]
__global__ void health_scatter(const int* __restrict__ hu, const int* __restrict__ hf,
                               const float* __restrict__ score, const float* __restrict__ prefs,
                               float* __restrict__ s, int E) {
    int e = blockIdx.x * 256 + threadIdx.x;
    if (e >= E) return;
    atomicAdd(&s[hf[e]], prefs[hu[e]] * score[e]);
}

// xf2[f][c] += 0.1 * s[f]
__global__ void add_health(float* __restrict__ xf2, const float* __restrict__ s, int n4) {
    int i = blockIdx.x * 256 + threadIdx.x;
    if (i >= n4) return;
    float sv = 0.1f * s[i >> 5];
    float4 v = ((float4*)xf2)[i];
    v.x += sv; v.y += sv; v.z += sv; v.w += sv;
    ((float4*)xf2)[i] = v;
}

// ---------------------------------------------------------------------------
extern "C" void kernel_launch(void* const* d_in, const int* in_sizes, int n_in,
                              void* d_out, int out_size, void* d_ws, size_t ws_size,
                              hipStream_t stream) {
    const float* x_user = (const float*)d_in[0];
    const float* x_food = (const float*)d_in[1];
    const int* uf_src = (const int*)d_in[2];
    const int* uf_dst = (const int*)d_in[3];
    const int* fu_src = (const int*)d_in[4];
    const int* fu_dst = (const int*)d_in[5];
    const int* he_user = (const int*)d_in[6];
    const int* he_food = (const int*)d_in[7];
    const float* scores = (const float*)d_in[8];
    // GAT biases (d_in[13],[18],[23],[28]) cancel through BatchNorm — unused.
    const float* bn1_user_g = (const float*)d_in[29];
    const float* bn1_user_b = (const float*)d_in[30];
    const float* bn1_food_g = (const float*)d_in[31];
    const float* bn1_food_b = (const float*)d_in[32];
    const float* bn2_user_g = (const float*)d_in[33];
    const float* bn2_user_b = (const float*)d_in[34];
    const float* bn2_food_g = (const float*)d_in[35];
    const float* bn2_food_b = (const float*)d_in[36];
    const float* hw1 = (const float*)d_in[37];
    const float* hb1 = (const float*)d_in[38];
    const float* hw2 = (const float*)d_in[39];
    const float* hb2 = (const float*)d_in[40];

    float* outp  = (float*)d_out;
    float* xu2   = outp;                          // [NU,128]
    float* xf2   = outp + (size_t)NU_ * 128;      // [NF,128]
    float* prefs = xf2 + (size_t)NF_ * 128;       // [NU]

    // ---- workspace layout ----
    float* ws = (float*)d_ws;
    ushort* hs_u = (ushort*)ws;                        // NU*128 bf16
    ushort* hs_f = hs_u + (size_t)NU_ * 128;           // NF*128
    float* base1 = ws + (size_t)(NU_ + NF_) * 64;
    ushort* xu1b = (ushort*)base1;                     // NU*128 (layer-1 out / layer-2 in)
    ushort* xf1b = xu1b + (size_t)NU_ * 128;           // NF*128
    float* base2 = base1 + (size_t)(NU_ + NF_) * 64;
    ushort* xu2b = (ushort*)base2;                     // NU*128 (layer-1 input bu, then layer-2 raw out)
    ushort* xf2b = xu2b + (size_t)NU_ * 128;           // NF*128 (bfo, then layer-2 raw out)
    float* base3 = base2 + (size_t)(NU_ + NF_) * 64;
    float* asn_u = base3;                              // NU
    float* adn_u = asn_u + NU_;                        // NU
    float* asn_f = adn_u + NU_;                        // NF
    float* adn_f = asn_f + NF_;                        // NF
    // --- zeroed-once region ---
    float* stat4 = adn_f + NF_;                        // 4*256
    float* sbuf  = stat4 + 1024;                       // NF
    int*   deg_f = (int*)(sbuf + NF_);                 // NF
    int*   deg_u = deg_f + NF_;                        // NU
    // --- zeroed-once region end ---
    int* part_f  = deg_u + NU_;                        // 32
    int* part_u  = part_f + 32;                        // 64
    int* uf_off  = part_u + 64;                        // NF+4
    int* fu_off  = uf_off + (NF_ + 4);                 // NU+4
    int* cur_f   = fu_off + (NU_ + 4);                 // NF
    int* cur_u   = cur_f + NF_;                        // NU
    int* uf_esrc = cur_u + NU_;                        // E
    int* fu_esrc = uf_esrc + E_;                       // E
    ushort* wt0  = (ushort*)(fu_esrc + E_);            // 128*128 each
    ushort* wt1  = wt0 + 16384;
    ushort* wt2  = wt1 + 16384;
    ushort* wt3  = wt2 + 16384;
    ushort* hw1t = wt3 + 16384;                        // 64*128
    float* vall  = (float*)(hw1t + 8192);              // 8*128

    const size_t zero_elems = 1024 + NF_ + NF_ + NU_;
    hipMemsetAsync(stat4, 0, zero_elems * sizeof(float), stream);

    // --- fused preprocessing ---
    PPArgs pp;
    pp.xu = x_user; pp.xf = x_food; pp.bu = xu2b; pp.bfo = xf2b;
    pp.W[0] = (const float*)d_in[9];  pp.T[0] = wt0;
    pp.W[1] = (const float*)d_in[14]; pp.T[1] = wt1;
    pp.W[2] = (const float*)d_in[19]; pp.T[2] = wt2;
    pp.W[3] = (const float*)d_in[24]; pp.T[3] = wt3;
    pp.W[4] = hw1;                    pp.T[4] = hw1t;
    pp.waW[0] = (const float*)d_in[9];  pp.waA[0] = (const float*)d_in[11];
    pp.waW[1] = (const float*)d_in[10]; pp.waA[1] = (const float*)d_in[12];
    pp.waW[2] = (const float*)d_in[14]; pp.waA[2] = (const float*)d_in[16];
    pp.waW[3] = (const float*)d_in[15]; pp.waA[3] = (const float*)d_in[17];
    pp.waW[4] = (const float*)d_in[19]; pp.waA[4] = (const float*)d_in[21];
    pp.waW[5] = (const float*)d_in[20]; pp.waA[5] = (const float*)d_in[22];
    pp.waW[6] = (const float*)d_in[24]; pp.waA[6] = (const float*)d_in[26];
    pp.waW[7] = (const float*)d_in[25]; pp.waA[7] = (const float*)d_in[27];
    pp.vall = vall;
    const int PPB = NU_ * 32 / 256 + NF_ * 32 / 256 + 288 + 256;
    preprocess<<<PPB, 256, 0, stream>>>(pp);

    // --- CSR build, both edge types ---
    const int EB = (E_ + 255) / 256;
    const int NBF = (NF_ + 1023) / 1024;   // 25
    const int NBU = (NU_ + 1023) / 1024;   // 49
    csr_count_both<<<2 * EB, 256, 0, stream>>>(uf_dst, fu_dst, deg_f, deg_u, EB);
    csr_psum_both<<<NBF + NBU, 256, 0, stream>>>(deg_f, part_f, deg_u, part_u);
    csr_scan_both<<<1, 128, 0, stream>>>(part_f, &uf_off[NF_], part_u, &fu_off[NU_]);
    csr_bscan_both<<<NBF + NBU, 256, 0, stream>>>(deg_f, part_f, uf_off, cur_f,
                                                  deg_u, part_u, fu_off, cur_u);
    csr_fill_both<<<2 * EB, 256, 0, stream>>>(uf_src, uf_dst, cur_f, uf_esrc,
                                              fu_src, fu_dst, cur_u, fu_esrc, EB);

    const int GB   = (NU_ + 127) / 128 + (NF_ + 127) / 128;       // 587
    const int MVB  = (NU_ + NF_ + 3) / 4;                         // 18750
    const int AGB  = (NF_ + 3) / 4 + (NU_ + 3) / 4;               // 18750
    const int APB  = ((NU_ + NF_) * 16 + 255) / 256;              // 4688

    // ---- layer 1 ----
    gemm_both<<<GB, 256, 0, stream>>>(xu2b, wt0, hs_u, xf2b, wt1, hs_f);
    matvec4<<<MVB, 256, 0, stream>>>(xu2b, xf2b, vall + 0, vall + 384, vall + 128, vall + 256,
                                     asn_u, adn_u, adn_f, asn_f);
    gat_agg_both<<<AGB, 256, 0, stream>>>(uf_off, uf_esrc, asn_u, adn_f, hs_u, xf1b,
                                          fu_off, fu_esrc, asn_f, adn_u, hs_f, xu1b);
    bn_stats2b<<<768, 256, 0, stream>>>(xu1b, stat4 + 0, NU_, 512, xf1b, stat4 + 256, NF_, 256);
    bn_finalize2<<<1, 256, 0, stream>>>(stat4 + 0, NU_, bn1_user_g, bn1_user_b,
                                        stat4 + 256, NF_, bn1_food_g, bn1_food_b);
    bn_apply2b<<<APB, 256, 0, stream>>>(xu1b, stat4 + 0,   (float*)nullptr, xu1b, NU_,
                                        xf1b, stat4 + 256, (float*)nullptr, xf1b, NF_);

    // ---- layer 2 ----
    gemm_both<<<GB, 256, 0, stream>>>(xu1b, wt2, hs_u, xf1b, wt3, hs_f);
    matvec4<<<MVB, 256, 0, stream>>>(xu1b, xf1b, vall + 512, vall + 896, vall + 640, vall + 768,
                                     asn_u, adn_u, adn_f, asn_f);
    gat_agg_both<<<AGB, 256, 0, stream>>>(uf_off, uf_esrc, asn_u, adn_f, hs_u, xf2b,
                                          fu_off, fu_esrc, asn_f, adn_u, hs_f, xu2b);
    bn_stats2b<<<768, 256, 0, stream>>>(xu2b, stat4 + 512, NU_, 512, xf2b, stat4 + 768, NF_, 256);
    bn_finalize2<<<1, 256, 0, stream>>>(stat4 + 512, NU_, bn2_user_g, bn2_user_b,
                                        stat4 + 768, NF_, bn2_food_g, bn2_food_b);
    bn_apply2b<<<APB, 256, 0, stream>>>(xu2b, stat4 + 512, xu2, xu2b, NU_,
                                        xf2b, stat4 + 768, xf2, (ushort*)nullptr, NF_);

    // ---- health preference MLP + scatter update ----
    mlp_mfma<<<(NU_ + 127) / 128, 256, 0, stream>>>(xu2b, hw1t, hb1, hw2, hb2, prefs, NU_);
    health_scatter<<<EB, 256, 0, stream>>>(he_user, he_food, scores, prefs, sbuf, E_);
    add_health<<<(NF_ * 32 + 255) / 256, 256, 0, stream>>>(xf2, sbuf, NF_ * 32);
}